// Round 6
// baseline (765.072 us; speedup 1.0000x reference)
//
#include <hip/hip_runtime.h>

// ---------------------------------------------------------------------------
// MPNN_block_seperate — MFMA split-bf16 conv path + MFMA fused graph stage, v6.
// v5 counters: convs latency-bound (all pipes <30%, occ 30%) — the serial
// stage->barrier->MFMA->barrier chunk loop exposes full global-load latency.
// v6: each conv block loops over all its l-tiles with DOUBLE-BUFFERED LDS and
// an issue-early/write-late pipeline (T3 2-phase + T14): loads for stage s+1
// issue before stage s's MFMAs, BN+split+LDS-write happen after, one barrier
// per chunk.  MFMA order unchanged -> conv results bit-identical to v5.
// Graph stage (graph_f_k) unchanged from v5.
// ---------------------------------------------------------------------------

#define TPB 256

// stats block offsets (floats)
#define RAW1 0
#define FIN1 512
#define RAW2 1024
#define FIN2 1280
#define RAW3 1536
#define FIN3 2048
#define RAWG 2560
#define ST_FLOATS 2688

typedef __attribute__((ext_vector_type(8))) short bf16x8;
typedef __attribute__((ext_vector_type(4))) float f32x4;

union U8 { unsigned u[4]; bf16x8 v; };

__device__ __forceinline__ unsigned short bf16tr(float x) {
    return (unsigned short)(__float_as_uint(x) >> 16);
}
__device__ __forceinline__ float bf16tof(unsigned short h) {
    return __uint_as_float(((unsigned int)h) << 16);
}
__device__ __forceinline__ void split2(float a, float b, unsigned& h, unsigned& l) {
    unsigned short ha = bf16tr(a), hb = bf16tr(b);
    unsigned short la = bf16tr(a - bf16tof(ha)), lb = bf16tr(b - bf16tof(hb));
    h = (unsigned)ha | ((unsigned)hb << 16);
    l = (unsigned)la | ((unsigned)lb << 16);
}

// ---- one-time weight split: w[co][ci][k] (fp32) -> wh/wl [k][CO][CI] bf16 ----
__global__ __launch_bounds__(TPB) void split_w_k(const float* __restrict__ w,
                                                 unsigned short* __restrict__ wh,
                                                 unsigned short* __restrict__ wl,
                                                 int CO, int CI)
{
    int idx = blockIdx.x * TPB + threadIdx.x;
    if (idx >= CO * CI * 3) return;
    int ci = idx % CI; int rest = idx / CI; int co = rest % CO; int k = rest / CO;
    float v = w[((size_t)co * CI + ci) * 3 + k];
    unsigned short h = bf16tr(v);
    unsigned short l = bf16tr(v - bf16tof(h));
    wh[idx] = h; wl[idx] = l;
}

// ---- linear split (identity layout) for map_w / theta_w ----
__global__ __launch_bounds__(TPB) void split_lin_k(const float* __restrict__ w,
                                                   unsigned short* __restrict__ wh,
                                                   unsigned short* __restrict__ wl,
                                                   int n)
{
    int i = blockIdx.x * TPB + threadIdx.x;
    if (i >= n) return;
    float v = w[i];
    unsigned short h = bf16tr(v);
    wh[i] = h; wl[i] = bf16tr(v - bf16tof(h));
}

// ---------------------------------------------------------------------------
// Pipelined MFMA conv core.  One block per bz; internal loop over NT l-tiles
// x (CI/32) ci-chunks with double-buffered LDS.
//   LAYOUT 0: input x [16][256][64][64]; row l at base[l*4096 + ci]
//   LAYOUT 1: input [bz][Lin][CI] row-major
//   STAGEBN:  staging applies relu(v*finIn[ci] + finIn[CI+ci])
//   MODE 3: stats + pooled-RAW -> out[bn0o+bz][j][co]   (store if bz < bzStore)
//   MODE 4: stats + pooled-RAW -> SPA [bq][72][64][128]
//   MODE 5: pooled-RAW only    -> out[bn0o+bz][j][co]
// ---------------------------------------------------------------------------
template<int LAYOUT, int MODE, int STAGEBN, int CF>
__global__ __launch_bounds__(TPB) void mconv_k(const float* __restrict__ in,
                                               const unsigned short* __restrict__ wh,
                                               const unsigned short* __restrict__ wl,
                                               const float* __restrict__ finIn,
                                               float* __restrict__ out,
                                               float* __restrict__ raw,
                                               int CI, int CO, int Lin, int pad,
                                               int Lconv, int Lp, int NT,
                                               int bzStore, int bn0x, int bn0o)
{
    __shared__ __align__(16) unsigned short Xh[2][66 * 72];
    __shared__ __align__(16) unsigned short Xl[2][66 * 72];
    __shared__ float s_s1[256], s_s2[256];
    constexpr bool STATS = (MODE == 3 || MODE == 4);

    int tid  = threadIdx.x;
    int lane = tid & 63;
    int w    = tid >> 6;
    int g16  = lane >> 4;
    int l16  = lane & 15;
    int wbase = w * (CF * 16);
    int bz   = blockIdx.z;

    const float* base;
    int RS;
    if (LAYOUT == 0) {
        int bn = bn0x + bz;
        base = in + (size_t)(bn >> 6) * 1048576 + (size_t)(bn & 63) * 64;
        RS = 4096;
    } else {
        base = in + (size_t)bz * CI * Lin;
        RS = CI;
    }

    if (STATS && tid < CO) { s_s1[tid] = 0.f; s_s2[tid] = 0.f; }

    const int NC = CI >> 5;          // 32-ci chunks per tile
    const int NS = NT * NC;          // pipeline stages

    // staging register file: item0 = idx tid, item1 = idx tid+256 (tid<8 only)
    int r0 = tid >> 2, q0 = tid & 3;
    bool has1 = (tid < 8);
    int r1 = (tid + 256) >> 2, q1 = tid & 3;

    float v0[8], v1[8];

    auto LOAD = [&](int s) {
        int t = s / NC, c = s - t * NC;
        int gb = t * 64 - 1 - pad;
        {
            int gl = gb + r0;
            if (gl >= 0 && gl < Lin) {
                const float* p = base + (size_t)gl * RS + c * 32 + 8 * q0;
                float4 a = *(const float4*)p, b4 = *(const float4*)(p + 4);
                v0[0] = a.x;  v0[1] = a.y;  v0[2] = a.z;  v0[3] = a.w;
                v0[4] = b4.x; v0[5] = b4.y; v0[6] = b4.z; v0[7] = b4.w;
            } else {
#pragma unroll
                for (int j = 0; j < 8; j++) v0[j] = 0.f;
            }
        }
        if (has1) {
            int gl = gb + r1;
            if (gl >= 0 && gl < Lin) {
                const float* p = base + (size_t)gl * RS + c * 32 + 8 * q1;
                float4 a = *(const float4*)p, b4 = *(const float4*)(p + 4);
                v1[0] = a.x;  v1[1] = a.y;  v1[2] = a.z;  v1[3] = a.w;
                v1[4] = b4.x; v1[5] = b4.y; v1[6] = b4.z; v1[7] = b4.w;
            } else {
#pragma unroll
                for (int j = 0; j < 8; j++) v1[j] = 0.f;
            }
        }
    };

    auto WRITE1 = [&](float* v, int r, int q, int c, int gb, int buf) {
        if (STAGEBN) {
            int gl = gb + r;
            if (gl >= 0 && gl < Lin) {
                const float* sc = finIn + c * 32 + 8 * q;
                const float* sh = finIn + CI + c * 32 + 8 * q;
                float4 s0 = *(const float4*)sc, s1 = *(const float4*)(sc + 4);
                float4 h0 = *(const float4*)sh, h1 = *(const float4*)(sh + 4);
                v[0] = fmaxf(v[0] * s0.x + h0.x, 0.f);
                v[1] = fmaxf(v[1] * s0.y + h0.y, 0.f);
                v[2] = fmaxf(v[2] * s0.z + h0.z, 0.f);
                v[3] = fmaxf(v[3] * s0.w + h0.w, 0.f);
                v[4] = fmaxf(v[4] * s1.x + h1.x, 0.f);
                v[5] = fmaxf(v[5] * s1.y + h1.y, 0.f);
                v[6] = fmaxf(v[6] * s1.z + h1.z, 0.f);
                v[7] = fmaxf(v[7] * s1.w + h1.w, 0.f);
            }
        }
        uint4 hu, lu;
        split2(v[0], v[1], hu.x, lu.x);
        split2(v[2], v[3], hu.y, lu.y);
        split2(v[4], v[5], hu.z, lu.z);
        split2(v[6], v[7], hu.w, lu.w);
        *(uint4*)&Xh[buf][r * 72 + 8 * q] = hu;
        *(uint4*)&Xl[buf][r * 72 + 8 * q] = lu;
    };

    auto WRITE = [&](int s, int buf) {
        int t = s / NC, c = s - t * NC;
        int gb = t * 64 - 1 - pad;
        WRITE1(v0, r0, q0, c, gb, buf);
        if (has1) WRITE1(v1, r1, q1, c, gb, buf);
    };

    // ---- prologue ----
    LOAD(0);
    WRITE(0, 0);
    __syncthreads();

    f32x4 acc[CF][4];
    int cur = 0;

    for (int s = 0; s < NS; s++) {
        int t = s / NC, c = s - t * NC;
        int Lbase = t * 64 - 1;
        if (c == 0) {
#pragma unroll
            for (int cf = 0; cf < CF; cf++)
#pragma unroll
                for (int nf = 0; nf < 4; nf++) {
                    f32x4 z = {0.f, 0.f, 0.f, 0.f};
                    acc[cf][nf] = z;
                }
        }

        if (s + 1 < NS) LOAD(s + 1);     // issue next-stage loads early

        // ---- MFMA over chunk c of tile t ----
        int ci0 = c * 32;
#pragma unroll
        for (int k = 0; k < 3; k++) {
            bf16x8 ah[CF], al[CF];
#pragma unroll
            for (int cf = 0; cf < CF; cf++) {
                size_t wof = ((size_t)(k * CO + wbase + cf * 16 + l16)) * CI
                             + ci0 + g16 * 8;
                ah[cf] = *(const bf16x8*)(wh + wof);
                al[cf] = *(const bf16x8*)(wl + wof);
            }
#pragma unroll
            for (int nf = 0; nf < 4; nf++) {
                if (Lbase + nf * 16 >= Lconv) continue;
                int rb = nf * 16 + l16 + k;
                bf16x8 bh = *(const bf16x8*)&Xh[cur][rb * 72 + g16 * 8];
                bf16x8 bl = *(const bf16x8*)&Xl[cur][rb * 72 + g16 * 8];
#pragma unroll
                for (int cf = 0; cf < CF; cf++) {
                    acc[cf][nf] = __builtin_amdgcn_mfma_f32_16x16x32_bf16(
                        ah[cf], bh, acc[cf][nf], 0, 0, 0);
                    acc[cf][nf] = __builtin_amdgcn_mfma_f32_16x16x32_bf16(
                        ah[cf], bl, acc[cf][nf], 0, 0, 0);
                    acc[cf][nf] = __builtin_amdgcn_mfma_f32_16x16x32_bf16(
                        al[cf], bh, acc[cf][nf], 0, 0, 0);
                }
            }
        }

        // ---- tile epilogue ----
        if (c == NC - 1) {
            if (STATS) {
#pragma unroll
                for (int cf = 0; cf < CF; cf++)
#pragma unroll
                    for (int rg = 0; rg < 4; rg++) {
                        float a = 0.f, b = 0.f;
#pragma unroll
                        for (int nf = 0; nf < 4; nf++) {
                            int l = Lbase + nf * 16 + l16;
                            if (l >= 0 && l < Lconv) {
                                float v = acc[cf][nf][rg];
                                a += v; b += v * v;
                            }
                        }
#pragma unroll
                        for (int m = 1; m < 16; m <<= 1) {
                            a += __shfl_xor(a, m); b += __shfl_xor(b, m);
                        }
                        if (l16 == 0) {
                            atomicAdd(&s_s1[wbase + cf * 16 + g16 * 4 + rg], a);
                            atomicAdd(&s_s2[wbase + cf * 16 + g16 * 4 + rg], b);
                        }
                    }
            }
            if ((MODE == 3 || MODE == 5) && bz < bzStore) {
#pragma unroll
                for (int cf = 0; cf < CF; cf++)
#pragma unroll
                    for (int nf = 0; nf < 4; nf++) {
                        int l = Lbase + nf * 16 + l16;
                        bool ok = (l >= 0 && l < Lconv);
                        float4 pv;
#pragma unroll
                        for (int rg = 0; rg < 4; rg++) {
                            float v = ok ? acc[cf][nf][rg] : -3.0e38f;
                            float vv = __shfl_xor(v, 1);
                            ((float*)&pv)[rg] = fmaxf(v, vv);
                        }
                        int j = (l + 1) >> 1;
                        if (!(lane & 1) && j < Lp)
                            *(float4*)&out[((size_t)(bn0o + bz) * Lp + j) * CO
                                           + wbase + cf * 16 + g16 * 4] = pv;
                    }
            }
            if (MODE == 4) {
#pragma unroll
                for (int cf = 0; cf < CF; cf++)
#pragma unroll
                    for (int nf = 0; nf < 4; nf++) {
                        int l = Lbase + nf * 16 + l16;
                        bool ok = (l >= 0 && l < Lconv);
                        int j = (l + 1) >> 1;
#pragma unroll
                        for (int rg = 0; rg < 4; rg++) {
                            float v = ok ? acc[cf][nf][rg] : -3.0e38f;
                            float vv = __shfl_xor(v, 1);
                            if (!(lane & 1) && j < Lp) {
                                float pv = fmaxf(v, vv);
                                int co = wbase + cf * 16 + g16 * 4 + rg;
                                int lin = co * 36 + j;
                                int tc = lin >> 7, f = lin & 127;
                                int bq = bz >> 6, n = bz & 63;
                                out[(((size_t)bq * 72 + tc) * 64 + n) * 128 + f] = pv;
                            }
                        }
                    }
            }
        }

        if (s + 1 < NS) WRITE(s + 1, cur ^ 1);   // write-late into other buffer
        __syncthreads();
        cur ^= 1;
    }

    if (STATS) {
        if (tid < CO) {
            atomicAdd(&raw[tid], s_s1[tid]);
            atomicAdd(&raw[CO + tid], s_s2[tid]);
        }
    }
}

// fin[c] = scale = g*rsqrt(var+eps);  fin[C+c] = shift = b - mean*scale
__global__ __launch_bounds__(TPB) void bn_fin_k(const float* __restrict__ raw,
                                                const float* __restrict__ g,
                                                const float* __restrict__ b,
                                                float* __restrict__ fin, int C, float invN)
{
    int c = threadIdx.x + blockIdx.x * TPB;
    if (c < C) {
        float m = raw[c] * invN;
        float v = raw[C + c] * invN - m * m;
        float sc = g[c] * rsqrtf(v + 1e-5f);
        fin[c] = sc;
        fin[C + c] = b[c] - m * sc;
    }
}

// ---------------------------------------------------------------------------
// Fused graph stage on MFMA (unchanged from v5).
// ---------------------------------------------------------------------------
#define AJX(n,m) s_adj[(((n) * 64 + (m)) ^ (((n) & 7) << 3))]

__global__ __launch_bounds__(TPB) void graph_f_k(const float* __restrict__ spa,
                                                 const float* __restrict__ fin3,
                                                 const unsigned short* __restrict__ wmh,
                                                 const unsigned short* __restrict__ wml,
                                                 const float* __restrict__ mapb,
                                                 const unsigned short* __restrict__ thh,
                                                 const unsigned short* __restrict__ thl,
                                                 const float* __restrict__ thb,
                                                 float* __restrict__ gout,
                                                 float* __restrict__ rawg)
{
    __shared__ __align__(16) unsigned short NFh[8192], NFl[8192];  // [64][128] swz
    __shared__ __align__(16) float s_adj[4096];                    // [64][64]  swz
    __shared__ __align__(16) unsigned short Gth[4096], Gtl[4096];  // [o][m]    swz
    __shared__ float s_red[256], s_rmax[64], s_rsum[64], s_s1[64], s_s2[64];

    int tid  = threadIdx.x;
    int lane = tid & 63;
    int w    = tid >> 6;
    int g16  = lane >> 4, l16 = lane & 15;
    int n0   = w * 16;
    int bp   = blockIdx.x;
    int tcb  = (bp % 72) * 128;

    if (tid < 64) { s_s1[tid] = 0.f; s_s2[tid] = 0.f; }

    // ---- P0: A = relu(bn3(spa)) for rows n0+l16 -> registers (split bf16) ----
    unsigned aH[16], aL[16];
    {
        const float* ar = spa + ((size_t)bp * 64 + n0 + l16) * 128;
#pragma unroll
        for (int kc = 0; kc < 4; kc++) {
            int kb = kc * 32 + g16 * 8;
            float4 x0 = *(const float4*)(ar + kb);
            float4 x1 = *(const float4*)(ar + kb + 4);
            float v[8] = {x0.x, x0.y, x0.z, x0.w, x1.x, x1.y, x1.z, x1.w};
#pragma unroll
            for (int j = 0; j < 8; j++) {
                int co = ((tcb + kb + j) * 29128) >> 20;   // exact /36 for x<32768
                float z = v[j] * fin3[co] + fin3[256 + co];
                v[j] = z > 0.f ? z : 0.f;
            }
            split2(v[0], v[1], aH[kc*4+0], aL[kc*4+0]);
            split2(v[2], v[3], aH[kc*4+1], aL[kc*4+1]);
            split2(v[4], v[5], aH[kc*4+2], aL[kc*4+2]);
            split2(v[6], v[7], aH[kc*4+3], aL[kc*4+3]);
        }
    }

    // ---- P1: nf = A @ map_w^T + mapb  -> NFh/NFl ----
    {
        f32x4 acc[8];
#pragma unroll
        for (int i = 0; i < 8; i++) { f32x4 z = {0.f,0.f,0.f,0.f}; acc[i] = z; }
#pragma unroll
        for (int ff = 0; ff < 8; ff++) {
#pragma unroll
            for (int kc = 0; kc < 4; kc++) {
                U8 ah, al;
#pragma unroll
                for (int u = 0; u < 4; u++) { ah.u[u] = aH[kc*4+u]; al.u[u] = aL[kc*4+u]; }
                size_t wo = (size_t)(ff * 16 + l16) * 128 + kc * 32 + g16 * 8;
                bf16x8 bh = *(const bf16x8*)(wmh + wo);
                bf16x8 bl = *(const bf16x8*)(wml + wo);
                acc[ff] = __builtin_amdgcn_mfma_f32_16x16x32_bf16(ah.v, bh, acc[ff], 0, 0, 0);
                acc[ff] = __builtin_amdgcn_mfma_f32_16x16x32_bf16(ah.v, bl, acc[ff], 0, 0, 0);
                acc[ff] = __builtin_amdgcn_mfma_f32_16x16x32_bf16(al.v, bh, acc[ff], 0, 0, 0);
            }
        }
#pragma unroll
        for (int ff = 0; ff < 8; ff++) {
            float bv = mapb[ff * 16 + l16];
#pragma unroll
            for (int rg = 0; rg < 4; rg++) {
                int n = n0 + g16 * 4 + rg;
                float v = acc[ff][rg] + bv;
                int s = ((n * 128) + ff * 16 + l16) ^ ((n & 7) << 3);
                unsigned short h = bf16tr(v);
                NFh[s] = h;
                NFl[s] = bf16tr(v - bf16tof(h));
            }
        }
    }
    __syncthreads();

    // ---- preload this wave's NF rows (A-operand for adj and G) ----
    bf16x8 nh[4], nl[4];
#pragma unroll
    for (int kc = 0; kc < 4; kc++) {
        int r = n0 + l16;
        int s = ((r * 128) + kc * 32 + g16 * 8) ^ ((r & 7) << 3);
        nh[kc] = *(const bf16x8*)&NFh[s];
        nl[kc] = *(const bf16x8*)&NFl[s];
    }

    // ---- P2: adj = nf @ nf^T  (diag -1e8, leaky) -> s_adj ----
    {
        f32x4 aj[4];
#pragma unroll
        for (int i = 0; i < 4; i++) { f32x4 z = {0.f,0.f,0.f,0.f}; aj[i] = z; }
#pragma unroll
        for (int mf = 0; mf < 4; mf++) {
#pragma unroll
            for (int kc = 0; kc < 4; kc++) {
                int r = mf * 16 + l16;
                int s = ((r * 128) + kc * 32 + g16 * 8) ^ ((r & 7) << 3);
                bf16x8 bh = *(const bf16x8*)&NFh[s];
                bf16x8 bl = *(const bf16x8*)&NFl[s];
                aj[mf] = __builtin_amdgcn_mfma_f32_16x16x32_bf16(nh[kc], bh, aj[mf], 0, 0, 0);
                aj[mf] = __builtin_amdgcn_mfma_f32_16x16x32_bf16(nh[kc], bl, aj[mf], 0, 0, 0);
                aj[mf] = __builtin_amdgcn_mfma_f32_16x16x32_bf16(nl[kc], bh, aj[mf], 0, 0, 0);
            }
        }
#pragma unroll
        for (int mf = 0; mf < 4; mf++)
#pragma unroll
            for (int rg = 0; rg < 4; rg++) {
                int n = n0 + g16 * 4 + rg, m = mf * 16 + l16;
                float v = aj[mf][rg];
                if (n == m) v -= 1e8f;
                v = v > 0.f ? v : 0.01f * v;
                AJX(n, m) = v;
            }
    }

    // ---- P3: G = nf @ theta^T -> Gt (transposed, split bf16) ----
    {
        f32x4 gg[4];
#pragma unroll
        for (int i = 0; i < 4; i++) { f32x4 z = {0.f,0.f,0.f,0.f}; gg[i] = z; }
#pragma unroll
        for (int of = 0; of < 4; of++) {
#pragma unroll
            for (int kc = 0; kc < 4; kc++) {
                size_t to = (size_t)(of * 16 + l16) * 128 + kc * 32 + g16 * 8;
                bf16x8 th_ = *(const bf16x8*)(thh + to);
                bf16x8 tl_ = *(const bf16x8*)(thl + to);
                gg[of] = __builtin_amdgcn_mfma_f32_16x16x32_bf16(nh[kc], th_, gg[of], 0, 0, 0);
                gg[of] = __builtin_amdgcn_mfma_f32_16x16x32_bf16(nh[kc], tl_, gg[of], 0, 0, 0);
                gg[of] = __builtin_amdgcn_mfma_f32_16x16x32_bf16(nl[kc], th_, gg[of], 0, 0, 0);
            }
        }
#pragma unroll
        for (int of = 0; of < 4; of++) {
            unsigned short hs[4], ls[4];
#pragma unroll
            for (int rg = 0; rg < 4; rg++) {
                float v = gg[of][rg];
                hs[rg] = bf16tr(v);
                ls[rg] = bf16tr(v - bf16tof(hs[rg]));
            }
            int o = of * 16 + l16;
            int m = n0 + g16 * 4;            // 4 consecutive m
            int s = ((o * 64) + m) ^ ((o & 7) << 3);
            uint2 hp, lp;
            hp.x = (unsigned)hs[0] | ((unsigned)hs[1] << 16);
            hp.y = (unsigned)hs[2] | ((unsigned)hs[3] << 16);
            lp.x = (unsigned)ls[0] | ((unsigned)ls[1] << 16);
            lp.y = (unsigned)ls[2] | ((unsigned)ls[3] << 16);
            *(uint2*)&Gth[s] = hp;
            *(uint2*)&Gtl[s] = lp;
        }
    }
    __syncthreads();

    // ---- P4: row softmax + I on s_adj ----
    {
        int n = tid >> 2, q = tid & 3;
        float mx = -3.0e38f;
        for (int m = q * 16; m < q * 16 + 16; m++) mx = fmaxf(mx, AJX(n, m));
        s_red[n * 4 + q] = mx;
    }
    __syncthreads();
    if (tid < 64)
        s_rmax[tid] = fmaxf(fmaxf(s_red[tid * 4], s_red[tid * 4 + 1]),
                            fmaxf(s_red[tid * 4 + 2], s_red[tid * 4 + 3]));
    __syncthreads();
    {
        int n = tid >> 2, q = tid & 3;
        float mx = s_rmax[n];
        float sm = 0.f;
        for (int m = q * 16; m < q * 16 + 16; m++) {
            float e = __expf(AJX(n, m) - mx);
            AJX(n, m) = e;
            sm += e;
        }
        s_red[n * 4 + q] = sm;
    }
    __syncthreads();
    if (tid < 64)
        s_rsum[tid] = 1.0f / (s_red[tid * 4] + s_red[tid * 4 + 1] +
                              s_red[tid * 4 + 2] + s_red[tid * 4 + 3]);
    __syncthreads();
    {
        int n = tid >> 2, q = tid & 3;
        float inv = s_rsum[n];
        for (int m = q * 16; m < q * 16 + 16; m++)
            AJX(n, m) = AJX(n, m) * inv + ((n == m) ? 1.f : 0.f);
    }
    __syncthreads();

    // ---- P5: out = adjS @ G + thb -> gout, fused stats ----
    {
        f32x4 oacc[4];
#pragma unroll
        for (int i = 0; i < 4; i++) { f32x4 z = {0.f,0.f,0.f,0.f}; oacc[i] = z; }
#pragma unroll
        for (int kc = 0; kc < 2; kc++) {
            int r = n0 + l16;
            int sf = ((r * 64) + kc * 32 + g16 * 8) ^ ((r & 7) << 3);
            float4 p0 = *(const float4*)&s_adj[sf];
            float4 p1 = *(const float4*)&s_adj[sf + 4];
            U8 ah, al;
            split2(p0.x, p0.y, ah.u[0], al.u[0]);
            split2(p0.z, p0.w, ah.u[1], al.u[1]);
            split2(p1.x, p1.y, ah.u[2], al.u[2]);
            split2(p1.z, p1.w, ah.u[3], al.u[3]);
#pragma unroll
            for (int of = 0; of < 4; of++) {
                int o = of * 16 + l16;
                int s = ((o * 64) + kc * 32 + g16 * 8) ^ ((o & 7) << 3);
                bf16x8 gh = *(const bf16x8*)&Gth[s];
                bf16x8 gl = *(const bf16x8*)&Gtl[s];
                oacc[of] = __builtin_amdgcn_mfma_f32_16x16x32_bf16(ah.v, gh, oacc[of], 0, 0, 0);
                oacc[of] = __builtin_amdgcn_mfma_f32_16x16x32_bf16(ah.v, gl, oacc[of], 0, 0, 0);
                oacc[of] = __builtin_amdgcn_mfma_f32_16x16x32_bf16(al.v, gh, oacc[of], 0, 0, 0);
            }
        }
        float* gb = gout + (size_t)bp * 4096;
#pragma unroll
        for (int of = 0; of < 4; of++) {
            float tb = thb[of * 16 + l16];
            float a = 0.f, b = 0.f;
#pragma unroll
            for (int rg = 0; rg < 4; rg++) {
                int n = n0 + g16 * 4 + rg;
                float v = oacc[of][rg] + tb;
                gb[n * 64 + of * 16 + l16] = v;
                a += v; b += v * v;
            }
            a += __shfl_xor(a, 16); a += __shfl_xor(a, 32);
            b += __shfl_xor(b, 16); b += __shfl_xor(b, 32);
            if (g16 == 0) {
                atomicAdd(&s_s1[of * 16 + l16], a);
                atomicAdd(&s_s2[of * 16 + l16], b);
            }
        }
    }
    __syncthreads();
    if (tid < 64) {
        atomicAdd(&rawg[tid], s_s1[tid]);
        atomicAdd(&rawg[64 + tid], s_s2[tid]);
    }
}

// ---------------- final BN + leaky + pair mean, unchanged ----------------
__global__ __launch_bounds__(TPB) void final_k(const float* __restrict__ gout,
                                               const float* __restrict__ raw,
                                               const float* __restrict__ g,
                                               const float* __restrict__ b,
                                               float* __restrict__ out)
{
    long idx = (long)blockIdx.x * TPB + threadIdx.x;
    if (idx >= 2359296L) return;
    int o = (int)(idx & 63);
    long t = idx >> 6;
    int n = (int)(t & 63);
    long t2 = t >> 6;
    long wd = t2 % 36;
    long bb = t2 / 36;
    const float invN = 1.0f / 73728.0f;
    float m = raw[o] * invN;
    float var = raw[64 + o] * invN - m * m;
    float scale = g[o] * rsqrtf(var + 1e-5f);
    float shift = b[o] - m * scale;
    long bp = bb * 72 + wd * 2;
    float v0 = gout[(bp * 64 + n) * 64 + o] * scale + shift;
    float v1 = gout[((bp + 1) * 64 + n) * 64 + o] * scale + shift;
    v0 = v0 > 0.f ? v0 : 0.01f * v0;
    v1 = v1 > 0.f ? v1 : 0.01f * v1;
    out[idx] = 0.5f * (v0 + v1);
}

// ---------------------------------------------------------------------------
extern "C" void kernel_launch(void* const* d_in, const int* in_sizes, int n_in,
                              void* d_out, int out_size, void* d_ws, size_t ws_size,
                              hipStream_t stream)
{
    (void)in_sizes; (void)n_in; (void)out_size;
    const float* x    = (const float*)d_in[0];
    const float* c1w  = (const float*)d_in[1];
    const float* g1   = (const float*)d_in[2];
    const float* b1   = (const float*)d_in[3];
    const float* c2w  = (const float*)d_in[4];
    const float* g2   = (const float*)d_in[5];
    const float* b2   = (const float*)d_in[6];
    const float* c3w  = (const float*)d_in[7];
    const float* g3   = (const float*)d_in[8];
    const float* b3   = (const float*)d_in[9];
    const float* mapw = (const float*)d_in[10];
    const float* mapb = (const float*)d_in[11];
    const float* thw  = (const float*)d_in[12];
    const float* thb  = (const float*)d_in[13];
    const float* bng  = (const float*)d_in[14];
    const float* bnb  = (const float*)d_in[15];
    float* out = (float*)d_out;
    float* ws  = (float*)d_ws;

    // ws_size is constant across calls -> identical launch sequence every call.
    const size_t WSPLIT_USHORT = 540672;    // conv + map/theta split weights
    const size_t MONO_BYTES = ((size_t)33816576 + 8650752 + ST_FLOATS) * 4
                              + WSPLIT_USHORT * 2;
    int nch = (ws_size >= MONO_BYTES) ? 1 : 2;
    size_t P1SZ = (size_t)(nch == 1 ? 1024 : 512) * 33024;   // [bz][129][256]

    float* P1   = ws;                       // pooled-RAW conv1, [bz][129][256]
    float* P2   = ws + P1SZ;                // pooled-RAW conv2, [1024][66][128]
    float* SPA  = ws;                       // pooled-RAW conv3, [1152][64][128] (P1 dead)
    float* GOUT = ws + 9437184;             // [1152][64][64]  (after SPA, inside P1)
    float* ST   = ws + P1SZ + 8650752;
    unsigned short* WB  = (unsigned short*)(ST + ST_FLOATS);
    unsigned short* WH1 = WB;               // [3][256][64]
    unsigned short* WL1 = WB + 49152;
    unsigned short* WH2 = WB + 98304;       // [3][128][256]
    unsigned short* WL2 = WB + 196608;
    unsigned short* WH3 = WB + 294912;      // [3][256][128]
    unsigned short* WL3 = WB + 393216;
    unsigned short* WMH = WB + 491520;      // [128][128]
    unsigned short* WML = WB + 507904;
    unsigned short* THH = WB + 524288;      // [64][128]
    unsigned short* THL = WB + 532480;

    hipMemsetAsync((void*)ST, 0, ST_FLOATS * sizeof(float), stream);
    split_w_k<<<192, TPB, 0, stream>>>(c1w, WH1, WL1, 256, 64);
    split_w_k<<<384, TPB, 0, stream>>>(c2w, WH2, WL2, 128, 256);
    split_w_k<<<384, TPB, 0, stream>>>(c3w, WH3, WL3, 256, 128);
    split_lin_k<<<64, TPB, 0, stream>>>(mapw, WMH, WML, 16384);
    split_lin_k<<<32, TPB, 0, stream>>>(thw, THH, THL, 8192);

    if (nch == 1) {
        mconv_k<0, 3, 0, 4><<<dim3(1, 1, 1024), TPB, 0, stream>>>(
            x, WH1, WL1, nullptr, P1, ST + RAW1,
            64, 256, 256, 1, 256, 129, 5, 1024, 0, 0);
        bn_fin_k<<<1, TPB, 0, stream>>>(ST + RAW1, g1, b1, ST + FIN1, 256, 1.0f / 262144.0f);
        mconv_k<1, 3, 1, 2><<<dim3(1, 1, 1024), TPB, 0, stream>>>(
            P1, WH2, WL2, ST + FIN1, P2, ST + RAW2,
            256, 128, 129, 2, 131, 66, 3, 1024, 0, 0);
    } else {
        mconv_k<0, 3, 0, 4><<<dim3(1, 1, 1024), TPB, 0, stream>>>(
            x, WH1, WL1, nullptr, P1, ST + RAW1,
            64, 256, 256, 1, 256, 129, 5, 512, 0, 0);
        bn_fin_k<<<1, TPB, 0, stream>>>(ST + RAW1, g1, b1, ST + FIN1, 256, 1.0f / 262144.0f);
        mconv_k<1, 3, 1, 2><<<dim3(1, 1, 512), TPB, 0, stream>>>(
            P1, WH2, WL2, ST + FIN1, P2, ST + RAW2,
            256, 128, 129, 2, 131, 66, 3, 512, 0, 0);
        mconv_k<0, 5, 0, 4><<<dim3(1, 1, 512), TPB, 0, stream>>>(
            x, WH1, WL1, nullptr, P1, nullptr,
            64, 256, 256, 1, 256, 129, 5, 512, 512, 0);
        mconv_k<1, 3, 1, 2><<<dim3(1, 1, 512), TPB, 0, stream>>>(
            P1, WH2, WL2, ST + FIN1, P2, ST + RAW2,
            256, 128, 129, 2, 131, 66, 3, 512, 0, 512);
    }
    bn_fin_k<<<1, TPB, 0, stream>>>(ST + RAW2, g2, b2, ST + FIN2, 128, 1.0f / 134144.0f);

    mconv_k<1, 4, 1, 4><<<dim3(1, 1, 1024), TPB, 0, stream>>>(
        P2, WH3, WL3, ST + FIN2, SPA, ST + RAW3,
        128, 256, 66, 3, 70, 36, 2, 1024, 0, 0);
    bn_fin_k<<<1, TPB, 0, stream>>>(ST + RAW3, g3, b3, ST + FIN3, 256, 1.0f / 71680.0f);

    // ---- fused graph stage (gemm_nf + adj/softmax + G + out + stats) ----
    graph_f_k<<<1152, TPB, 0, stream>>>(SPA, ST + FIN3, WMH, WML, mapb,
                                        THH, THL, thb, GOUT, ST + RAWG);
    final_k<<<9216, TPB, 0, stream>>>(GOUT, ST + RAWG, bng, bnb, out);
}

// Round 7
// 743.358 us; speedup vs baseline: 1.0292x; 1.0292x over previous
//
#include <hip/hip_runtime.h>

// ---------------------------------------------------------------------------
// MPNN_block_seperate — MFMA split-bf16 conv path + MFMA fused graph stage, v7.
// v6 post-mortem: explicit LDS double-buffer + 1-block-per-bz collapsed
// occupancy (21%, 765us) — classic dbuf-vs-occupancy loss.  v7 reverts to the
// v5 structure (grid.x = l-tiles, single 19KB LDS buffer, 694us) and adds:
// (1) register prefetch: LOAD(c+1) issues before MFMA(c), staging split into
//     load-early/write-late with NO extra LDS and NO grid change;
// (2) graph_f_k: Gt buffers alias the NF LDS (dead after P2; one extra
//     barrier) -> LDS 66->51KB, 2->3 blocks/CU.
// Conv arithmetic identical to v5 -> bit-identical results.
// ---------------------------------------------------------------------------

#define TPB 256

// stats block offsets (floats)
#define RAW1 0
#define FIN1 512
#define RAW2 1024
#define FIN2 1280
#define RAW3 1536
#define FIN3 2048
#define RAWG 2560
#define ST_FLOATS 2688

typedef __attribute__((ext_vector_type(8))) short bf16x8;
typedef __attribute__((ext_vector_type(4))) float f32x4;

union U8 { unsigned u[4]; bf16x8 v; };

__device__ __forceinline__ unsigned short bf16tr(float x) {
    return (unsigned short)(__float_as_uint(x) >> 16);
}
__device__ __forceinline__ float bf16tof(unsigned short h) {
    return __uint_as_float(((unsigned int)h) << 16);
}
__device__ __forceinline__ void split2(float a, float b, unsigned& h, unsigned& l) {
    unsigned short ha = bf16tr(a), hb = bf16tr(b);
    unsigned short la = bf16tr(a - bf16tof(ha)), lb = bf16tr(b - bf16tof(hb));
    h = (unsigned)ha | ((unsigned)hb << 16);
    l = (unsigned)la | ((unsigned)lb << 16);
}

// ---- one-time weight split: w[co][ci][k] (fp32) -> wh/wl [k][CO][CI] bf16 ----
__global__ __launch_bounds__(TPB) void split_w_k(const float* __restrict__ w,
                                                 unsigned short* __restrict__ wh,
                                                 unsigned short* __restrict__ wl,
                                                 int CO, int CI)
{
    int idx = blockIdx.x * TPB + threadIdx.x;
    if (idx >= CO * CI * 3) return;
    int ci = idx % CI; int rest = idx / CI; int co = rest % CO; int k = rest / CO;
    float v = w[((size_t)co * CI + ci) * 3 + k];
    unsigned short h = bf16tr(v);
    unsigned short l = bf16tr(v - bf16tof(h));
    wh[idx] = h; wl[idx] = l;
}

// ---- linear split (identity layout) for map_w / theta_w ----
__global__ __launch_bounds__(TPB) void split_lin_k(const float* __restrict__ w,
                                                   unsigned short* __restrict__ wh,
                                                   unsigned short* __restrict__ wl,
                                                   int n)
{
    int i = blockIdx.x * TPB + threadIdx.x;
    if (i >= n) return;
    float v = w[i];
    unsigned short h = bf16tr(v);
    wh[i] = h; wl[i] = bf16tr(v - bf16tof(h));
}

// ---------------------------------------------------------------------------
// MFMA conv core, v5 structure + register prefetch.
// Tile: FULL CO x 64 l per block (grid.x = tile).  4 waves, wave owns CF*16 co.
//   LAYOUT 0: input x [16][256][64][64]; row l at base[l*4096 + ci]
//   LAYOUT 1: input [bz][Lin][CI] row-major
//   STAGEBN:  staging applies relu(v*finIn[ci] + finIn[CI+ci])
//   MODE 3: stats + pooled-RAW -> out[bn0o+bz][j][co]   (store if bz < bzStore)
//   MODE 4: stats + pooled-RAW -> SPA [bq][72][64][128]
//   MODE 5: pooled-RAW only    -> out[bn0o+bz][j][co]
// Per chunk: sync; WRITE(c) regs->LDS; sync; LOAD(c+1) (issue early); MFMA(c).
// ---------------------------------------------------------------------------
template<int LAYOUT, int MODE, int STAGEBN, int CF>
__global__ __launch_bounds__(TPB) void mconv_k(const float* __restrict__ in,
                                               const unsigned short* __restrict__ wh,
                                               const unsigned short* __restrict__ wl,
                                               const float* __restrict__ finIn,
                                               float* __restrict__ out,
                                               float* __restrict__ raw,
                                               int CI, int CO, int Lin, int pad,
                                               int Lconv, int Lp,
                                               int bzStore, int bn0x, int bn0o)
{
    __shared__ __align__(16) unsigned short Xh[66 * 72];
    __shared__ __align__(16) unsigned short Xl[66 * 72];
    __shared__ float s_s1[256], s_s2[256];
    constexpr bool STATS = (MODE == 3 || MODE == 4);

    int tid  = threadIdx.x;
    int lane = tid & 63;
    int w    = tid >> 6;
    int g16  = lane >> 4;
    int l16  = lane & 15;
    int wbase = w * (CF * 16);
    int bz   = blockIdx.z;
    int Lbase = (int)blockIdx.x * 64 - 1;
    int gbase = Lbase - pad;            // staged row r <-> input position gbase + r

    const float* base;
    int RS;
    if (LAYOUT == 0) {
        int bn = bn0x + bz;
        base = in + (size_t)(bn >> 6) * 1048576 + (size_t)(bn & 63) * 64;
        RS = 4096;
    } else {
        base = in + (size_t)bz * CI * Lin;
        RS = CI;
    }

    if (STATS && tid < CO) { s_s1[tid] = 0.f; s_s2[tid] = 0.f; }

    const int NC = CI >> 5;

    // staging thread mapping: item0 = idx tid, item1 = idx tid+256 (tid<8 only)
    int r0 = tid >> 2, q0 = tid & 3;
    bool has1 = (tid < 8);
    int r1 = (tid + 256) >> 2, q1 = tid & 3;
    float v0[8], v1[8];

    auto LOAD1 = [&](float* v, int r, int q, int c) {
        int gl = gbase + r;
        if (gl >= 0 && gl < Lin) {
            const float* p = base + (size_t)gl * RS + c * 32 + 8 * q;
            float4 a = *(const float4*)p, b4 = *(const float4*)(p + 4);
            v[0] = a.x;  v[1] = a.y;  v[2] = a.z;  v[3] = a.w;
            v[4] = b4.x; v[5] = b4.y; v[6] = b4.z; v[7] = b4.w;
        } else {
#pragma unroll
            for (int j = 0; j < 8; j++) v[j] = 0.f;
        }
    };
    auto LOAD = [&](int c) {
        LOAD1(v0, r0, q0, c);
        if (has1) LOAD1(v1, r1, q1, c);
    };
    auto WRITE1 = [&](float* v, int r, int q, int c) {
        if (STAGEBN) {
            int gl = gbase + r;
            if (gl >= 0 && gl < Lin) {
                const float* sc = finIn + c * 32 + 8 * q;
                const float* sh = finIn + CI + c * 32 + 8 * q;
                float4 s0 = *(const float4*)sc, s1 = *(const float4*)(sc + 4);
                float4 h0 = *(const float4*)sh, h1 = *(const float4*)(sh + 4);
                v[0] = fmaxf(v[0] * s0.x + h0.x, 0.f);
                v[1] = fmaxf(v[1] * s0.y + h0.y, 0.f);
                v[2] = fmaxf(v[2] * s0.z + h0.z, 0.f);
                v[3] = fmaxf(v[3] * s0.w + h0.w, 0.f);
                v[4] = fmaxf(v[4] * s1.x + h1.x, 0.f);
                v[5] = fmaxf(v[5] * s1.y + h1.y, 0.f);
                v[6] = fmaxf(v[6] * s1.z + h1.z, 0.f);
                v[7] = fmaxf(v[7] * s1.w + h1.w, 0.f);
            }
        }
        uint4 hu, lu;
        split2(v[0], v[1], hu.x, lu.x);
        split2(v[2], v[3], hu.y, lu.y);
        split2(v[4], v[5], hu.z, lu.z);
        split2(v[6], v[7], hu.w, lu.w);
        *(uint4*)&Xh[r * 72 + 8 * q] = hu;
        *(uint4*)&Xl[r * 72 + 8 * q] = lu;
    };
    auto WRITE = [&](int c) {
        WRITE1(v0, r0, q0, c);
        if (has1) WRITE1(v1, r1, q1, c);
    };

    f32x4 acc[CF][4];
#pragma unroll
    for (int cf = 0; cf < CF; cf++)
#pragma unroll
        for (int nf = 0; nf < 4; nf++) {
            f32x4 z = {0.f, 0.f, 0.f, 0.f};
            acc[cf][nf] = z;
        }

    LOAD(0);
    for (int c = 0; c < NC; c++) {
        __syncthreads();
        WRITE(c);
        __syncthreads();
        if (c + 1 < NC) LOAD(c + 1);     // issue next chunk's loads early

        int ci0 = c * 32;
#pragma unroll
        for (int k = 0; k < 3; k++) {
            bf16x8 ah[CF], al[CF];
#pragma unroll
            for (int cf = 0; cf < CF; cf++) {
                size_t wof = ((size_t)(k * CO + wbase + cf * 16 + l16)) * CI
                             + ci0 + g16 * 8;
                ah[cf] = *(const bf16x8*)(wh + wof);
                al[cf] = *(const bf16x8*)(wl + wof);
            }
#pragma unroll
            for (int nf = 0; nf < 4; nf++) {
                if (Lbase + nf * 16 >= Lconv) continue;   // dead fragment
                int rb = nf * 16 + l16 + k;
                bf16x8 bh = *(const bf16x8*)&Xh[rb * 72 + g16 * 8];
                bf16x8 bl = *(const bf16x8*)&Xl[rb * 72 + g16 * 8];
#pragma unroll
                for (int cf = 0; cf < CF; cf++) {
                    acc[cf][nf] = __builtin_amdgcn_mfma_f32_16x16x32_bf16(
                        ah[cf], bh, acc[cf][nf], 0, 0, 0);
                    acc[cf][nf] = __builtin_amdgcn_mfma_f32_16x16x32_bf16(
                        ah[cf], bl, acc[cf][nf], 0, 0, 0);
                    acc[cf][nf] = __builtin_amdgcn_mfma_f32_16x16x32_bf16(
                        al[cf], bh, acc[cf][nf], 0, 0, 0);
                }
            }
        }
    }

    // ---- stats partials ----
    if (STATS) {
#pragma unroll
        for (int cf = 0; cf < CF; cf++)
#pragma unroll
            for (int rg = 0; rg < 4; rg++) {
                float a = 0.f, b = 0.f;
#pragma unroll
                for (int nf = 0; nf < 4; nf++) {
                    int l = Lbase + nf * 16 + l16;
                    if (l >= 0 && l < Lconv) {
                        float v = acc[cf][nf][rg];
                        a += v; b += v * v;
                    }
                }
#pragma unroll
                for (int m = 1; m < 16; m <<= 1) {
                    a += __shfl_xor(a, m); b += __shfl_xor(b, m);
                }
                if (l16 == 0) {
                    atomicAdd(&s_s1[wbase + cf * 16 + g16 * 4 + rg], a);
                    atomicAdd(&s_s2[wbase + cf * 16 + g16 * 4 + rg], b);
                }
            }
    }

    // ---- pooled-RAW store ----
    if ((MODE == 3 || MODE == 5) && bz < bzStore) {
#pragma unroll
        for (int cf = 0; cf < CF; cf++)
#pragma unroll
            for (int nf = 0; nf < 4; nf++) {
                int l = Lbase + nf * 16 + l16;
                bool ok = (l >= 0 && l < Lconv);
                float4 pv;
#pragma unroll
                for (int rg = 0; rg < 4; rg++) {
                    float v = ok ? acc[cf][nf][rg] : -3.0e38f;
                    float vv = __shfl_xor(v, 1);
                    ((float*)&pv)[rg] = fmaxf(v, vv);
                }
                int j = (l + 1) >> 1;
                if (!(lane & 1) && j < Lp)
                    *(float4*)&out[((size_t)(bn0o + bz) * Lp + j) * CO
                                   + wbase + cf * 16 + g16 * 4] = pv;
            }
    }
    if (MODE == 4) {
#pragma unroll
        for (int cf = 0; cf < CF; cf++)
#pragma unroll
            for (int nf = 0; nf < 4; nf++) {
                int l = Lbase + nf * 16 + l16;
                bool ok = (l >= 0 && l < Lconv);
                int j = (l + 1) >> 1;
#pragma unroll
                for (int rg = 0; rg < 4; rg++) {
                    float v = ok ? acc[cf][nf][rg] : -3.0e38f;
                    float vv = __shfl_xor(v, 1);
                    if (!(lane & 1) && j < Lp) {
                        float pv = fmaxf(v, vv);
                        int co = wbase + cf * 16 + g16 * 4 + rg;
                        int lin = co * 36 + j;
                        int tc = lin >> 7, f = lin & 127;
                        int bq = bz >> 6, n = bz & 63;
                        out[(((size_t)bq * 72 + tc) * 64 + n) * 128 + f] = pv;
                    }
                }
            }
    }

    if (STATS) {
        __syncthreads();
        if (tid < CO) {
            atomicAdd(&raw[tid], s_s1[tid]);
            atomicAdd(&raw[CO + tid], s_s2[tid]);
        }
    }
}

// fin[c] = scale = g*rsqrt(var+eps);  fin[C+c] = shift = b - mean*scale
__global__ __launch_bounds__(TPB) void bn_fin_k(const float* __restrict__ raw,
                                                const float* __restrict__ g,
                                                const float* __restrict__ b,
                                                float* __restrict__ fin, int C, float invN)
{
    int c = threadIdx.x + blockIdx.x * TPB;
    if (c < C) {
        float m = raw[c] * invN;
        float v = raw[C + c] * invN - m * m;
        float sc = g[c] * rsqrtf(v + 1e-5f);
        fin[c] = sc;
        fin[C + c] = b[c] - m * sc;
    }
}

// ---------------------------------------------------------------------------
// Fused graph stage on MFMA.  v7: Gt aliases NF LDS (dead after P2) -> LDS
// 66->51KB, 3 blocks/CU.  One extra barrier between P2 and P3.
// ---------------------------------------------------------------------------
#define AJX(n,m) s_adj[(((n) * 64 + (m)) ^ (((n) & 7) << 3))]

__global__ __launch_bounds__(TPB) void graph_f_k(const float* __restrict__ spa,
                                                 const float* __restrict__ fin3,
                                                 const unsigned short* __restrict__ wmh,
                                                 const unsigned short* __restrict__ wml,
                                                 const float* __restrict__ mapb,
                                                 const unsigned short* __restrict__ thh,
                                                 const unsigned short* __restrict__ thl,
                                                 const float* __restrict__ thb,
                                                 float* __restrict__ gout,
                                                 float* __restrict__ rawg)
{
    __shared__ __align__(16) char smem[49152];
    unsigned short* NFh = (unsigned short*)smem;             // [64][128] swz, 16KB
    unsigned short* NFl = (unsigned short*)(smem + 16384);   // 16KB
    float* s_adj        = (float*)(smem + 32768);            // [64][64] swz, 16KB
    unsigned short* Gth = (unsigned short*)smem;             // alias NFh (dead)
    unsigned short* Gtl = (unsigned short*)(smem + 16384);   // alias NFl (dead)
    __shared__ float s_red[256], s_rmax[64], s_rsum[64], s_s1[64], s_s2[64];

    int tid  = threadIdx.x;
    int lane = tid & 63;
    int w    = tid >> 6;
    int g16  = lane >> 4, l16 = lane & 15;
    int n0   = w * 16;
    int bp   = blockIdx.x;
    int tcb  = (bp % 72) * 128;

    if (tid < 64) { s_s1[tid] = 0.f; s_s2[tid] = 0.f; }

    // ---- P0: A = relu(bn3(spa)) for rows n0+l16 -> registers (split bf16) ----
    unsigned aH[16], aL[16];
    {
        const float* ar = spa + ((size_t)bp * 64 + n0 + l16) * 128;
#pragma unroll
        for (int kc = 0; kc < 4; kc++) {
            int kb = kc * 32 + g16 * 8;
            float4 x0 = *(const float4*)(ar + kb);
            float4 x1 = *(const float4*)(ar + kb + 4);
            float v[8] = {x0.x, x0.y, x0.z, x0.w, x1.x, x1.y, x1.z, x1.w};
#pragma unroll
            for (int j = 0; j < 8; j++) {
                int co = ((tcb + kb + j) * 29128) >> 20;   // exact /36 for x<32768
                float z = v[j] * fin3[co] + fin3[256 + co];
                v[j] = z > 0.f ? z : 0.f;
            }
            split2(v[0], v[1], aH[kc*4+0], aL[kc*4+0]);
            split2(v[2], v[3], aH[kc*4+1], aL[kc*4+1]);
            split2(v[4], v[5], aH[kc*4+2], aL[kc*4+2]);
            split2(v[6], v[7], aH[kc*4+3], aL[kc*4+3]);
        }
    }

    // ---- P1: nf = A @ map_w^T + mapb  -> NFh/NFl ----
    {
        f32x4 acc[8];
#pragma unroll
        for (int i = 0; i < 8; i++) { f32x4 z = {0.f,0.f,0.f,0.f}; acc[i] = z; }
#pragma unroll
        for (int ff = 0; ff < 8; ff++) {
#pragma unroll
            for (int kc = 0; kc < 4; kc++) {
                U8 ah, al;
#pragma unroll
                for (int u = 0; u < 4; u++) { ah.u[u] = aH[kc*4+u]; al.u[u] = aL[kc*4+u]; }
                size_t wo = (size_t)(ff * 16 + l16) * 128 + kc * 32 + g16 * 8;
                bf16x8 bh = *(const bf16x8*)(wmh + wo);
                bf16x8 bl = *(const bf16x8*)(wml + wo);
                acc[ff] = __builtin_amdgcn_mfma_f32_16x16x32_bf16(ah.v, bh, acc[ff], 0, 0, 0);
                acc[ff] = __builtin_amdgcn_mfma_f32_16x16x32_bf16(ah.v, bl, acc[ff], 0, 0, 0);
                acc[ff] = __builtin_amdgcn_mfma_f32_16x16x32_bf16(al.v, bh, acc[ff], 0, 0, 0);
            }
        }
#pragma unroll
        for (int ff = 0; ff < 8; ff++) {
            float bv = mapb[ff * 16 + l16];
#pragma unroll
            for (int rg = 0; rg < 4; rg++) {
                int n = n0 + g16 * 4 + rg;
                float v = acc[ff][rg] + bv;
                int s = ((n * 128) + ff * 16 + l16) ^ ((n & 7) << 3);
                unsigned short h = bf16tr(v);
                NFh[s] = h;
                NFl[s] = bf16tr(v - bf16tof(h));
            }
        }
    }
    __syncthreads();

    // ---- preload this wave's NF rows (A-operand for adj and G) ----
    bf16x8 nh[4], nl[4];
#pragma unroll
    for (int kc = 0; kc < 4; kc++) {
        int r = n0 + l16;
        int s = ((r * 128) + kc * 32 + g16 * 8) ^ ((r & 7) << 3);
        nh[kc] = *(const bf16x8*)&NFh[s];
        nl[kc] = *(const bf16x8*)&NFl[s];
    }

    // ---- P2: adj = nf @ nf^T  (diag -1e8, leaky) -> s_adj ----
    {
        f32x4 aj[4];
#pragma unroll
        for (int i = 0; i < 4; i++) { f32x4 z = {0.f,0.f,0.f,0.f}; aj[i] = z; }
#pragma unroll
        for (int mf = 0; mf < 4; mf++) {
#pragma unroll
            for (int kc = 0; kc < 4; kc++) {
                int r = mf * 16 + l16;
                int s = ((r * 128) + kc * 32 + g16 * 8) ^ ((r & 7) << 3);
                bf16x8 bh = *(const bf16x8*)&NFh[s];
                bf16x8 bl = *(const bf16x8*)&NFl[s];
                aj[mf] = __builtin_amdgcn_mfma_f32_16x16x32_bf16(nh[kc], bh, aj[mf], 0, 0, 0);
                aj[mf] = __builtin_amdgcn_mfma_f32_16x16x32_bf16(nh[kc], bl, aj[mf], 0, 0, 0);
                aj[mf] = __builtin_amdgcn_mfma_f32_16x16x32_bf16(nl[kc], bh, aj[mf], 0, 0, 0);
            }
        }
#pragma unroll
        for (int mf = 0; mf < 4; mf++)
#pragma unroll
            for (int rg = 0; rg < 4; rg++) {
                int n = n0 + g16 * 4 + rg, m = mf * 16 + l16;
                float v = aj[mf][rg];
                if (n == m) v -= 1e8f;
                v = v > 0.f ? v : 0.01f * v;
                AJX(n, m) = v;
            }
    }
    __syncthreads();   // all NF reads done before Gt overwrites the aliased LDS

    // ---- P3: G = nf @ theta^T -> Gt (transposed, split bf16; aliases NF) ----
    {
        f32x4 gg[4];
#pragma unroll
        for (int i = 0; i < 4; i++) { f32x4 z = {0.f,0.f,0.f,0.f}; gg[i] = z; }
#pragma unroll
        for (int of = 0; of < 4; of++) {
#pragma unroll
            for (int kc = 0; kc < 4; kc++) {
                size_t to = (size_t)(of * 16 + l16) * 128 + kc * 32 + g16 * 8;
                bf16x8 th_ = *(const bf16x8*)(thh + to);
                bf16x8 tl_ = *(const bf16x8*)(thl + to);
                gg[of] = __builtin_amdgcn_mfma_f32_16x16x32_bf16(nh[kc], th_, gg[of], 0, 0, 0);
                gg[of] = __builtin_amdgcn_mfma_f32_16x16x32_bf16(nh[kc], tl_, gg[of], 0, 0, 0);
                gg[of] = __builtin_amdgcn_mfma_f32_16x16x32_bf16(nl[kc], th_, gg[of], 0, 0, 0);
            }
        }
#pragma unroll
        for (int of = 0; of < 4; of++) {
            unsigned short hs[4], ls[4];
#pragma unroll
            for (int rg = 0; rg < 4; rg++) {
                float v = gg[of][rg];
                hs[rg] = bf16tr(v);
                ls[rg] = bf16tr(v - bf16tof(hs[rg]));
            }
            int o = of * 16 + l16;
            int m = n0 + g16 * 4;            // 4 consecutive m
            int s = ((o * 64) + m) ^ ((o & 7) << 3);
            uint2 hp, lp;
            hp.x = (unsigned)hs[0] | ((unsigned)hs[1] << 16);
            hp.y = (unsigned)hs[2] | ((unsigned)hs[3] << 16);
            lp.x = (unsigned)ls[0] | ((unsigned)ls[1] << 16);
            lp.y = (unsigned)ls[2] | ((unsigned)ls[3] << 16);
            *(uint2*)&Gth[s] = hp;
            *(uint2*)&Gtl[s] = lp;
        }
    }
    __syncthreads();

    // ---- P4: row softmax + I on s_adj ----
    {
        int n = tid >> 2, q = tid & 3;
        float mx = -3.0e38f;
        for (int m = q * 16; m < q * 16 + 16; m++) mx = fmaxf(mx, AJX(n, m));
        s_red[n * 4 + q] = mx;
    }
    __syncthreads();
    if (tid < 64)
        s_rmax[tid] = fmaxf(fmaxf(s_red[tid * 4], s_red[tid * 4 + 1]),
                            fmaxf(s_red[tid * 4 + 2], s_red[tid * 4 + 3]));
    __syncthreads();
    {
        int n = tid >> 2, q = tid & 3;
        float mx = s_rmax[n];
        float sm = 0.f;
        for (int m = q * 16; m < q * 16 + 16; m++) {
            float e = __expf(AJX(n, m) - mx);
            AJX(n, m) = e;
            sm += e;
        }
        s_red[n * 4 + q] = sm;
    }
    __syncthreads();
    if (tid < 64)
        s_rsum[tid] = 1.0f / (s_red[tid * 4] + s_red[tid * 4 + 1] +
                              s_red[tid * 4 + 2] + s_red[tid * 4 + 3]);
    __syncthreads();
    {
        int n = tid >> 2, q = tid & 3;
        float inv = s_rsum[n];
        for (int m = q * 16; m < q * 16 + 16; m++)
            AJX(n, m) = AJX(n, m) * inv + ((n == m) ? 1.f : 0.f);
    }
    __syncthreads();

    // ---- P5: out = adjS @ G + thb -> gout, fused stats ----
    {
        f32x4 oacc[4];
#pragma unroll
        for (int i = 0; i < 4; i++) { f32x4 z = {0.f,0.f,0.f,0.f}; oacc[i] = z; }
#pragma unroll
        for (int kc = 0; kc < 2; kc++) {
            int r = n0 + l16;
            int sf = ((r * 64) + kc * 32 + g16 * 8) ^ ((r & 7) << 3);
            float4 p0 = *(const float4*)&s_adj[sf];
            float4 p1 = *(const float4*)&s_adj[sf + 4];
            U8 ah, al;
            split2(p0.x, p0.y, ah.u[0], al.u[0]);
            split2(p0.z, p0.w, ah.u[1], al.u[1]);
            split2(p1.x, p1.y, ah.u[2], al.u[2]);
            split2(p1.z, p1.w, ah.u[3], al.u[3]);
#pragma unroll
            for (int of = 0; of < 4; of++) {
                int o = of * 16 + l16;
                int s = ((o * 64) + kc * 32 + g16 * 8) ^ ((o & 7) << 3);
                bf16x8 gh = *(const bf16x8*)&Gth[s];
                bf16x8 gl = *(const bf16x8*)&Gtl[s];
                oacc[of] = __builtin_amdgcn_mfma_f32_16x16x32_bf16(ah.v, gh, oacc[of], 0, 0, 0);
                oacc[of] = __builtin_amdgcn_mfma_f32_16x16x32_bf16(ah.v, gl, oacc[of], 0, 0, 0);
                oacc[of] = __builtin_amdgcn_mfma_f32_16x16x32_bf16(al.v, gh, oacc[of], 0, 0, 0);
            }
        }
        float* gb = gout + (size_t)bp * 4096;
#pragma unroll
        for (int of = 0; of < 4; of++) {
            float tb = thb[of * 16 + l16];
            float a = 0.f, b = 0.f;
#pragma unroll
            for (int rg = 0; rg < 4; rg++) {
                int n = n0 + g16 * 4 + rg;
                float v = oacc[of][rg] + tb;
                gb[n * 64 + of * 16 + l16] = v;
                a += v; b += v * v;
            }
            a += __shfl_xor(a, 16); a += __shfl_xor(a, 32);
            b += __shfl_xor(b, 16); b += __shfl_xor(b, 32);
            if (g16 == 0) {
                atomicAdd(&s_s1[of * 16 + l16], a);
                atomicAdd(&s_s2[of * 16 + l16], b);
            }
        }
    }
    __syncthreads();
    if (tid < 64) {
        atomicAdd(&rawg[tid], s_s1[tid]);
        atomicAdd(&rawg[64 + tid], s_s2[tid]);
    }
}

// ---------------- final BN + leaky + pair mean, unchanged ----------------
__global__ __launch_bounds__(TPB) void final_k(const float* __restrict__ gout,
                                               const float* __restrict__ raw,
                                               const float* __restrict__ g,
                                               const float* __restrict__ b,
                                               float* __restrict__ out)
{
    long idx = (long)blockIdx.x * TPB + threadIdx.x;
    if (idx >= 2359296L) return;
    int o = (int)(idx & 63);
    long t = idx >> 6;
    int n = (int)(t & 63);
    long t2 = t >> 6;
    long wd = t2 % 36;
    long bb = t2 / 36;
    const float invN = 1.0f / 73728.0f;
    float m = raw[o] * invN;
    float var = raw[64 + o] * invN - m * m;
    float scale = g[o] * rsqrtf(var + 1e-5f);
    float shift = b[o] - m * scale;
    long bp = bb * 72 + wd * 2;
    float v0 = gout[(bp * 64 + n) * 64 + o] * scale + shift;
    float v1 = gout[((bp + 1) * 64 + n) * 64 + o] * scale + shift;
    v0 = v0 > 0.f ? v0 : 0.01f * v0;
    v1 = v1 > 0.f ? v1 : 0.01f * v1;
    out[idx] = 0.5f * (v0 + v1);
}

// ---------------------------------------------------------------------------
extern "C" void kernel_launch(void* const* d_in, const int* in_sizes, int n_in,
                              void* d_out, int out_size, void* d_ws, size_t ws_size,
                              hipStream_t stream)
{
    (void)in_sizes; (void)n_in; (void)out_size;
    const float* x    = (const float*)d_in[0];
    const float* c1w  = (const float*)d_in[1];
    const float* g1   = (const float*)d_in[2];
    const float* b1   = (const float*)d_in[3];
    const float* c2w  = (const float*)d_in[4];
    const float* g2   = (const float*)d_in[5];
    const float* b2   = (const float*)d_in[6];
    const float* c3w  = (const float*)d_in[7];
    const float* g3   = (const float*)d_in[8];
    const float* b3   = (const float*)d_in[9];
    const float* mapw = (const float*)d_in[10];
    const float* mapb = (const float*)d_in[11];
    const float* thw  = (const float*)d_in[12];
    const float* thb  = (const float*)d_in[13];
    const float* bng  = (const float*)d_in[14];
    const float* bnb  = (const float*)d_in[15];
    float* out = (float*)d_out;
    float* ws  = (float*)d_ws;

    // ws_size is constant across calls -> identical launch sequence every call.
    const size_t WSPLIT_USHORT = 540672;    // conv + map/theta split weights
    const size_t MONO_BYTES = ((size_t)33816576 + 8650752 + ST_FLOATS) * 4
                              + WSPLIT_USHORT * 2;
    int nch = (ws_size >= MONO_BYTES) ? 1 : 2;
    size_t P1SZ = (size_t)(nch == 1 ? 1024 : 512) * 33024;   // [bz][129][256]

    float* P1   = ws;                       // pooled-RAW conv1, [bz][129][256]
    float* P2   = ws + P1SZ;                // pooled-RAW conv2, [1024][66][128]
    float* SPA  = ws;                       // pooled-RAW conv3, [1152][64][128] (P1 dead)
    float* GOUT = ws + 9437184;             // [1152][64][64]  (after SPA, inside P1)
    float* ST   = ws + P1SZ + 8650752;
    unsigned short* WB  = (unsigned short*)(ST + ST_FLOATS);
    unsigned short* WH1 = WB;               // [3][256][64]
    unsigned short* WL1 = WB + 49152;
    unsigned short* WH2 = WB + 98304;       // [3][128][256]
    unsigned short* WL2 = WB + 196608;
    unsigned short* WH3 = WB + 294912;      // [3][256][128]
    unsigned short* WL3 = WB + 393216;
    unsigned short* WMH = WB + 491520;      // [128][128]
    unsigned short* WML = WB + 507904;
    unsigned short* THH = WB + 524288;      // [64][128]
    unsigned short* THL = WB + 532480;

    hipMemsetAsync((void*)ST, 0, ST_FLOATS * sizeof(float), stream);
    split_w_k<<<192, TPB, 0, stream>>>(c1w, WH1, WL1, 256, 64);
    split_w_k<<<384, TPB, 0, stream>>>(c2w, WH2, WL2, 128, 256);
    split_w_k<<<384, TPB, 0, stream>>>(c3w, WH3, WL3, 256, 128);
    split_lin_k<<<64, TPB, 0, stream>>>(mapw, WMH, WML, 16384);
    split_lin_k<<<32, TPB, 0, stream>>>(thw, THH, THL, 8192);

    if (nch == 1) {
        mconv_k<0, 3, 0, 4><<<dim3(5, 1, 1024), TPB, 0, stream>>>(
            x, WH1, WL1, nullptr, P1, ST + RAW1,
            64, 256, 256, 1, 256, 129, 1024, 0, 0);
        bn_fin_k<<<1, TPB, 0, stream>>>(ST + RAW1, g1, b1, ST + FIN1, 256, 1.0f / 262144.0f);
        mconv_k<1, 3, 1, 2><<<dim3(3, 1, 1024), TPB, 0, stream>>>(
            P1, WH2, WL2, ST + FIN1, P2, ST + RAW2,
            256, 128, 129, 2, 131, 66, 1024, 0, 0);
    } else {
        mconv_k<0, 3, 0, 4><<<dim3(5, 1, 1024), TPB, 0, stream>>>(
            x, WH1, WL1, nullptr, P1, ST + RAW1,
            64, 256, 256, 1, 256, 129, 512, 0, 0);
        bn_fin_k<<<1, TPB, 0, stream>>>(ST + RAW1, g1, b1, ST + FIN1, 256, 1.0f / 262144.0f);
        mconv_k<1, 3, 1, 2><<<dim3(3, 1, 512), TPB, 0, stream>>>(
            P1, WH2, WL2, ST + FIN1, P2, ST + RAW2,
            256, 128, 129, 2, 131, 66, 512, 0, 0);
        mconv_k<0, 5, 0, 4><<<dim3(5, 1, 512), TPB, 0, stream>>>(
            x, WH1, WL1, nullptr, P1, nullptr,
            64, 256, 256, 1, 256, 129, 512, 512, 0);
        mconv_k<1, 3, 1, 2><<<dim3(3, 1, 512), TPB, 0, stream>>>(
            P1, WH2, WL2, ST + FIN1, P2, ST + RAW2,
            256, 128, 129, 2, 131, 66, 512, 0, 512);
    }
    bn_fin_k<<<1, TPB, 0, stream>>>(ST + RAW2, g2, b2, ST + FIN2, 128, 1.0f / 134144.0f);

    mconv_k<1, 4, 1, 4><<<dim3(2, 1, 1024), TPB, 0, stream>>>(
        P2, WH3, WL3, ST + FIN2, SPA, ST + RAW3,
        128, 256, 66, 3, 70, 36, 1024, 0, 0);
    bn_fin_k<<<1, TPB, 0, stream>>>(ST + RAW3, g3, b3, ST + FIN3, 256, 1.0f / 71680.0f);

    // ---- fused graph stage (gemm_nf + adj/softmax + G + out + stats) ----
    graph_f_k<<<1152, TPB, 0, stream>>>(SPA, ST + FIN3, WMH, WML, mapb,
                                        THH, THL, thb, GOUT, ST + RAWG);
    final_k<<<9216, TPB, 0, stream>>>(GOUT, ST + RAWG, bng, bnb, out);
}

// Round 8
// 701.260 us; speedup vs baseline: 1.0910x; 1.0600x over previous
//
#include <hip/hip_runtime.h>

// ---------------------------------------------------------------------------
// MPNN_block_seperate — MFMA split-bf16 conv path + MFMA fused graph stage, v8.
// v6 (LDS dbuf) and v7 (reg prefetch) both regressed by trading occupancy for
// pipeline depth (VGPR 72->96, occ 30->21%).  v8 = exact v5 conv structure
// (best known, 694us) + the one safe v7 improvement: graph_f_k's Gt buffers
// alias the NF LDS (dead after P2, barrier-protected) -> LDS 66->49KB,
// 2->3 blocks/CU on the latency-bound graph kernel.
// ---------------------------------------------------------------------------

#define TPB 256

// stats block offsets (floats)
#define RAW1 0
#define FIN1 512
#define RAW2 1024
#define FIN2 1280
#define RAW3 1536
#define FIN3 2048
#define RAWG 2560
#define ST_FLOATS 2688

typedef __attribute__((ext_vector_type(8))) short bf16x8;
typedef __attribute__((ext_vector_type(4))) float f32x4;

union U8 { unsigned u[4]; bf16x8 v; };

__device__ __forceinline__ unsigned short bf16tr(float x) {
    return (unsigned short)(__float_as_uint(x) >> 16);
}
__device__ __forceinline__ float bf16tof(unsigned short h) {
    return __uint_as_float(((unsigned int)h) << 16);
}
__device__ __forceinline__ void split2(float a, float b, unsigned& h, unsigned& l) {
    unsigned short ha = bf16tr(a), hb = bf16tr(b);
    unsigned short la = bf16tr(a - bf16tof(ha)), lb = bf16tr(b - bf16tof(hb));
    h = (unsigned)ha | ((unsigned)hb << 16);
    l = (unsigned)la | ((unsigned)lb << 16);
}

// ---- one-time weight split: w[co][ci][k] (fp32) -> wh/wl [k][CO][CI] bf16 ----
__global__ __launch_bounds__(TPB) void split_w_k(const float* __restrict__ w,
                                                 unsigned short* __restrict__ wh,
                                                 unsigned short* __restrict__ wl,
                                                 int CO, int CI)
{
    int idx = blockIdx.x * TPB + threadIdx.x;
    if (idx >= CO * CI * 3) return;
    int ci = idx % CI; int rest = idx / CI; int co = rest % CO; int k = rest / CO;
    float v = w[((size_t)co * CI + ci) * 3 + k];
    unsigned short h = bf16tr(v);
    unsigned short l = bf16tr(v - bf16tof(h));
    wh[idx] = h; wl[idx] = l;
}

// ---- linear split (identity layout) for map_w / theta_w ----
__global__ __launch_bounds__(TPB) void split_lin_k(const float* __restrict__ w,
                                                   unsigned short* __restrict__ wh,
                                                   unsigned short* __restrict__ wl,
                                                   int n)
{
    int i = blockIdx.x * TPB + threadIdx.x;
    if (i >= n) return;
    float v = w[i];
    unsigned short h = bf16tr(v);
    wh[i] = h; wl[i] = bf16tr(v - bf16tof(h));
}

// ---------------------------------------------------------------------------
// MFMA conv core (v5 structure, verbatim).  Tile: FULL CO x 64 l, 4 waves;
// wave owns CF*16 channels.
//   LAYOUT 0: input x [16][256][64][64]; row l at base[l*4096 + ci]
//   LAYOUT 1: input [bz][Lin][CI] row-major
//   STAGEBN:  staging applies relu(v*finIn[ci] + finIn[CI+ci])
//   MODE 3: stats + pooled-RAW -> out[bn0o+bz][j][co]   (store if bz < bzStore)
//   MODE 4: stats + pooled-RAW -> SPA [bq][72][64][128]
//   MODE 5: pooled-RAW only    -> out[bn0o+bz][j][co]
// ---------------------------------------------------------------------------
template<int LAYOUT, int MODE, int STAGEBN, int CF>
__global__ __launch_bounds__(TPB) void mconv_k(const float* __restrict__ in,
                                               const unsigned short* __restrict__ wh,
                                               const unsigned short* __restrict__ wl,
                                               const float* __restrict__ finIn,
                                               float* __restrict__ out,
                                               float* __restrict__ raw,
                                               int CI, int CO, int Lin, int pad,
                                               int Lconv, int Lp,
                                               int bzStore, int bn0x, int bn0o)
{
    __shared__ __align__(16) unsigned short Xh[66 * 72];
    __shared__ __align__(16) unsigned short Xl[66 * 72];
    __shared__ float s_s1[256], s_s2[256];
    constexpr bool STATS = (MODE == 3 || MODE == 4);

    int tid  = threadIdx.x;
    int lane = tid & 63;
    int w    = tid >> 6;
    int g16  = lane >> 4;
    int l16  = lane & 15;
    int wbase = w * (CF * 16);
    int bz   = blockIdx.z;
    int Lbase = (int)blockIdx.x * 64 - 1;
    int gbase = Lbase - pad;

    const float* base;
    int RS;
    if (LAYOUT == 0) {
        int bn = bn0x + bz;
        base = in + (size_t)(bn >> 6) * 1048576 + (size_t)(bn & 63) * 64;
        RS = 4096;
    } else {
        base = in + (size_t)bz * CI * Lin;
        RS = CI;
    }

    if (STATS && tid < CO) { s_s1[tid] = 0.f; s_s2[tid] = 0.f; }

    f32x4 acc[CF][4];
#pragma unroll
    for (int cf = 0; cf < CF; cf++)
#pragma unroll
        for (int nf = 0; nf < 4; nf++) {
            f32x4 z = {0.f, 0.f, 0.f, 0.f};
            acc[cf][nf] = z;
        }

    for (int ci0 = 0; ci0 < CI; ci0 += 32) {
        __syncthreads();
        for (int idx = tid; idx < 264; idx += TPB) {
            int r = idx >> 2, q = idx & 3;
            int gl = gbase + r;
            float4 va = {0.f, 0.f, 0.f, 0.f}, vb = {0.f, 0.f, 0.f, 0.f};
            if (gl >= 0 && gl < Lin) {
                const float* p = base + (size_t)gl * RS + ci0 + 8 * q;
                va = *(const float4*)p;
                vb = *(const float4*)(p + 4);
                if (STAGEBN) {
                    const float* sc = finIn + ci0 + 8 * q;
                    const float* sh = finIn + CI + ci0 + 8 * q;
                    float4 s0 = *(const float4*)sc, s1 = *(const float4*)(sc + 4);
                    float4 h0 = *(const float4*)sh, h1 = *(const float4*)(sh + 4);
                    va.x = fmaxf(va.x * s0.x + h0.x, 0.f);
                    va.y = fmaxf(va.y * s0.y + h0.y, 0.f);
                    va.z = fmaxf(va.z * s0.z + h0.z, 0.f);
                    va.w = fmaxf(va.w * s0.w + h0.w, 0.f);
                    vb.x = fmaxf(vb.x * s1.x + h1.x, 0.f);
                    vb.y = fmaxf(vb.y * s1.y + h1.y, 0.f);
                    vb.z = fmaxf(vb.z * s1.z + h1.z, 0.f);
                    vb.w = fmaxf(vb.w * s1.w + h1.w, 0.f);
                }
            }
            uint4 hu, lu;
            split2(va.x, va.y, hu.x, lu.x);
            split2(va.z, va.w, hu.y, lu.y);
            split2(vb.x, vb.y, hu.z, lu.z);
            split2(vb.z, vb.w, hu.w, lu.w);
            *(uint4*)&Xh[r * 72 + 8 * q] = hu;
            *(uint4*)&Xl[r * 72 + 8 * q] = lu;
        }
        __syncthreads();

#pragma unroll
        for (int k = 0; k < 3; k++) {
            bf16x8 ah[CF], al[CF];
#pragma unroll
            for (int cf = 0; cf < CF; cf++) {
                size_t wof = ((size_t)(k * CO + wbase + cf * 16 + l16)) * CI
                             + ci0 + g16 * 8;
                ah[cf] = *(const bf16x8*)(wh + wof);
                al[cf] = *(const bf16x8*)(wl + wof);
            }
#pragma unroll
            for (int nf = 0; nf < 4; nf++) {
                if (Lbase + nf * 16 >= Lconv) continue;
                int rb = nf * 16 + l16 + k;
                bf16x8 bh = *(const bf16x8*)&Xh[rb * 72 + g16 * 8];
                bf16x8 bl = *(const bf16x8*)&Xl[rb * 72 + g16 * 8];
#pragma unroll
                for (int cf = 0; cf < CF; cf++) {
                    acc[cf][nf] = __builtin_amdgcn_mfma_f32_16x16x32_bf16(
                        ah[cf], bh, acc[cf][nf], 0, 0, 0);
                    acc[cf][nf] = __builtin_amdgcn_mfma_f32_16x16x32_bf16(
                        ah[cf], bl, acc[cf][nf], 0, 0, 0);
                    acc[cf][nf] = __builtin_amdgcn_mfma_f32_16x16x32_bf16(
                        al[cf], bh, acc[cf][nf], 0, 0, 0);
                }
            }
        }
    }

    if (STATS) {
#pragma unroll
        for (int cf = 0; cf < CF; cf++)
#pragma unroll
            for (int rg = 0; rg < 4; rg++) {
                float a = 0.f, b = 0.f;
#pragma unroll
                for (int nf = 0; nf < 4; nf++) {
                    int l = Lbase + nf * 16 + l16;
                    if (l >= 0 && l < Lconv) {
                        float v = acc[cf][nf][rg];
                        a += v; b += v * v;
                    }
                }
#pragma unroll
                for (int m = 1; m < 16; m <<= 1) {
                    a += __shfl_xor(a, m); b += __shfl_xor(b, m);
                }
                if (l16 == 0) {
                    atomicAdd(&s_s1[wbase + cf * 16 + g16 * 4 + rg], a);
                    atomicAdd(&s_s2[wbase + cf * 16 + g16 * 4 + rg], b);
                }
            }
    }

    if ((MODE == 3 || MODE == 5) && bz < bzStore) {
#pragma unroll
        for (int cf = 0; cf < CF; cf++)
#pragma unroll
            for (int nf = 0; nf < 4; nf++) {
                int l = Lbase + nf * 16 + l16;
                bool ok = (l >= 0 && l < Lconv);
                float4 pv;
#pragma unroll
                for (int rg = 0; rg < 4; rg++) {
                    float v = ok ? acc[cf][nf][rg] : -3.0e38f;
                    float vv = __shfl_xor(v, 1);
                    ((float*)&pv)[rg] = fmaxf(v, vv);
                }
                int j = (l + 1) >> 1;
                if (!(lane & 1) && j < Lp)
                    *(float4*)&out[((size_t)(bn0o + bz) * Lp + j) * CO
                                   + wbase + cf * 16 + g16 * 4] = pv;
            }
    }
    if (MODE == 4) {
#pragma unroll
        for (int cf = 0; cf < CF; cf++)
#pragma unroll
            for (int nf = 0; nf < 4; nf++) {
                int l = Lbase + nf * 16 + l16;
                bool ok = (l >= 0 && l < Lconv);
                int j = (l + 1) >> 1;
#pragma unroll
                for (int rg = 0; rg < 4; rg++) {
                    float v = ok ? acc[cf][nf][rg] : -3.0e38f;
                    float vv = __shfl_xor(v, 1);
                    if (!(lane & 1) && j < Lp) {
                        float pv = fmaxf(v, vv);
                        int co = wbase + cf * 16 + g16 * 4 + rg;
                        int lin = co * 36 + j;
                        int tc = lin >> 7, f = lin & 127;
                        int bq = bz >> 6, n = bz & 63;
                        out[(((size_t)bq * 72 + tc) * 64 + n) * 128 + f] = pv;
                    }
                }
            }
    }

    if (STATS) {
        __syncthreads();
        if (tid < CO) {
            atomicAdd(&raw[tid], s_s1[tid]);
            atomicAdd(&raw[CO + tid], s_s2[tid]);
        }
    }
}

// fin[c] = scale = g*rsqrt(var+eps);  fin[C+c] = shift = b - mean*scale
__global__ __launch_bounds__(TPB) void bn_fin_k(const float* __restrict__ raw,
                                                const float* __restrict__ g,
                                                const float* __restrict__ b,
                                                float* __restrict__ fin, int C, float invN)
{
    int c = threadIdx.x + blockIdx.x * TPB;
    if (c < C) {
        float m = raw[c] * invN;
        float v = raw[C + c] * invN - m * m;
        float sc = g[c] * rsqrtf(v + 1e-5f);
        fin[c] = sc;
        fin[C + c] = b[c] - m * sc;
    }
}

// ---------------------------------------------------------------------------
// Fused graph stage on MFMA.  Gt aliases NF LDS (dead after P2) -> LDS 49KB,
// 3 blocks/CU.  One extra barrier between P2 and P3.
// ---------------------------------------------------------------------------
#define AJX(n,m) s_adj[(((n) * 64 + (m)) ^ (((n) & 7) << 3))]

__global__ __launch_bounds__(TPB) void graph_f_k(const float* __restrict__ spa,
                                                 const float* __restrict__ fin3,
                                                 const unsigned short* __restrict__ wmh,
                                                 const unsigned short* __restrict__ wml,
                                                 const float* __restrict__ mapb,
                                                 const unsigned short* __restrict__ thh,
                                                 const unsigned short* __restrict__ thl,
                                                 const float* __restrict__ thb,
                                                 float* __restrict__ gout,
                                                 float* __restrict__ rawg)
{
    __shared__ __align__(16) char smem[49152];
    unsigned short* NFh = (unsigned short*)smem;             // [64][128] swz, 16KB
    unsigned short* NFl = (unsigned short*)(smem + 16384);   // 16KB
    float* s_adj        = (float*)(smem + 32768);            // [64][64] swz, 16KB
    unsigned short* Gth = (unsigned short*)smem;             // alias NFh (dead)
    unsigned short* Gtl = (unsigned short*)(smem + 16384);   // alias NFl (dead)
    __shared__ float s_red[256], s_rmax[64], s_rsum[64], s_s1[64], s_s2[64];

    int tid  = threadIdx.x;
    int lane = tid & 63;
    int w    = tid >> 6;
    int g16  = lane >> 4, l16 = lane & 15;
    int n0   = w * 16;
    int bp   = blockIdx.x;
    int tcb  = (bp % 72) * 128;

    if (tid < 64) { s_s1[tid] = 0.f; s_s2[tid] = 0.f; }

    // ---- P0: A = relu(bn3(spa)) for rows n0+l16 -> registers (split bf16) ----
    unsigned aH[16], aL[16];
    {
        const float* ar = spa + ((size_t)bp * 64 + n0 + l16) * 128;
#pragma unroll
        for (int kc = 0; kc < 4; kc++) {
            int kb = kc * 32 + g16 * 8;
            float4 x0 = *(const float4*)(ar + kb);
            float4 x1 = *(const float4*)(ar + kb + 4);
            float v[8] = {x0.x, x0.y, x0.z, x0.w, x1.x, x1.y, x1.z, x1.w};
#pragma unroll
            for (int j = 0; j < 8; j++) {
                int co = ((tcb + kb + j) * 29128) >> 20;   // exact /36 for x<32768
                float z = v[j] * fin3[co] + fin3[256 + co];
                v[j] = z > 0.f ? z : 0.f;
            }
            split2(v[0], v[1], aH[kc*4+0], aL[kc*4+0]);
            split2(v[2], v[3], aH[kc*4+1], aL[kc*4+1]);
            split2(v[4], v[5], aH[kc*4+2], aL[kc*4+2]);
            split2(v[6], v[7], aH[kc*4+3], aL[kc*4+3]);
        }
    }

    // ---- P1: nf = A @ map_w^T + mapb  -> NFh/NFl ----
    {
        f32x4 acc[8];
#pragma unroll
        for (int i = 0; i < 8; i++) { f32x4 z = {0.f,0.f,0.f,0.f}; acc[i] = z; }
#pragma unroll
        for (int ff = 0; ff < 8; ff++) {
#pragma unroll
            for (int kc = 0; kc < 4; kc++) {
                U8 ah, al;
#pragma unroll
                for (int u = 0; u < 4; u++) { ah.u[u] = aH[kc*4+u]; al.u[u] = aL[kc*4+u]; }
                size_t wo = (size_t)(ff * 16 + l16) * 128 + kc * 32 + g16 * 8;
                bf16x8 bh = *(const bf16x8*)(wmh + wo);
                bf16x8 bl = *(const bf16x8*)(wml + wo);
                acc[ff] = __builtin_amdgcn_mfma_f32_16x16x32_bf16(ah.v, bh, acc[ff], 0, 0, 0);
                acc[ff] = __builtin_amdgcn_mfma_f32_16x16x32_bf16(ah.v, bl, acc[ff], 0, 0, 0);
                acc[ff] = __builtin_amdgcn_mfma_f32_16x16x32_bf16(al.v, bh, acc[ff], 0, 0, 0);
            }
        }
#pragma unroll
        for (int ff = 0; ff < 8; ff++) {
            float bv = mapb[ff * 16 + l16];
#pragma unroll
            for (int rg = 0; rg < 4; rg++) {
                int n = n0 + g16 * 4 + rg;
                float v = acc[ff][rg] + bv;
                int s = ((n * 128) + ff * 16 + l16) ^ ((n & 7) << 3);
                unsigned short h = bf16tr(v);
                NFh[s] = h;
                NFl[s] = bf16tr(v - bf16tof(h));
            }
        }
    }
    __syncthreads();

    // ---- preload this wave's NF rows (A-operand for adj and G) ----
    bf16x8 nh[4], nl[4];
#pragma unroll
    for (int kc = 0; kc < 4; kc++) {
        int r = n0 + l16;
        int s = ((r * 128) + kc * 32 + g16 * 8) ^ ((r & 7) << 3);
        nh[kc] = *(const bf16x8*)&NFh[s];
        nl[kc] = *(const bf16x8*)&NFl[s];
    }

    // ---- P2: adj = nf @ nf^T  (diag -1e8, leaky) -> s_adj ----
    {
        f32x4 aj[4];
#pragma unroll
        for (int i = 0; i < 4; i++) { f32x4 z = {0.f,0.f,0.f,0.f}; aj[i] = z; }
#pragma unroll
        for (int mf = 0; mf < 4; mf++) {
#pragma unroll
            for (int kc = 0; kc < 4; kc++) {
                int r = mf * 16 + l16;
                int s = ((r * 128) + kc * 32 + g16 * 8) ^ ((r & 7) << 3);
                bf16x8 bh = *(const bf16x8*)&NFh[s];
                bf16x8 bl = *(const bf16x8*)&NFl[s];
                aj[mf] = __builtin_amdgcn_mfma_f32_16x16x32_bf16(nh[kc], bh, aj[mf], 0, 0, 0);
                aj[mf] = __builtin_amdgcn_mfma_f32_16x16x32_bf16(nh[kc], bl, aj[mf], 0, 0, 0);
                aj[mf] = __builtin_amdgcn_mfma_f32_16x16x32_bf16(nl[kc], bh, aj[mf], 0, 0, 0);
            }
        }
#pragma unroll
        for (int mf = 0; mf < 4; mf++)
#pragma unroll
            for (int rg = 0; rg < 4; rg++) {
                int n = n0 + g16 * 4 + rg, m = mf * 16 + l16;
                float v = aj[mf][rg];
                if (n == m) v -= 1e8f;
                v = v > 0.f ? v : 0.01f * v;
                AJX(n, m) = v;
            }
    }
    __syncthreads();   // all NF reads done before Gt overwrites the aliased LDS

    // ---- P3: G = nf @ theta^T -> Gt (transposed, split bf16; aliases NF) ----
    {
        f32x4 gg[4];
#pragma unroll
        for (int i = 0; i < 4; i++) { f32x4 z = {0.f,0.f,0.f,0.f}; gg[i] = z; }
#pragma unroll
        for (int of = 0; of < 4; of++) {
#pragma unroll
            for (int kc = 0; kc < 4; kc++) {
                size_t to = (size_t)(of * 16 + l16) * 128 + kc * 32 + g16 * 8;
                bf16x8 th_ = *(const bf16x8*)(thh + to);
                bf16x8 tl_ = *(const bf16x8*)(thl + to);
                gg[of] = __builtin_amdgcn_mfma_f32_16x16x32_bf16(nh[kc], th_, gg[of], 0, 0, 0);
                gg[of] = __builtin_amdgcn_mfma_f32_16x16x32_bf16(nh[kc], tl_, gg[of], 0, 0, 0);
                gg[of] = __builtin_amdgcn_mfma_f32_16x16x32_bf16(nl[kc], th_, gg[of], 0, 0, 0);
            }
        }
#pragma unroll
        for (int of = 0; of < 4; of++) {
            unsigned short hs[4], ls[4];
#pragma unroll
            for (int rg = 0; rg < 4; rg++) {
                float v = gg[of][rg];
                hs[rg] = bf16tr(v);
                ls[rg] = bf16tr(v - bf16tof(hs[rg]));
            }
            int o = of * 16 + l16;
            int m = n0 + g16 * 4;            // 4 consecutive m
            int s = ((o * 64) + m) ^ ((o & 7) << 3);
            uint2 hp, lp;
            hp.x = (unsigned)hs[0] | ((unsigned)hs[1] << 16);
            hp.y = (unsigned)hs[2] | ((unsigned)hs[3] << 16);
            lp.x = (unsigned)ls[0] | ((unsigned)ls[1] << 16);
            lp.y = (unsigned)ls[2] | ((unsigned)ls[3] << 16);
            *(uint2*)&Gth[s] = hp;
            *(uint2*)&Gtl[s] = lp;
        }
    }
    __syncthreads();

    // ---- P4: row softmax + I on s_adj ----
    {
        int n = tid >> 2, q = tid & 3;
        float mx = -3.0e38f;
        for (int m = q * 16; m < q * 16 + 16; m++) mx = fmaxf(mx, AJX(n, m));
        s_red[n * 4 + q] = mx;
    }
    __syncthreads();
    if (tid < 64)
        s_rmax[tid] = fmaxf(fmaxf(s_red[tid * 4], s_red[tid * 4 + 1]),
                            fmaxf(s_red[tid * 4 + 2], s_red[tid * 4 + 3]));
    __syncthreads();
    {
        int n = tid >> 2, q = tid & 3;
        float mx = s_rmax[n];
        float sm = 0.f;
        for (int m = q * 16; m < q * 16 + 16; m++) {
            float e = __expf(AJX(n, m) - mx);
            AJX(n, m) = e;
            sm += e;
        }
        s_red[n * 4 + q] = sm;
    }
    __syncthreads();
    if (tid < 64)
        s_rsum[tid] = 1.0f / (s_red[tid * 4] + s_red[tid * 4 + 1] +
                              s_red[tid * 4 + 2] + s_red[tid * 4 + 3]);
    __syncthreads();
    {
        int n = tid >> 2, q = tid & 3;
        float inv = s_rsum[n];
        for (int m = q * 16; m < q * 16 + 16; m++)
            AJX(n, m) = AJX(n, m) * inv + ((n == m) ? 1.f : 0.f);
    }
    __syncthreads();

    // ---- P5: out = adjS @ G + thb -> gout, fused stats ----
    {
        f32x4 oacc[4];
#pragma unroll
        for (int i = 0; i < 4; i++) { f32x4 z = {0.f,0.f,0.f,0.f}; oacc[i] = z; }
#pragma unroll
        for (int kc = 0; kc < 2; kc++) {
            int r = n0 + l16;
            int sf = ((r * 64) + kc * 32 + g16 * 8) ^ ((r & 7) << 3);
            float4 p0 = *(const float4*)&s_adj[sf];
            float4 p1 = *(const float4*)&s_adj[sf + 4];
            U8 ah, al;
            split2(p0.x, p0.y, ah.u[0], al.u[0]);
            split2(p0.z, p0.w, ah.u[1], al.u[1]);
            split2(p1.x, p1.y, ah.u[2], al.u[2]);
            split2(p1.z, p1.w, ah.u[3], al.u[3]);
#pragma unroll
            for (int of = 0; of < 4; of++) {
                int o = of * 16 + l16;
                int s = ((o * 64) + kc * 32 + g16 * 8) ^ ((o & 7) << 3);
                bf16x8 gh = *(const bf16x8*)&Gth[s];
                bf16x8 gl = *(const bf16x8*)&Gtl[s];
                oacc[of] = __builtin_amdgcn_mfma_f32_16x16x32_bf16(ah.v, gh, oacc[of], 0, 0, 0);
                oacc[of] = __builtin_amdgcn_mfma_f32_16x16x32_bf16(ah.v, gl, oacc[of], 0, 0, 0);
                oacc[of] = __builtin_amdgcn_mfma_f32_16x16x32_bf16(al.v, gh, oacc[of], 0, 0, 0);
            }
        }
        float* gb = gout + (size_t)bp * 4096;
#pragma unroll
        for (int of = 0; of < 4; of++) {
            float tb = thb[of * 16 + l16];
            float a = 0.f, b = 0.f;
#pragma unroll
            for (int rg = 0; rg < 4; rg++) {
                int n = n0 + g16 * 4 + rg;
                float v = oacc[of][rg] + tb;
                gb[n * 64 + of * 16 + l16] = v;
                a += v; b += v * v;
            }
            a += __shfl_xor(a, 16); a += __shfl_xor(a, 32);
            b += __shfl_xor(b, 16); b += __shfl_xor(b, 32);
            if (g16 == 0) {
                atomicAdd(&s_s1[of * 16 + l16], a);
                atomicAdd(&s_s2[of * 16 + l16], b);
            }
        }
    }
    __syncthreads();
    if (tid < 64) {
        atomicAdd(&rawg[tid], s_s1[tid]);
        atomicAdd(&rawg[64 + tid], s_s2[tid]);
    }
}

// ---------------- final BN + leaky + pair mean, unchanged ----------------
__global__ __launch_bounds__(TPB) void final_k(const float* __restrict__ gout,
                                               const float* __restrict__ raw,
                                               const float* __restrict__ g,
                                               const float* __restrict__ b,
                                               float* __restrict__ out)
{
    long idx = (long)blockIdx.x * TPB + threadIdx.x;
    if (idx >= 2359296L) return;
    int o = (int)(idx & 63);
    long t = idx >> 6;
    int n = (int)(t & 63);
    long t2 = t >> 6;
    long wd = t2 % 36;
    long bb = t2 / 36;
    const float invN = 1.0f / 73728.0f;
    float m = raw[o] * invN;
    float var = raw[64 + o] * invN - m * m;
    float scale = g[o] * rsqrtf(var + 1e-5f);
    float shift = b[o] - m * scale;
    long bp = bb * 72 + wd * 2;
    float v0 = gout[(bp * 64 + n) * 64 + o] * scale + shift;
    float v1 = gout[((bp + 1) * 64 + n) * 64 + o] * scale + shift;
    v0 = v0 > 0.f ? v0 : 0.01f * v0;
    v1 = v1 > 0.f ? v1 : 0.01f * v1;
    out[idx] = 0.5f * (v0 + v1);
}

// ---------------------------------------------------------------------------
extern "C" void kernel_launch(void* const* d_in, const int* in_sizes, int n_in,
                              void* d_out, int out_size, void* d_ws, size_t ws_size,
                              hipStream_t stream)
{
    (void)in_sizes; (void)n_in; (void)out_size;
    const float* x    = (const float*)d_in[0];
    const float* c1w  = (const float*)d_in[1];
    const float* g1   = (const float*)d_in[2];
    const float* b1   = (const float*)d_in[3];
    const float* c2w  = (const float*)d_in[4];
    const float* g2   = (const float*)d_in[5];
    const float* b2   = (const float*)d_in[6];
    const float* c3w  = (const float*)d_in[7];
    const float* g3   = (const float*)d_in[8];
    const float* b3   = (const float*)d_in[9];
    const float* mapw = (const float*)d_in[10];
    const float* mapb = (const float*)d_in[11];
    const float* thw  = (const float*)d_in[12];
    const float* thb  = (const float*)d_in[13];
    const float* bng  = (const float*)d_in[14];
    const float* bnb  = (const float*)d_in[15];
    float* out = (float*)d_out;
    float* ws  = (float*)d_ws;

    // ws_size is constant across calls -> identical launch sequence every call.
    const size_t WSPLIT_USHORT = 540672;    // conv + map/theta split weights
    const size_t MONO_BYTES = ((size_t)33816576 + 8650752 + ST_FLOATS) * 4
                              + WSPLIT_USHORT * 2;
    int nch = (ws_size >= MONO_BYTES) ? 1 : 2;
    size_t P1SZ = (size_t)(nch == 1 ? 1024 : 512) * 33024;   // [bz][129][256]

    float* P1   = ws;                       // pooled-RAW conv1, [bz][129][256]
    float* P2   = ws + P1SZ;                // pooled-RAW conv2, [1024][66][128]
    float* SPA  = ws;                       // pooled-RAW conv3, [1152][64][128] (P1 dead)
    float* GOUT = ws + 9437184;             // [1152][64][64]  (after SPA, inside P1)
    float* ST   = ws + P1SZ + 8650752;
    unsigned short* WB  = (unsigned short*)(ST + ST_FLOATS);
    unsigned short* WH1 = WB;               // [3][256][64]
    unsigned short* WL1 = WB + 49152;
    unsigned short* WH2 = WB + 98304;       // [3][128][256]
    unsigned short* WL2 = WB + 196608;
    unsigned short* WH3 = WB + 294912;      // [3][256][128]
    unsigned short* WL3 = WB + 393216;
    unsigned short* WMH = WB + 491520;      // [128][128]
    unsigned short* WML = WB + 507904;
    unsigned short* THH = WB + 524288;      // [64][128]
    unsigned short* THL = WB + 532480;

    hipMemsetAsync((void*)ST, 0, ST_FLOATS * sizeof(float), stream);
    split_w_k<<<192, TPB, 0, stream>>>(c1w, WH1, WL1, 256, 64);
    split_w_k<<<384, TPB, 0, stream>>>(c2w, WH2, WL2, 128, 256);
    split_w_k<<<384, TPB, 0, stream>>>(c3w, WH3, WL3, 256, 128);
    split_lin_k<<<64, TPB, 0, stream>>>(mapw, WMH, WML, 16384);
    split_lin_k<<<32, TPB, 0, stream>>>(thw, THH, THL, 8192);

    if (nch == 1) {
        mconv_k<0, 3, 0, 4><<<dim3(5, 1, 1024), TPB, 0, stream>>>(
            x, WH1, WL1, nullptr, P1, ST + RAW1,
            64, 256, 256, 1, 256, 129, 1024, 0, 0);
        bn_fin_k<<<1, TPB, 0, stream>>>(ST + RAW1, g1, b1, ST + FIN1, 256, 1.0f / 262144.0f);
        mconv_k<1, 3, 1, 2><<<dim3(3, 1, 1024), TPB, 0, stream>>>(
            P1, WH2, WL2, ST + FIN1, P2, ST + RAW2,
            256, 128, 129, 2, 131, 66, 1024, 0, 0);
    } else {
        mconv_k<0, 3, 0, 4><<<dim3(5, 1, 1024), TPB, 0, stream>>>(
            x, WH1, WL1, nullptr, P1, ST + RAW1,
            64, 256, 256, 1, 256, 129, 512, 0, 0);
        bn_fin_k<<<1, TPB, 0, stream>>>(ST + RAW1, g1, b1, ST + FIN1, 256, 1.0f / 262144.0f);
        mconv_k<1, 3, 1, 2><<<dim3(3, 1, 512), TPB, 0, stream>>>(
            P1, WH2, WL2, ST + FIN1, P2, ST + RAW2,
            256, 128, 129, 2, 131, 66, 512, 0, 0);
        mconv_k<0, 5, 0, 4><<<dim3(5, 1, 512), TPB, 0, stream>>>(
            x, WH1, WL1, nullptr, P1, nullptr,
            64, 256, 256, 1, 256, 129, 512, 512, 0);
        mconv_k<1, 3, 1, 2><<<dim3(3, 1, 512), TPB, 0, stream>>>(
            P1, WH2, WL2, ST + FIN1, P2, ST + RAW2,
            256, 128, 129, 2, 131, 66, 512, 0, 512);
    }
    bn_fin_k<<<1, TPB, 0, stream>>>(ST + RAW2, g2, b2, ST + FIN2, 128, 1.0f / 134144.0f);

    mconv_k<1, 4, 1, 4><<<dim3(2, 1, 1024), TPB, 0, stream>>>(
        P2, WH3, WL3, ST + FIN2, SPA, ST + RAW3,
        128, 256, 66, 3, 70, 36, 1024, 0, 0);
    bn_fin_k<<<1, TPB, 0, stream>>>(ST + RAW3, g3, b3, ST + FIN3, 256, 1.0f / 71680.0f);

    // ---- fused graph stage (gemm_nf + adj/softmax + G + out + stats) ----
    graph_f_k<<<1152, TPB, 0, stream>>>(SPA, ST + FIN3, WMH, WML, mapb,
                                        THH, THL, thb, GOUT, ST + RAWG);
    final_k<<<9216, TPB, 0, stream>>>(GOUT, ST + RAWG, bng, bnb, out);
}

// Round 9
// 679.319 us; speedup vs baseline: 1.1262x; 1.0323x over previous
//
#include <hip/hip_runtime.h>

// ---------------------------------------------------------------------------
// MPNN_block_seperate — MFMA split-bf16 conv path + MFMA fused graph stage, v9.
// v8 = stable 694-701us baseline.  v9 keeps the exact v5/v8 conv structure
// (VGPR 72, 19KB LDS, grid.x = l-tiles) and removes exposed-latency work:
// (1) 64-ci staging phases (same LDS footprint: rows are 72-stride, 64 ci fit)
//     -> barrier pairs halved (conv1 2->1, conv2 8->4, conv3 4->2); the MFMA
//     loop still walks 32-ci chunks in the same order -> bit-identical.
// (2) staged-row clamp rlim = min(66, nf_last*16+18): mostly-dead tiles
//     (conv1 t4, conv2 t2, conv3 t1) stop staging 66 rows for <=7 valid cols.
// (3) all 5 weight-split launches merged into one segmented kernel.
// ---------------------------------------------------------------------------

#define TPB 256

// stats block offsets (floats)
#define RAW1 0
#define FIN1 512
#define RAW2 1024
#define FIN2 1280
#define RAW3 1536
#define FIN3 2048
#define RAWG 2560
#define ST_FLOATS 2688

typedef __attribute__((ext_vector_type(8))) short bf16x8;
typedef __attribute__((ext_vector_type(4))) float f32x4;

union U8 { unsigned u[4]; bf16x8 v; };

__device__ __forceinline__ unsigned short bf16tr(float x) {
    return (unsigned short)(__float_as_uint(x) >> 16);
}
__device__ __forceinline__ float bf16tof(unsigned short h) {
    return __uint_as_float(((unsigned int)h) << 16);
}
__device__ __forceinline__ void split2(float a, float b, unsigned& h, unsigned& l) {
    unsigned short ha = bf16tr(a), hb = bf16tr(b);
    unsigned short la = bf16tr(a - bf16tof(ha)), lb = bf16tr(b - bf16tof(hb));
    h = (unsigned)ha | ((unsigned)hb << 16);
    l = (unsigned)la | ((unsigned)lb << 16);
}

// ---- one-shot weight split: 3 conv weights ([k][CO][CI] layout) + 2 linear ----
__global__ __launch_bounds__(TPB) void split_all_k(const float* __restrict__ c1w,
                                                   const float* __restrict__ c2w,
                                                   const float* __restrict__ c3w,
                                                   const float* __restrict__ mapw,
                                                   const float* __restrict__ thw,
                                                   unsigned short* __restrict__ WB)
{
    int i = blockIdx.x * TPB + threadIdx.x;
    const float* src;
    unsigned short *wh, *wl;
    int CO, CI, j;
    if (i < 49152)       { src = c1w; wh = WB;          wl = WB + 49152;  CO = 256; CI = 64;  j = i; }
    else if (i < 147456) { src = c2w; wh = WB + 98304;  wl = WB + 196608; CO = 128; CI = 256; j = i - 49152; }
    else if (i < 245760) { src = c3w; wh = WB + 294912; wl = WB + 393216; CO = 256; CI = 128; j = i - 147456; }
    else if (i < 262144) {
        int j2 = i - 245760;
        float v = mapw[j2];
        unsigned short h = bf16tr(v);
        WB[491520 + j2] = h; WB[507904 + j2] = bf16tr(v - bf16tof(h));
        return;
    } else if (i < 270336) {
        int j2 = i - 262144;
        float v = thw[j2];
        unsigned short h = bf16tr(v);
        WB[524288 + j2] = h; WB[532480 + j2] = bf16tr(v - bf16tof(h));
        return;
    } else return;
    int ci = j % CI; int rest = j / CI; int co = rest % CO; int k = rest / CO;
    float v = src[((size_t)co * CI + ci) * 3 + k];
    unsigned short h = bf16tr(v);
    wh[j] = h; wl[j] = bf16tr(v - bf16tof(h));
}

// ---------------------------------------------------------------------------
// MFMA conv core.  Tile: FULL CO x 64 l, 4 waves; wave owns CF*16 channels.
// Staging phase covers 64 ci (rows hold 64 ci + 8 pad at 72-stride); MFMA
// walks the two 32-ci sub-chunks in order (bit-identical to 32-ci phases).
//   LAYOUT 0: input x [16][256][64][64]; row l at base[l*4096 + ci]
//   LAYOUT 1: input [bz][Lin][CI] row-major
//   STAGEBN:  staging applies relu(v*finIn[ci] + finIn[CI+ci])
//   MODE 3: stats + pooled-RAW -> out[bn0o+bz][j][co]   (store if bz < bzStore)
//   MODE 4: stats + pooled-RAW -> SPA [bq][72][64][128]
//   MODE 5: pooled-RAW only    -> out[bn0o+bz][j][co]
// ---------------------------------------------------------------------------
template<int LAYOUT, int MODE, int STAGEBN, int CF>
__global__ __launch_bounds__(TPB) void mconv_k(const float* __restrict__ in,
                                               const unsigned short* __restrict__ wh,
                                               const unsigned short* __restrict__ wl,
                                               const float* __restrict__ finIn,
                                               float* __restrict__ out,
                                               float* __restrict__ raw,
                                               int CI, int CO, int Lin, int pad,
                                               int Lconv, int Lp,
                                               int bzStore, int bn0x, int bn0o)
{
    __shared__ __align__(16) unsigned short Xh[66 * 72];
    __shared__ __align__(16) unsigned short Xl[66 * 72];
    __shared__ float s_s1[256], s_s2[256];
    constexpr bool STATS = (MODE == 3 || MODE == 4);

    int tid  = threadIdx.x;
    int lane = tid & 63;
    int w    = tid >> 6;
    int g16  = lane >> 4;
    int l16  = lane & 15;
    int wbase = w * (CF * 16);
    int bz   = blockIdx.z;
    int Lbase = (int)blockIdx.x * 64 - 1;
    int gbase = Lbase - pad;

    const float* base;
    int RS;
    if (LAYOUT == 0) {
        int bn = bn0x + bz;
        base = in + (size_t)(bn >> 6) * 1048576 + (size_t)(bn & 63) * 64;
        RS = 4096;
    } else {
        base = in + (size_t)bz * CI * Lin;
        RS = CI;
    }

    if (STATS && tid < CO) { s_s1[tid] = 0.f; s_s2[tid] = 0.f; }

    // rows actually consumed: nf_last*16 + 15 (cols) + 2 (taps) + 1
    int nfl = (Lconv - Lbase - 1) >> 4;
    if (nfl > 3) nfl = 3;
    int rlim = nfl * 16 + 18;
    if (rlim > 66) rlim = 66;
    int items = rlim << 3;

    f32x4 acc[CF][4];
#pragma unroll
    for (int cf = 0; cf < CF; cf++)
#pragma unroll
        for (int nf = 0; nf < 4; nf++) {
            f32x4 z = {0.f, 0.f, 0.f, 0.f};
            acc[cf][nf] = z;
        }

    for (int c0 = 0; c0 < CI; c0 += 64) {
        __syncthreads();
        // ---- stage rlim rows x 64 ci: contiguous float4 loads, 16B LDS writes ----
        for (int idx = tid; idx < items; idx += TPB) {
            int r = idx >> 3, q = idx & 7;
            int gl = gbase + r;
            float4 va = {0.f, 0.f, 0.f, 0.f}, vb = {0.f, 0.f, 0.f, 0.f};
            if (gl >= 0 && gl < Lin) {
                const float* p = base + (size_t)gl * RS + c0 + 8 * q;
                va = *(const float4*)p;
                vb = *(const float4*)(p + 4);
                if (STAGEBN) {
                    const float* sc = finIn + c0 + 8 * q;
                    const float* sh = finIn + CI + c0 + 8 * q;
                    float4 s0 = *(const float4*)sc, s1 = *(const float4*)(sc + 4);
                    float4 h0 = *(const float4*)sh, h1 = *(const float4*)(sh + 4);
                    va.x = fmaxf(va.x * s0.x + h0.x, 0.f);
                    va.y = fmaxf(va.y * s0.y + h0.y, 0.f);
                    va.z = fmaxf(va.z * s0.z + h0.z, 0.f);
                    va.w = fmaxf(va.w * s0.w + h0.w, 0.f);
                    vb.x = fmaxf(vb.x * s1.x + h1.x, 0.f);
                    vb.y = fmaxf(vb.y * s1.y + h1.y, 0.f);
                    vb.z = fmaxf(vb.z * s1.z + h1.z, 0.f);
                    vb.w = fmaxf(vb.w * s1.w + h1.w, 0.f);
                }
            }
            uint4 hu, lu;
            split2(va.x, va.y, hu.x, lu.x);
            split2(va.z, va.w, hu.y, lu.y);
            split2(vb.x, vb.y, hu.z, lu.z);
            split2(vb.z, vb.w, hu.w, lu.w);
            *(uint4*)&Xh[r * 72 + 8 * q] = hu;
            *(uint4*)&Xl[r * 72 + 8 * q] = lu;
        }
        __syncthreads();

        // ---- MFMA over the two 32-ci sub-chunks, in order (bit-identical) ----
        for (int ci0 = c0; ci0 < c0 + 64; ci0 += 32) {
            int lofs = ci0 & 63;        // 0 or 32 within the staged 64-ci row
#pragma unroll
            for (int k = 0; k < 3; k++) {
                bf16x8 ah[CF], al[CF];
#pragma unroll
                for (int cf = 0; cf < CF; cf++) {
                    size_t wof = ((size_t)(k * CO + wbase + cf * 16 + l16)) * CI
                                 + ci0 + g16 * 8;
                    ah[cf] = *(const bf16x8*)(wh + wof);
                    al[cf] = *(const bf16x8*)(wl + wof);
                }
#pragma unroll
                for (int nf = 0; nf < 4; nf++) {
                    if (Lbase + nf * 16 >= Lconv) continue;
                    int rb = nf * 16 + l16 + k;
                    bf16x8 bh = *(const bf16x8*)&Xh[rb * 72 + lofs + g16 * 8];
                    bf16x8 bl = *(const bf16x8*)&Xl[rb * 72 + lofs + g16 * 8];
#pragma unroll
                    for (int cf = 0; cf < CF; cf++) {
                        acc[cf][nf] = __builtin_amdgcn_mfma_f32_16x16x32_bf16(
                            ah[cf], bh, acc[cf][nf], 0, 0, 0);
                        acc[cf][nf] = __builtin_amdgcn_mfma_f32_16x16x32_bf16(
                            ah[cf], bl, acc[cf][nf], 0, 0, 0);
                        acc[cf][nf] = __builtin_amdgcn_mfma_f32_16x16x32_bf16(
                            al[cf], bh, acc[cf][nf], 0, 0, 0);
                    }
                }
            }
        }
    }

    if (STATS) {
#pragma unroll
        for (int cf = 0; cf < CF; cf++)
#pragma unroll
            for (int rg = 0; rg < 4; rg++) {
                float a = 0.f, b = 0.f;
#pragma unroll
                for (int nf = 0; nf < 4; nf++) {
                    int l = Lbase + nf * 16 + l16;
                    if (l >= 0 && l < Lconv) {
                        float v = acc[cf][nf][rg];
                        a += v; b += v * v;
                    }
                }
#pragma unroll
                for (int m = 1; m < 16; m <<= 1) {
                    a += __shfl_xor(a, m); b += __shfl_xor(b, m);
                }
                if (l16 == 0) {
                    atomicAdd(&s_s1[wbase + cf * 16 + g16 * 4 + rg], a);
                    atomicAdd(&s_s2[wbase + cf * 16 + g16 * 4 + rg], b);
                }
            }
    }

    if ((MODE == 3 || MODE == 5) && bz < bzStore) {
#pragma unroll
        for (int cf = 0; cf < CF; cf++)
#pragma unroll
            for (int nf = 0; nf < 4; nf++) {
                int l = Lbase + nf * 16 + l16;
                bool ok = (l >= 0 && l < Lconv);
                float4 pv;
#pragma unroll
                for (int rg = 0; rg < 4; rg++) {
                    float v = ok ? acc[cf][nf][rg] : -3.0e38f;
                    float vv = __shfl_xor(v, 1);
                    ((float*)&pv)[rg] = fmaxf(v, vv);
                }
                int j = (l + 1) >> 1;
                if (!(lane & 1) && j < Lp)
                    *(float4*)&out[((size_t)(bn0o + bz) * Lp + j) * CO
                                   + wbase + cf * 16 + g16 * 4] = pv;
            }
    }
    if (MODE == 4) {
#pragma unroll
        for (int cf = 0; cf < CF; cf++)
#pragma unroll
            for (int nf = 0; nf < 4; nf++) {
                int l = Lbase + nf * 16 + l16;
                bool ok = (l >= 0 && l < Lconv);
                int j = (l + 1) >> 1;
#pragma unroll
                for (int rg = 0; rg < 4; rg++) {
                    float v = ok ? acc[cf][nf][rg] : -3.0e38f;
                    float vv = __shfl_xor(v, 1);
                    if (!(lane & 1) && j < Lp) {
                        float pv = fmaxf(v, vv);
                        int co = wbase + cf * 16 + g16 * 4 + rg;
                        int lin = co * 36 + j;
                        int tc = lin >> 7, f = lin & 127;
                        int bq = bz >> 6, n = bz & 63;
                        out[(((size_t)bq * 72 + tc) * 64 + n) * 128 + f] = pv;
                    }
                }
            }
    }

    if (STATS) {
        __syncthreads();
        if (tid < CO) {
            atomicAdd(&raw[tid], s_s1[tid]);
            atomicAdd(&raw[CO + tid], s_s2[tid]);
        }
    }
}

// fin[c] = scale = g*rsqrt(var+eps);  fin[C+c] = shift = b - mean*scale
__global__ __launch_bounds__(TPB) void bn_fin_k(const float* __restrict__ raw,
                                                const float* __restrict__ g,
                                                const float* __restrict__ b,
                                                float* __restrict__ fin, int C, float invN)
{
    int c = threadIdx.x + blockIdx.x * TPB;
    if (c < C) {
        float m = raw[c] * invN;
        float v = raw[C + c] * invN - m * m;
        float sc = g[c] * rsqrtf(v + 1e-5f);
        fin[c] = sc;
        fin[C + c] = b[c] - m * sc;
    }
}

// ---------------------------------------------------------------------------
// Fused graph stage on MFMA.  Gt aliases NF LDS (dead after P2) -> LDS 49KB.
// ---------------------------------------------------------------------------
#define AJX(n,m) s_adj[(((n) * 64 + (m)) ^ (((n) & 7) << 3))]

__global__ __launch_bounds__(TPB) void graph_f_k(const float* __restrict__ spa,
                                                 const float* __restrict__ fin3,
                                                 const unsigned short* __restrict__ wmh,
                                                 const unsigned short* __restrict__ wml,
                                                 const float* __restrict__ mapb,
                                                 const unsigned short* __restrict__ thh,
                                                 const unsigned short* __restrict__ thl,
                                                 const float* __restrict__ thb,
                                                 float* __restrict__ gout,
                                                 float* __restrict__ rawg)
{
    __shared__ __align__(16) char smem[49152];
    unsigned short* NFh = (unsigned short*)smem;             // [64][128] swz, 16KB
    unsigned short* NFl = (unsigned short*)(smem + 16384);   // 16KB
    float* s_adj        = (float*)(smem + 32768);            // [64][64] swz, 16KB
    unsigned short* Gth = (unsigned short*)smem;             // alias NFh (dead)
    unsigned short* Gtl = (unsigned short*)(smem + 16384);   // alias NFl (dead)
    __shared__ float s_red[256], s_rmax[64], s_rsum[64], s_s1[64], s_s2[64];

    int tid  = threadIdx.x;
    int lane = tid & 63;
    int w    = tid >> 6;
    int g16  = lane >> 4, l16 = lane & 15;
    int n0   = w * 16;
    int bp   = blockIdx.x;
    int tcb  = (bp % 72) * 128;

    if (tid < 64) { s_s1[tid] = 0.f; s_s2[tid] = 0.f; }

    // ---- P0: A = relu(bn3(spa)) for rows n0+l16 -> registers (split bf16) ----
    unsigned aH[16], aL[16];
    {
        const float* ar = spa + ((size_t)bp * 64 + n0 + l16) * 128;
#pragma unroll
        for (int kc = 0; kc < 4; kc++) {
            int kb = kc * 32 + g16 * 8;
            float4 x0 = *(const float4*)(ar + kb);
            float4 x1 = *(const float4*)(ar + kb + 4);
            float v[8] = {x0.x, x0.y, x0.z, x0.w, x1.x, x1.y, x1.z, x1.w};
#pragma unroll
            for (int j = 0; j < 8; j++) {
                int co = ((tcb + kb + j) * 29128) >> 20;   // exact /36 for x<32768
                float z = v[j] * fin3[co] + fin3[256 + co];
                v[j] = z > 0.f ? z : 0.f;
            }
            split2(v[0], v[1], aH[kc*4+0], aL[kc*4+0]);
            split2(v[2], v[3], aH[kc*4+1], aL[kc*4+1]);
            split2(v[4], v[5], aH[kc*4+2], aL[kc*4+2]);
            split2(v[6], v[7], aH[kc*4+3], aL[kc*4+3]);
        }
    }

    // ---- P1: nf = A @ map_w^T + mapb  -> NFh/NFl ----
    {
        f32x4 acc[8];
#pragma unroll
        for (int i = 0; i < 8; i++) { f32x4 z = {0.f,0.f,0.f,0.f}; acc[i] = z; }
#pragma unroll
        for (int ff = 0; ff < 8; ff++) {
#pragma unroll
            for (int kc = 0; kc < 4; kc++) {
                U8 ah, al;
#pragma unroll
                for (int u = 0; u < 4; u++) { ah.u[u] = aH[kc*4+u]; al.u[u] = aL[kc*4+u]; }
                size_t wo = (size_t)(ff * 16 + l16) * 128 + kc * 32 + g16 * 8;
                bf16x8 bh = *(const bf16x8*)(wmh + wo);
                bf16x8 bl = *(const bf16x8*)(wml + wo);
                acc[ff] = __builtin_amdgcn_mfma_f32_16x16x32_bf16(ah.v, bh, acc[ff], 0, 0, 0);
                acc[ff] = __builtin_amdgcn_mfma_f32_16x16x32_bf16(ah.v, bl, acc[ff], 0, 0, 0);
                acc[ff] = __builtin_amdgcn_mfma_f32_16x16x32_bf16(al.v, bh, acc[ff], 0, 0, 0);
            }
        }
#pragma unroll
        for (int ff = 0; ff < 8; ff++) {
            float bv = mapb[ff * 16 + l16];
#pragma unroll
            for (int rg = 0; rg < 4; rg++) {
                int n = n0 + g16 * 4 + rg;
                float v = acc[ff][rg] + bv;
                int s = ((n * 128) + ff * 16 + l16) ^ ((n & 7) << 3);
                unsigned short h = bf16tr(v);
                NFh[s] = h;
                NFl[s] = bf16tr(v - bf16tof(h));
            }
        }
    }
    __syncthreads();

    // ---- preload this wave's NF rows (A-operand for adj and G) ----
    bf16x8 nh[4], nl[4];
#pragma unroll
    for (int kc = 0; kc < 4; kc++) {
        int r = n0 + l16;
        int s = ((r * 128) + kc * 32 + g16 * 8) ^ ((r & 7) << 3);
        nh[kc] = *(const bf16x8*)&NFh[s];
        nl[kc] = *(const bf16x8*)&NFl[s];
    }

    // ---- P2: adj = nf @ nf^T  (diag -1e8, leaky) -> s_adj ----
    {
        f32x4 aj[4];
#pragma unroll
        for (int i = 0; i < 4; i++) { f32x4 z = {0.f,0.f,0.f,0.f}; aj[i] = z; }
#pragma unroll
        for (int mf = 0; mf < 4; mf++) {
#pragma unroll
            for (int kc = 0; kc < 4; kc++) {
                int r = mf * 16 + l16;
                int s = ((r * 128) + kc * 32 + g16 * 8) ^ ((r & 7) << 3);
                bf16x8 bh = *(const bf16x8*)&NFh[s];
                bf16x8 bl = *(const bf16x8*)&NFl[s];
                aj[mf] = __builtin_amdgcn_mfma_f32_16x16x32_bf16(nh[kc], bh, aj[mf], 0, 0, 0);
                aj[mf] = __builtin_amdgcn_mfma_f32_16x16x32_bf16(nh[kc], bl, aj[mf], 0, 0, 0);
                aj[mf] = __builtin_amdgcn_mfma_f32_16x16x32_bf16(nl[kc], bh, aj[mf], 0, 0, 0);
            }
        }
#pragma unroll
        for (int mf = 0; mf < 4; mf++)
#pragma unroll
            for (int rg = 0; rg < 4; rg++) {
                int n = n0 + g16 * 4 + rg, m = mf * 16 + l16;
                float v = aj[mf][rg];
                if (n == m) v -= 1e8f;
                v = v > 0.f ? v : 0.01f * v;
                AJX(n, m) = v;
            }
    }
    __syncthreads();   // all NF reads done before Gt overwrites the aliased LDS

    // ---- P3: G = nf @ theta^T -> Gt (transposed, split bf16; aliases NF) ----
    {
        f32x4 gg[4];
#pragma unroll
        for (int i = 0; i < 4; i++) { f32x4 z = {0.f,0.f,0.f,0.f}; gg[i] = z; }
#pragma unroll
        for (int of = 0; of < 4; of++) {
#pragma unroll
            for (int kc = 0; kc < 4; kc++) {
                size_t to = (size_t)(of * 16 + l16) * 128 + kc * 32 + g16 * 8;
                bf16x8 th_ = *(const bf16x8*)(thh + to);
                bf16x8 tl_ = *(const bf16x8*)(thl + to);
                gg[of] = __builtin_amdgcn_mfma_f32_16x16x32_bf16(nh[kc], th_, gg[of], 0, 0, 0);
                gg[of] = __builtin_amdgcn_mfma_f32_16x16x32_bf16(nh[kc], tl_, gg[of], 0, 0, 0);
                gg[of] = __builtin_amdgcn_mfma_f32_16x16x32_bf16(nl[kc], th_, gg[of], 0, 0, 0);
            }
        }
#pragma unroll
        for (int of = 0; of < 4; of++) {
            unsigned short hs[4], ls[4];
#pragma unroll
            for (int rg = 0; rg < 4; rg++) {
                float v = gg[of][rg];
                hs[rg] = bf16tr(v);
                ls[rg] = bf16tr(v - bf16tof(hs[rg]));
            }
            int o = of * 16 + l16;
            int m = n0 + g16 * 4;            // 4 consecutive m
            int s = ((o * 64) + m) ^ ((o & 7) << 3);
            uint2 hp, lp;
            hp.x = (unsigned)hs[0] | ((unsigned)hs[1] << 16);
            hp.y = (unsigned)hs[2] | ((unsigned)hs[3] << 16);
            lp.x = (unsigned)ls[0] | ((unsigned)ls[1] << 16);
            lp.y = (unsigned)ls[2] | ((unsigned)ls[3] << 16);
            *(uint2*)&Gth[s] = hp;
            *(uint2*)&Gtl[s] = lp;
        }
    }
    __syncthreads();

    // ---- P4: row softmax + I on s_adj ----
    {
        int n = tid >> 2, q = tid & 3;
        float mx = -3.0e38f;
        for (int m = q * 16; m < q * 16 + 16; m++) mx = fmaxf(mx, AJX(n, m));
        s_red[n * 4 + q] = mx;
    }
    __syncthreads();
    if (tid < 64)
        s_rmax[tid] = fmaxf(fmaxf(s_red[tid * 4], s_red[tid * 4 + 1]),
                            fmaxf(s_red[tid * 4 + 2], s_red[tid * 4 + 3]));
    __syncthreads();
    {
        int n = tid >> 2, q = tid & 3;
        float mx = s_rmax[n];
        float sm = 0.f;
        for (int m = q * 16; m < q * 16 + 16; m++) {
            float e = __expf(AJX(n, m) - mx);
            AJX(n, m) = e;
            sm += e;
        }
        s_red[n * 4 + q] = sm;
    }
    __syncthreads();
    if (tid < 64)
        s_rsum[tid] = 1.0f / (s_red[tid * 4] + s_red[tid * 4 + 1] +
                              s_red[tid * 4 + 2] + s_red[tid * 4 + 3]);
    __syncthreads();
    {
        int n = tid >> 2, q = tid & 3;
        float inv = s_rsum[n];
        for (int m = q * 16; m < q * 16 + 16; m++)
            AJX(n, m) = AJX(n, m) * inv + ((n == m) ? 1.f : 0.f);
    }
    __syncthreads();

    // ---- P5: out = adjS @ G + thb -> gout, fused stats ----
    {
        f32x4 oacc[4];
#pragma unroll
        for (int i = 0; i < 4; i++) { f32x4 z = {0.f,0.f,0.f,0.f}; oacc[i] = z; }
#pragma unroll
        for (int kc = 0; kc < 2; kc++) {
            int r = n0 + l16;
            int sf = ((r * 64) + kc * 32 + g16 * 8) ^ ((r & 7) << 3);
            float4 p0 = *(const float4*)&s_adj[sf];
            float4 p1 = *(const float4*)&s_adj[sf + 4];
            U8 ah, al;
            split2(p0.x, p0.y, ah.u[0], al.u[0]);
            split2(p0.z, p0.w, ah.u[1], al.u[1]);
            split2(p1.x, p1.y, ah.u[2], al.u[2]);
            split2(p1.z, p1.w, ah.u[3], al.u[3]);
#pragma unroll
            for (int of = 0; of < 4; of++) {
                int o = of * 16 + l16;
                int s = ((o * 64) + kc * 32 + g16 * 8) ^ ((o & 7) << 3);
                bf16x8 gh = *(const bf16x8*)&Gth[s];
                bf16x8 gl = *(const bf16x8*)&Gtl[s];
                oacc[of] = __builtin_amdgcn_mfma_f32_16x16x32_bf16(ah.v, gh, oacc[of], 0, 0, 0);
                oacc[of] = __builtin_amdgcn_mfma_f32_16x16x32_bf16(ah.v, gl, oacc[of], 0, 0, 0);
                oacc[of] = __builtin_amdgcn_mfma_f32_16x16x32_bf16(al.v, gh, oacc[of], 0, 0, 0);
            }
        }
        float* gb = gout + (size_t)bp * 4096;
#pragma unroll
        for (int of = 0; of < 4; of++) {
            float tb = thb[of * 16 + l16];
            float a = 0.f, b = 0.f;
#pragma unroll
            for (int rg = 0; rg < 4; rg++) {
                int n = n0 + g16 * 4 + rg;
                float v = oacc[of][rg] + tb;
                gb[n * 64 + of * 16 + l16] = v;
                a += v; b += v * v;
            }
            a += __shfl_xor(a, 16); a += __shfl_xor(a, 32);
            b += __shfl_xor(b, 16); b += __shfl_xor(b, 32);
            if (g16 == 0) {
                atomicAdd(&s_s1[of * 16 + l16], a);
                atomicAdd(&s_s2[of * 16 + l16], b);
            }
        }
    }
    __syncthreads();
    if (tid < 64) {
        atomicAdd(&rawg[tid], s_s1[tid]);
        atomicAdd(&rawg[64 + tid], s_s2[tid]);
    }
}

// ---------------- final BN + leaky + pair mean, unchanged ----------------
__global__ __launch_bounds__(TPB) void final_k(const float* __restrict__ gout,
                                               const float* __restrict__ raw,
                                               const float* __restrict__ g,
                                               const float* __restrict__ b,
                                               float* __restrict__ out)
{
    long idx = (long)blockIdx.x * TPB + threadIdx.x;
    if (idx >= 2359296L) return;
    int o = (int)(idx & 63);
    long t = idx >> 6;
    int n = (int)(t & 63);
    long t2 = t >> 6;
    long wd = t2 % 36;
    long bb = t2 / 36;
    const float invN = 1.0f / 73728.0f;
    float m = raw[o] * invN;
    float var = raw[64 + o] * invN - m * m;
    float scale = g[o] * rsqrtf(var + 1e-5f);
    float shift = b[o] - m * scale;
    long bp = bb * 72 + wd * 2;
    float v0 = gout[(bp * 64 + n) * 64 + o] * scale + shift;
    float v1 = gout[((bp + 1) * 64 + n) * 64 + o] * scale + shift;
    v0 = v0 > 0.f ? v0 : 0.01f * v0;
    v1 = v1 > 0.f ? v1 : 0.01f * v1;
    out[idx] = 0.5f * (v0 + v1);
}

// ---------------------------------------------------------------------------
extern "C" void kernel_launch(void* const* d_in, const int* in_sizes, int n_in,
                              void* d_out, int out_size, void* d_ws, size_t ws_size,
                              hipStream_t stream)
{
    (void)in_sizes; (void)n_in; (void)out_size;
    const float* x    = (const float*)d_in[0];
    const float* c1w  = (const float*)d_in[1];
    const float* g1   = (const float*)d_in[2];
    const float* b1   = (const float*)d_in[3];
    const float* c2w  = (const float*)d_in[4];
    const float* g2   = (const float*)d_in[5];
    const float* b2   = (const float*)d_in[6];
    const float* c3w  = (const float*)d_in[7];
    const float* g3   = (const float*)d_in[8];
    const float* b3   = (const float*)d_in[9];
    const float* mapw = (const float*)d_in[10];
    const float* mapb = (const float*)d_in[11];
    const float* thw  = (const float*)d_in[12];
    const float* thb  = (const float*)d_in[13];
    const float* bng  = (const float*)d_in[14];
    const float* bnb  = (const float*)d_in[15];
    float* out = (float*)d_out;
    float* ws  = (float*)d_ws;

    // ws_size is constant across calls -> identical launch sequence every call.
    const size_t WSPLIT_USHORT = 540672;    // conv + map/theta split weights
    const size_t MONO_BYTES = ((size_t)33816576 + 8650752 + ST_FLOATS) * 4
                              + WSPLIT_USHORT * 2;
    int nch = (ws_size >= MONO_BYTES) ? 1 : 2;
    size_t P1SZ = (size_t)(nch == 1 ? 1024 : 512) * 33024;   // [bz][129][256]

    float* P1   = ws;                       // pooled-RAW conv1, [bz][129][256]
    float* P2   = ws + P1SZ;                // pooled-RAW conv2, [1024][66][128]
    float* SPA  = ws;                       // pooled-RAW conv3, [1152][64][128] (P1 dead)
    float* GOUT = ws + 9437184;             // [1152][64][64]  (after SPA, inside P1)
    float* ST   = ws + P1SZ + 8650752;
    unsigned short* WB  = (unsigned short*)(ST + ST_FLOATS);
    unsigned short* WH1 = WB;               // [3][256][64]
    unsigned short* WL1 = WB + 49152;
    unsigned short* WH2 = WB + 98304;       // [3][128][256]
    unsigned short* WL2 = WB + 196608;
    unsigned short* WH3 = WB + 294912;      // [3][256][128]
    unsigned short* WL3 = WB + 393216;
    unsigned short* WMH = WB + 491520;      // [128][128]
    unsigned short* WML = WB + 507904;
    unsigned short* THH = WB + 524288;      // [64][128]
    unsigned short* THL = WB + 532480;

    hipMemsetAsync((void*)ST, 0, ST_FLOATS * sizeof(float), stream);
    split_all_k<<<1056, TPB, 0, stream>>>(c1w, c2w, c3w, mapw, thw, WB);

    if (nch == 1) {
        mconv_k<0, 3, 0, 4><<<dim3(5, 1, 1024), TPB, 0, stream>>>(
            x, WH1, WL1, nullptr, P1, ST + RAW1,
            64, 256, 256, 1, 256, 129, 1024, 0, 0);
        bn_fin_k<<<1, TPB, 0, stream>>>(ST + RAW1, g1, b1, ST + FIN1, 256, 1.0f / 262144.0f);
        mconv_k<1, 3, 1, 2><<<dim3(3, 1, 1024), TPB, 0, stream>>>(
            P1, WH2, WL2, ST + FIN1, P2, ST + RAW2,
            256, 128, 129, 2, 131, 66, 1024, 0, 0);
    } else {
        mconv_k<0, 3, 0, 4><<<dim3(5, 1, 1024), TPB, 0, stream>>>(
            x, WH1, WL1, nullptr, P1, ST + RAW1,
            64, 256, 256, 1, 256, 129, 512, 0, 0);
        bn_fin_k<<<1, TPB, 0, stream>>>(ST + RAW1, g1, b1, ST + FIN1, 256, 1.0f / 262144.0f);
        mconv_k<1, 3, 1, 2><<<dim3(3, 1, 512), TPB, 0, stream>>>(
            P1, WH2, WL2, ST + FIN1, P2, ST + RAW2,
            256, 128, 129, 2, 131, 66, 512, 0, 0);
        mconv_k<0, 5, 0, 4><<<dim3(5, 1, 512), TPB, 0, stream>>>(
            x, WH1, WL1, nullptr, P1, nullptr,
            64, 256, 256, 1, 256, 129, 512, 512, 0);
        mconv_k<1, 3, 1, 2><<<dim3(3, 1, 512), TPB, 0, stream>>>(
            P1, WH2, WL2, ST + FIN1, P2, ST + RAW2,
            256, 128, 129, 2, 131, 66, 512, 0, 512);
    }
    bn_fin_k<<<1, TPB, 0, stream>>>(ST + RAW2, g2, b2, ST + FIN2, 128, 1.0f / 134144.0f);

    mconv_k<1, 4, 1, 4><<<dim3(2, 1, 1024), TPB, 0, stream>>>(
        P2, WH3, WL3, ST + FIN2, SPA, ST + RAW3,
        128, 256, 66, 3, 70, 36, 1024, 0, 0);
    bn_fin_k<<<1, TPB, 0, stream>>>(ST + RAW3, g3, b3, ST + FIN3, 256, 1.0f / 71680.0f);

    // ---- fused graph stage (gemm_nf + adj/softmax + G + out + stats) ----
    graph_f_k<<<1152, TPB, 0, stream>>>(SPA, ST + FIN3, WMH, WML, mapb,
                                        THH, THL, thb, GOUT, ST + RAWG);
    final_k<<<9216, TPB, 0, stream>>>(GOUT, ST + RAWG, bng, bnb, out);
}

// Round 10
// 676.856 us; speedup vs baseline: 1.1303x; 1.0036x over previous
//
#include <hip/hip_runtime.h>

// ---------------------------------------------------------------------------
// MPNN_block_seperate — MFMA split-bf16 conv path + MFMA fused graph stage, v10.
// v9 = 679us.  v10 changes ONE thing: the conv inner MFMA loop is reordered
// term-major.  v9 issued the 3 split-term MFMAs back-to-back into the SAME
// accumulator (true RAW chain at MFMA latency ~16-20cyc, not the ~5cyc issue
// rate); v10 issues {term1 for all cf}, {term2 for all cf}, {term3 for all cf}
// -> same-register reuse distance = CF with no extra VGPR.  Accumulation
// order changes only fp32 rounding (absmax drift negligible).
// ---------------------------------------------------------------------------

#define TPB 256

// stats block offsets (floats)
#define RAW1 0
#define FIN1 512
#define RAW2 1024
#define FIN2 1280
#define RAW3 1536
#define FIN3 2048
#define RAWG 2560
#define ST_FLOATS 2688

typedef __attribute__((ext_vector_type(8))) short bf16x8;
typedef __attribute__((ext_vector_type(4))) float f32x4;

union U8 { unsigned u[4]; bf16x8 v; };

__device__ __forceinline__ unsigned short bf16tr(float x) {
    return (unsigned short)(__float_as_uint(x) >> 16);
}
__device__ __forceinline__ float bf16tof(unsigned short h) {
    return __uint_as_float(((unsigned int)h) << 16);
}
__device__ __forceinline__ void split2(float a, float b, unsigned& h, unsigned& l) {
    unsigned short ha = bf16tr(a), hb = bf16tr(b);
    unsigned short la = bf16tr(a - bf16tof(ha)), lb = bf16tr(b - bf16tof(hb));
    h = (unsigned)ha | ((unsigned)hb << 16);
    l = (unsigned)la | ((unsigned)lb << 16);
}

// ---- one-shot weight split: 3 conv weights ([k][CO][CI] layout) + 2 linear ----
__global__ __launch_bounds__(TPB) void split_all_k(const float* __restrict__ c1w,
                                                   const float* __restrict__ c2w,
                                                   const float* __restrict__ c3w,
                                                   const float* __restrict__ mapw,
                                                   const float* __restrict__ thw,
                                                   unsigned short* __restrict__ WB)
{
    int i = blockIdx.x * TPB + threadIdx.x;
    const float* src;
    unsigned short *wh, *wl;
    int CO, CI, j;
    if (i < 49152)       { src = c1w; wh = WB;          wl = WB + 49152;  CO = 256; CI = 64;  j = i; }
    else if (i < 147456) { src = c2w; wh = WB + 98304;  wl = WB + 196608; CO = 128; CI = 256; j = i - 49152; }
    else if (i < 245760) { src = c3w; wh = WB + 294912; wl = WB + 393216; CO = 256; CI = 128; j = i - 147456; }
    else if (i < 262144) {
        int j2 = i - 245760;
        float v = mapw[j2];
        unsigned short h = bf16tr(v);
        WB[491520 + j2] = h; WB[507904 + j2] = bf16tr(v - bf16tof(h));
        return;
    } else if (i < 270336) {
        int j2 = i - 262144;
        float v = thw[j2];
        unsigned short h = bf16tr(v);
        WB[524288 + j2] = h; WB[532480 + j2] = bf16tr(v - bf16tof(h));
        return;
    } else return;
    int ci = j % CI; int rest = j / CI; int co = rest % CO; int k = rest / CO;
    float v = src[((size_t)co * CI + ci) * 3 + k];
    unsigned short h = bf16tr(v);
    wh[j] = h; wl[j] = bf16tr(v - bf16tof(h));
}

// ---------------------------------------------------------------------------
// MFMA conv core.  Tile: FULL CO x 64 l, 4 waves; wave owns CF*16 channels.
// 64-ci staging phases; MFMA walks the two 32-ci sub-chunks in order.
// Inner loop is TERM-MAJOR: per (k,nf) issue {hh x CF}, {hl x CF}, {lh x CF}.
//   LAYOUT 0: input x [16][256][64][64]; row l at base[l*4096 + ci]
//   LAYOUT 1: input [bz][Lin][CI] row-major
//   STAGEBN:  staging applies relu(v*finIn[ci] + finIn[CI+ci])
//   MODE 3: stats + pooled-RAW -> out[bn0o+bz][j][co]   (store if bz < bzStore)
//   MODE 4: stats + pooled-RAW -> SPA [bq][72][64][128]
//   MODE 5: pooled-RAW only    -> out[bn0o+bz][j][co]
// ---------------------------------------------------------------------------
template<int LAYOUT, int MODE, int STAGEBN, int CF>
__global__ __launch_bounds__(TPB) void mconv_k(const float* __restrict__ in,
                                               const unsigned short* __restrict__ wh,
                                               const unsigned short* __restrict__ wl,
                                               const float* __restrict__ finIn,
                                               float* __restrict__ out,
                                               float* __restrict__ raw,
                                               int CI, int CO, int Lin, int pad,
                                               int Lconv, int Lp,
                                               int bzStore, int bn0x, int bn0o)
{
    __shared__ __align__(16) unsigned short Xh[66 * 72];
    __shared__ __align__(16) unsigned short Xl[66 * 72];
    __shared__ float s_s1[256], s_s2[256];
    constexpr bool STATS = (MODE == 3 || MODE == 4);

    int tid  = threadIdx.x;
    int lane = tid & 63;
    int w    = tid >> 6;
    int g16  = lane >> 4;
    int l16  = lane & 15;
    int wbase = w * (CF * 16);
    int bz   = blockIdx.z;
    int Lbase = (int)blockIdx.x * 64 - 1;
    int gbase = Lbase - pad;

    const float* base;
    int RS;
    if (LAYOUT == 0) {
        int bn = bn0x + bz;
        base = in + (size_t)(bn >> 6) * 1048576 + (size_t)(bn & 63) * 64;
        RS = 4096;
    } else {
        base = in + (size_t)bz * CI * Lin;
        RS = CI;
    }

    if (STATS && tid < CO) { s_s1[tid] = 0.f; s_s2[tid] = 0.f; }

    // rows actually consumed: nf_last*16 + 15 (cols) + 2 (taps) + 1
    int nfl = (Lconv - Lbase - 1) >> 4;
    if (nfl > 3) nfl = 3;
    int rlim = nfl * 16 + 18;
    if (rlim > 66) rlim = 66;
    int items = rlim << 3;

    f32x4 acc[CF][4];
#pragma unroll
    for (int cf = 0; cf < CF; cf++)
#pragma unroll
        for (int nf = 0; nf < 4; nf++) {
            f32x4 z = {0.f, 0.f, 0.f, 0.f};
            acc[cf][nf] = z;
        }

    for (int c0 = 0; c0 < CI; c0 += 64) {
        __syncthreads();
        // ---- stage rlim rows x 64 ci: contiguous float4 loads, 16B LDS writes ----
        for (int idx = tid; idx < items; idx += TPB) {
            int r = idx >> 3, q = idx & 7;
            int gl = gbase + r;
            float4 va = {0.f, 0.f, 0.f, 0.f}, vb = {0.f, 0.f, 0.f, 0.f};
            if (gl >= 0 && gl < Lin) {
                const float* p = base + (size_t)gl * RS + c0 + 8 * q;
                va = *(const float4*)p;
                vb = *(const float4*)(p + 4);
                if (STAGEBN) {
                    const float* sc = finIn + c0 + 8 * q;
                    const float* sh = finIn + CI + c0 + 8 * q;
                    float4 s0 = *(const float4*)sc, s1 = *(const float4*)(sc + 4);
                    float4 h0 = *(const float4*)sh, h1 = *(const float4*)(sh + 4);
                    va.x = fmaxf(va.x * s0.x + h0.x, 0.f);
                    va.y = fmaxf(va.y * s0.y + h0.y, 0.f);
                    va.z = fmaxf(va.z * s0.z + h0.z, 0.f);
                    va.w = fmaxf(va.w * s0.w + h0.w, 0.f);
                    vb.x = fmaxf(vb.x * s1.x + h1.x, 0.f);
                    vb.y = fmaxf(vb.y * s1.y + h1.y, 0.f);
                    vb.z = fmaxf(vb.z * s1.z + h1.z, 0.f);
                    vb.w = fmaxf(vb.w * s1.w + h1.w, 0.f);
                }
            }
            uint4 hu, lu;
            split2(va.x, va.y, hu.x, lu.x);
            split2(va.z, va.w, hu.y, lu.y);
            split2(vb.x, vb.y, hu.z, lu.z);
            split2(vb.z, vb.w, hu.w, lu.w);
            *(uint4*)&Xh[r * 72 + 8 * q] = hu;
            *(uint4*)&Xl[r * 72 + 8 * q] = lu;
        }
        __syncthreads();

        // ---- MFMA over the two 32-ci sub-chunks; term-major (chain-broken) ----
        for (int ci0 = c0; ci0 < c0 + 64; ci0 += 32) {
            int lofs = ci0 & 63;        // 0 or 32 within the staged 64-ci row
#pragma unroll
            for (int k = 0; k < 3; k++) {
                bf16x8 ah[CF], al[CF];
#pragma unroll
                for (int cf = 0; cf < CF; cf++) {
                    size_t wof = ((size_t)(k * CO + wbase + cf * 16 + l16)) * CI
                                 + ci0 + g16 * 8;
                    ah[cf] = *(const bf16x8*)(wh + wof);
                    al[cf] = *(const bf16x8*)(wl + wof);
                }
#pragma unroll
                for (int nf = 0; nf < 4; nf++) {
                    if (Lbase + nf * 16 >= Lconv) continue;
                    int rb = nf * 16 + l16 + k;
                    bf16x8 bh = *(const bf16x8*)&Xh[rb * 72 + lofs + g16 * 8];
                    bf16x8 bl = *(const bf16x8*)&Xl[rb * 72 + lofs + g16 * 8];
#pragma unroll
                    for (int cf = 0; cf < CF; cf++)
                        acc[cf][nf] = __builtin_amdgcn_mfma_f32_16x16x32_bf16(
                            ah[cf], bh, acc[cf][nf], 0, 0, 0);
#pragma unroll
                    for (int cf = 0; cf < CF; cf++)
                        acc[cf][nf] = __builtin_amdgcn_mfma_f32_16x16x32_bf16(
                            ah[cf], bl, acc[cf][nf], 0, 0, 0);
#pragma unroll
                    for (int cf = 0; cf < CF; cf++)
                        acc[cf][nf] = __builtin_amdgcn_mfma_f32_16x16x32_bf16(
                            al[cf], bh, acc[cf][nf], 0, 0, 0);
                }
            }
        }
    }

    if (STATS) {
#pragma unroll
        for (int cf = 0; cf < CF; cf++)
#pragma unroll
            for (int rg = 0; rg < 4; rg++) {
                float a = 0.f, b = 0.f;
#pragma unroll
                for (int nf = 0; nf < 4; nf++) {
                    int l = Lbase + nf * 16 + l16;
                    if (l >= 0 && l < Lconv) {
                        float v = acc[cf][nf][rg];
                        a += v; b += v * v;
                    }
                }
#pragma unroll
                for (int m = 1; m < 16; m <<= 1) {
                    a += __shfl_xor(a, m); b += __shfl_xor(b, m);
                }
                if (l16 == 0) {
                    atomicAdd(&s_s1[wbase + cf * 16 + g16 * 4 + rg], a);
                    atomicAdd(&s_s2[wbase + cf * 16 + g16 * 4 + rg], b);
                }
            }
    }

    if ((MODE == 3 || MODE == 5) && bz < bzStore) {
#pragma unroll
        for (int cf = 0; cf < CF; cf++)
#pragma unroll
            for (int nf = 0; nf < 4; nf++) {
                int l = Lbase + nf * 16 + l16;
                bool ok = (l >= 0 && l < Lconv);
                float4 pv;
#pragma unroll
                for (int rg = 0; rg < 4; rg++) {
                    float v = ok ? acc[cf][nf][rg] : -3.0e38f;
                    float vv = __shfl_xor(v, 1);
                    ((float*)&pv)[rg] = fmaxf(v, vv);
                }
                int j = (l + 1) >> 1;
                if (!(lane & 1) && j < Lp)
                    *(float4*)&out[((size_t)(bn0o + bz) * Lp + j) * CO
                                   + wbase + cf * 16 + g16 * 4] = pv;
            }
    }
    if (MODE == 4) {
#pragma unroll
        for (int cf = 0; cf < CF; cf++)
#pragma unroll
            for (int nf = 0; nf < 4; nf++) {
                int l = Lbase + nf * 16 + l16;
                bool ok = (l >= 0 && l < Lconv);
                int j = (l + 1) >> 1;
#pragma unroll
                for (int rg = 0; rg < 4; rg++) {
                    float v = ok ? acc[cf][nf][rg] : -3.0e38f;
                    float vv = __shfl_xor(v, 1);
                    if (!(lane & 1) && j < Lp) {
                        float pv = fmaxf(v, vv);
                        int co = wbase + cf * 16 + g16 * 4 + rg;
                        int lin = co * 36 + j;
                        int tc = lin >> 7, f = lin & 127;
                        int bq = bz >> 6, n = bz & 63;
                        out[(((size_t)bq * 72 + tc) * 64 + n) * 128 + f] = pv;
                    }
                }
            }
    }

    if (STATS) {
        __syncthreads();
        if (tid < CO) {
            atomicAdd(&raw[tid], s_s1[tid]);
            atomicAdd(&raw[CO + tid], s_s2[tid]);
        }
    }
}

// fin[c] = scale = g*rsqrt(var+eps);  fin[C+c] = shift = b - mean*scale
__global__ __launch_bounds__(TPB) void bn_fin_k(const float* __restrict__ raw,
                                                const float* __restrict__ g,
                                                const float* __restrict__ b,
                                                float* __restrict__ fin, int C, float invN)
{
    int c = threadIdx.x + blockIdx.x * TPB;
    if (c < C) {
        float m = raw[c] * invN;
        float v = raw[C + c] * invN - m * m;
        float sc = g[c] * rsqrtf(v + 1e-5f);
        fin[c] = sc;
        fin[C + c] = b[c] - m * sc;
    }
}

// ---------------------------------------------------------------------------
// Fused graph stage on MFMA (unchanged from v9).  Gt aliases NF LDS.
// ---------------------------------------------------------------------------
#define AJX(n,m) s_adj[(((n) * 64 + (m)) ^ (((n) & 7) << 3))]

__global__ __launch_bounds__(TPB) void graph_f_k(const float* __restrict__ spa,
                                                 const float* __restrict__ fin3,
                                                 const unsigned short* __restrict__ wmh,
                                                 const unsigned short* __restrict__ wml,
                                                 const float* __restrict__ mapb,
                                                 const unsigned short* __restrict__ thh,
                                                 const unsigned short* __restrict__ thl,
                                                 const float* __restrict__ thb,
                                                 float* __restrict__ gout,
                                                 float* __restrict__ rawg)
{
    __shared__ __align__(16) char smem[49152];
    unsigned short* NFh = (unsigned short*)smem;             // [64][128] swz, 16KB
    unsigned short* NFl = (unsigned short*)(smem + 16384);   // 16KB
    float* s_adj        = (float*)(smem + 32768);            // [64][64] swz, 16KB
    unsigned short* Gth = (unsigned short*)smem;             // alias NFh (dead)
    unsigned short* Gtl = (unsigned short*)(smem + 16384);   // alias NFl (dead)
    __shared__ float s_red[256], s_rmax[64], s_rsum[64], s_s1[64], s_s2[64];

    int tid  = threadIdx.x;
    int lane = tid & 63;
    int w    = tid >> 6;
    int g16  = lane >> 4, l16 = lane & 15;
    int n0   = w * 16;
    int bp   = blockIdx.x;
    int tcb  = (bp % 72) * 128;

    if (tid < 64) { s_s1[tid] = 0.f; s_s2[tid] = 0.f; }

    // ---- P0: A = relu(bn3(spa)) for rows n0+l16 -> registers (split bf16) ----
    unsigned aH[16], aL[16];
    {
        const float* ar = spa + ((size_t)bp * 64 + n0 + l16) * 128;
#pragma unroll
        for (int kc = 0; kc < 4; kc++) {
            int kb = kc * 32 + g16 * 8;
            float4 x0 = *(const float4*)(ar + kb);
            float4 x1 = *(const float4*)(ar + kb + 4);
            float v[8] = {x0.x, x0.y, x0.z, x0.w, x1.x, x1.y, x1.z, x1.w};
#pragma unroll
            for (int j = 0; j < 8; j++) {
                int co = ((tcb + kb + j) * 29128) >> 20;   // exact /36 for x<32768
                float z = v[j] * fin3[co] + fin3[256 + co];
                v[j] = z > 0.f ? z : 0.f;
            }
            split2(v[0], v[1], aH[kc*4+0], aL[kc*4+0]);
            split2(v[2], v[3], aH[kc*4+1], aL[kc*4+1]);
            split2(v[4], v[5], aH[kc*4+2], aL[kc*4+2]);
            split2(v[6], v[7], aH[kc*4+3], aL[kc*4+3]);
        }
    }

    // ---- P1: nf = A @ map_w^T + mapb  -> NFh/NFl ----
    {
        f32x4 acc[8];
#pragma unroll
        for (int i = 0; i < 8; i++) { f32x4 z = {0.f,0.f,0.f,0.f}; acc[i] = z; }
#pragma unroll
        for (int ff = 0; ff < 8; ff++) {
#pragma unroll
            for (int kc = 0; kc < 4; kc++) {
                U8 ah, al;
#pragma unroll
                for (int u = 0; u < 4; u++) { ah.u[u] = aH[kc*4+u]; al.u[u] = aL[kc*4+u]; }
                size_t wo = (size_t)(ff * 16 + l16) * 128 + kc * 32 + g16 * 8;
                bf16x8 bh = *(const bf16x8*)(wmh + wo);
                bf16x8 bl = *(const bf16x8*)(wml + wo);
                acc[ff] = __builtin_amdgcn_mfma_f32_16x16x32_bf16(ah.v, bh, acc[ff], 0, 0, 0);
                acc[ff] = __builtin_amdgcn_mfma_f32_16x16x32_bf16(ah.v, bl, acc[ff], 0, 0, 0);
                acc[ff] = __builtin_amdgcn_mfma_f32_16x16x32_bf16(al.v, bh, acc[ff], 0, 0, 0);
            }
        }
#pragma unroll
        for (int ff = 0; ff < 8; ff++) {
            float bv = mapb[ff * 16 + l16];
#pragma unroll
            for (int rg = 0; rg < 4; rg++) {
                int n = n0 + g16 * 4 + rg;
                float v = acc[ff][rg] + bv;
                int s = ((n * 128) + ff * 16 + l16) ^ ((n & 7) << 3);
                unsigned short h = bf16tr(v);
                NFh[s] = h;
                NFl[s] = bf16tr(v - bf16tof(h));
            }
        }
    }
    __syncthreads();

    // ---- preload this wave's NF rows (A-operand for adj and G) ----
    bf16x8 nh[4], nl[4];
#pragma unroll
    for (int kc = 0; kc < 4; kc++) {
        int r = n0 + l16;
        int s = ((r * 128) + kc * 32 + g16 * 8) ^ ((r & 7) << 3);
        nh[kc] = *(const bf16x8*)&NFh[s];
        nl[kc] = *(const bf16x8*)&NFl[s];
    }

    // ---- P2: adj = nf @ nf^T  (diag -1e8, leaky) -> s_adj ----
    {
        f32x4 aj[4];
#pragma unroll
        for (int i = 0; i < 4; i++) { f32x4 z = {0.f,0.f,0.f,0.f}; aj[i] = z; }
#pragma unroll
        for (int mf = 0; mf < 4; mf++) {
#pragma unroll
            for (int kc = 0; kc < 4; kc++) {
                int r = mf * 16 + l16;
                int s = ((r * 128) + kc * 32 + g16 * 8) ^ ((r & 7) << 3);
                bf16x8 bh = *(const bf16x8*)&NFh[s];
                bf16x8 bl = *(const bf16x8*)&NFl[s];
                aj[mf] = __builtin_amdgcn_mfma_f32_16x16x32_bf16(nh[kc], bh, aj[mf], 0, 0, 0);
                aj[mf] = __builtin_amdgcn_mfma_f32_16x16x32_bf16(nh[kc], bl, aj[mf], 0, 0, 0);
                aj[mf] = __builtin_amdgcn_mfma_f32_16x16x32_bf16(nl[kc], bh, aj[mf], 0, 0, 0);
            }
        }
#pragma unroll
        for (int mf = 0; mf < 4; mf++)
#pragma unroll
            for (int rg = 0; rg < 4; rg++) {
                int n = n0 + g16 * 4 + rg, m = mf * 16 + l16;
                float v = aj[mf][rg];
                if (n == m) v -= 1e8f;
                v = v > 0.f ? v : 0.01f * v;
                AJX(n, m) = v;
            }
    }
    __syncthreads();   // all NF reads done before Gt overwrites the aliased LDS

    // ---- P3: G = nf @ theta^T -> Gt (transposed, split bf16; aliases NF) ----
    {
        f32x4 gg[4];
#pragma unroll
        for (int i = 0; i < 4; i++) { f32x4 z = {0.f,0.f,0.f,0.f}; gg[i] = z; }
#pragma unroll
        for (int of = 0; of < 4; of++) {
#pragma unroll
            for (int kc = 0; kc < 4; kc++) {
                size_t to = (size_t)(of * 16 + l16) * 128 + kc * 32 + g16 * 8;
                bf16x8 th_ = *(const bf16x8*)(thh + to);
                bf16x8 tl_ = *(const bf16x8*)(thl + to);
                gg[of] = __builtin_amdgcn_mfma_f32_16x16x32_bf16(nh[kc], th_, gg[of], 0, 0, 0);
                gg[of] = __builtin_amdgcn_mfma_f32_16x16x32_bf16(nh[kc], tl_, gg[of], 0, 0, 0);
                gg[of] = __builtin_amdgcn_mfma_f32_16x16x32_bf16(nl[kc], th_, gg[of], 0, 0, 0);
            }
        }
#pragma unroll
        for (int of = 0; of < 4; of++) {
            unsigned short hs[4], ls[4];
#pragma unroll
            for (int rg = 0; rg < 4; rg++) {
                float v = gg[of][rg];
                hs[rg] = bf16tr(v);
                ls[rg] = bf16tr(v - bf16tof(hs[rg]));
            }
            int o = of * 16 + l16;
            int m = n0 + g16 * 4;            // 4 consecutive m
            int s = ((o * 64) + m) ^ ((o & 7) << 3);
            uint2 hp, lp;
            hp.x = (unsigned)hs[0] | ((unsigned)hs[1] << 16);
            hp.y = (unsigned)hs[2] | ((unsigned)hs[3] << 16);
            lp.x = (unsigned)ls[0] | ((unsigned)ls[1] << 16);
            lp.y = (unsigned)ls[2] | ((unsigned)ls[3] << 16);
            *(uint2*)&Gth[s] = hp;
            *(uint2*)&Gtl[s] = lp;
        }
    }
    __syncthreads();

    // ---- P4: row softmax + I on s_adj ----
    {
        int n = tid >> 2, q = tid & 3;
        float mx = -3.0e38f;
        for (int m = q * 16; m < q * 16 + 16; m++) mx = fmaxf(mx, AJX(n, m));
        s_red[n * 4 + q] = mx;
    }
    __syncthreads();
    if (tid < 64)
        s_rmax[tid] = fmaxf(fmaxf(s_red[tid * 4], s_red[tid * 4 + 1]),
                            fmaxf(s_red[tid * 4 + 2], s_red[tid * 4 + 3]));
    __syncthreads();
    {
        int n = tid >> 2, q = tid & 3;
        float mx = s_rmax[n];
        float sm = 0.f;
        for (int m = q * 16; m < q * 16 + 16; m++) {
            float e = __expf(AJX(n, m) - mx);
            AJX(n, m) = e;
            sm += e;
        }
        s_red[n * 4 + q] = sm;
    }
    __syncthreads();
    if (tid < 64)
        s_rsum[tid] = 1.0f / (s_red[tid * 4] + s_red[tid * 4 + 1] +
                              s_red[tid * 4 + 2] + s_red[tid * 4 + 3]);
    __syncthreads();
    {
        int n = tid >> 2, q = tid & 3;
        float inv = s_rsum[n];
        for (int m = q * 16; m < q * 16 + 16; m++)
            AJX(n, m) = AJX(n, m) * inv + ((n == m) ? 1.f : 0.f);
    }
    __syncthreads();

    // ---- P5: out = adjS @ G + thb -> gout, fused stats ----
    {
        f32x4 oacc[4];
#pragma unroll
        for (int i = 0; i < 4; i++) { f32x4 z = {0.f,0.f,0.f,0.f}; oacc[i] = z; }
#pragma unroll
        for (int kc = 0; kc < 2; kc++) {
            int r = n0 + l16;
            int sf = ((r * 64) + kc * 32 + g16 * 8) ^ ((r & 7) << 3);
            float4 p0 = *(const float4*)&s_adj[sf];
            float4 p1 = *(const float4*)&s_adj[sf + 4];
            U8 ah, al;
            split2(p0.x, p0.y, ah.u[0], al.u[0]);
            split2(p0.z, p0.w, ah.u[1], al.u[1]);
            split2(p1.x, p1.y, ah.u[2], al.u[2]);
            split2(p1.z, p1.w, ah.u[3], al.u[3]);
#pragma unroll
            for (int of = 0; of < 4; of++) {
                int o = of * 16 + l16;
                int s = ((o * 64) + kc * 32 + g16 * 8) ^ ((o & 7) << 3);
                bf16x8 gh = *(const bf16x8*)&Gth[s];
                bf16x8 gl = *(const bf16x8*)&Gtl[s];
                oacc[of] = __builtin_amdgcn_mfma_f32_16x16x32_bf16(ah.v, gh, oacc[of], 0, 0, 0);
                oacc[of] = __builtin_amdgcn_mfma_f32_16x16x32_bf16(ah.v, gl, oacc[of], 0, 0, 0);
                oacc[of] = __builtin_amdgcn_mfma_f32_16x16x32_bf16(al.v, gh, oacc[of], 0, 0, 0);
            }
        }
        float* gb = gout + (size_t)bp * 4096;
#pragma unroll
        for (int of = 0; of < 4; of++) {
            float tb = thb[of * 16 + l16];
            float a = 0.f, b = 0.f;
#pragma unroll
            for (int rg = 0; rg < 4; rg++) {
                int n = n0 + g16 * 4 + rg;
                float v = oacc[of][rg] + tb;
                gb[n * 64 + of * 16 + l16] = v;
                a += v; b += v * v;
            }
            a += __shfl_xor(a, 16); a += __shfl_xor(a, 32);
            b += __shfl_xor(b, 16); b += __shfl_xor(b, 32);
            if (g16 == 0) {
                atomicAdd(&s_s1[of * 16 + l16], a);
                atomicAdd(&s_s2[of * 16 + l16], b);
            }
        }
    }
    __syncthreads();
    if (tid < 64) {
        atomicAdd(&rawg[tid], s_s1[tid]);
        atomicAdd(&rawg[64 + tid], s_s2[tid]);
    }
}

// ---------------- final BN + leaky + pair mean, unchanged ----------------
__global__ __launch_bounds__(TPB) void final_k(const float* __restrict__ gout,
                                               const float* __restrict__ raw,
                                               const float* __restrict__ g,
                                               const float* __restrict__ b,
                                               float* __restrict__ out)
{
    long idx = (long)blockIdx.x * TPB + threadIdx.x;
    if (idx >= 2359296L) return;
    int o = (int)(idx & 63);
    long t = idx >> 6;
    int n = (int)(t & 63);
    long t2 = t >> 6;
    long wd = t2 % 36;
    long bb = t2 / 36;
    const float invN = 1.0f / 73728.0f;
    float m = raw[o] * invN;
    float var = raw[64 + o] * invN - m * m;
    float scale = g[o] * rsqrtf(var + 1e-5f);
    float shift = b[o] - m * scale;
    long bp = bb * 72 + wd * 2;
    float v0 = gout[(bp * 64 + n) * 64 + o] * scale + shift;
    float v1 = gout[((bp + 1) * 64 + n) * 64 + o] * scale + shift;
    v0 = v0 > 0.f ? v0 : 0.01f * v0;
    v1 = v1 > 0.f ? v1 : 0.01f * v1;
    out[idx] = 0.5f * (v0 + v1);
}

// ---------------------------------------------------------------------------
extern "C" void kernel_launch(void* const* d_in, const int* in_sizes, int n_in,
                              void* d_out, int out_size, void* d_ws, size_t ws_size,
                              hipStream_t stream)
{
    (void)in_sizes; (void)n_in; (void)out_size;
    const float* x    = (const float*)d_in[0];
    const float* c1w  = (const float*)d_in[1];
    const float* g1   = (const float*)d_in[2];
    const float* b1   = (const float*)d_in[3];
    const float* c2w  = (const float*)d_in[4];
    const float* g2   = (const float*)d_in[5];
    const float* b2   = (const float*)d_in[6];
    const float* c3w  = (const float*)d_in[7];
    const float* g3   = (const float*)d_in[8];
    const float* b3   = (const float*)d_in[9];
    const float* mapw = (const float*)d_in[10];
    const float* mapb = (const float*)d_in[11];
    const float* thw  = (const float*)d_in[12];
    const float* thb  = (const float*)d_in[13];
    const float* bng  = (const float*)d_in[14];
    const float* bnb  = (const float*)d_in[15];
    float* out = (float*)d_out;
    float* ws  = (float*)d_ws;

    // ws_size is constant across calls -> identical launch sequence every call.
    const size_t WSPLIT_USHORT = 540672;    // conv + map/theta split weights
    const size_t MONO_BYTES = ((size_t)33816576 + 8650752 + ST_FLOATS) * 4
                              + WSPLIT_USHORT * 2;
    int nch = (ws_size >= MONO_BYTES) ? 1 : 2;
    size_t P1SZ = (size_t)(nch == 1 ? 1024 : 512) * 33024;   // [bz][129][256]

    float* P1   = ws;                       // pooled-RAW conv1, [bz][129][256]
    float* P2   = ws + P1SZ;                // pooled-RAW conv2, [1024][66][128]
    float* SPA  = ws;                       // pooled-RAW conv3, [1152][64][128] (P1 dead)
    float* GOUT = ws + 9437184;             // [1152][64][64]  (after SPA, inside P1)
    float* ST   = ws + P1SZ + 8650752;
    unsigned short* WB  = (unsigned short*)(ST + ST_FLOATS);
    unsigned short* WH1 = WB;               // [3][256][64]
    unsigned short* WL1 = WB + 49152;
    unsigned short* WH2 = WB + 98304;       // [3][128][256]
    unsigned short* WL2 = WB + 196608;
    unsigned short* WH3 = WB + 294912;      // [3][256][128]
    unsigned short* WL3 = WB + 393216;
    unsigned short* WMH = WB + 491520;      // [128][128]
    unsigned short* WML = WB + 507904;
    unsigned short* THH = WB + 524288;      // [64][128]
    unsigned short* THL = WB + 532480;

    hipMemsetAsync((void*)ST, 0, ST_FLOATS * sizeof(float), stream);
    split_all_k<<<1056, TPB, 0, stream>>>(c1w, c2w, c3w, mapw, thw, WB);

    if (nch == 1) {
        mconv_k<0, 3, 0, 4><<<dim3(5, 1, 1024), TPB, 0, stream>>>(
            x, WH1, WL1, nullptr, P1, ST + RAW1,
            64, 256, 256, 1, 256, 129, 1024, 0, 0);
        bn_fin_k<<<1, TPB, 0, stream>>>(ST + RAW1, g1, b1, ST + FIN1, 256, 1.0f / 262144.0f);
        mconv_k<1, 3, 1, 2><<<dim3(3, 1, 1024), TPB, 0, stream>>>(
            P1, WH2, WL2, ST + FIN1, P2, ST + RAW2,
            256, 128, 129, 2, 131, 66, 1024, 0, 0);
    } else {
        mconv_k<0, 3, 0, 4><<<dim3(5, 1, 1024), TPB, 0, stream>>>(
            x, WH1, WL1, nullptr, P1, ST + RAW1,
            64, 256, 256, 1, 256, 129, 512, 0, 0);
        bn_fin_k<<<1, TPB, 0, stream>>>(ST + RAW1, g1, b1, ST + FIN1, 256, 1.0f / 262144.0f);
        mconv_k<1, 3, 1, 2><<<dim3(3, 1, 512), TPB, 0, stream>>>(
            P1, WH2, WL2, ST + FIN1, P2, ST + RAW2,
            256, 128, 129, 2, 131, 66, 512, 0, 0);
        mconv_k<0, 5, 0, 4><<<dim3(5, 1, 512), TPB, 0, stream>>>(
            x, WH1, WL1, nullptr, P1, nullptr,
            64, 256, 256, 1, 256, 129, 512, 512, 0);
        mconv_k<1, 3, 1, 2><<<dim3(3, 1, 512), TPB, 0, stream>>>(
            P1, WH2, WL2, ST + FIN1, P2, ST + RAW2,
            256, 128, 129, 2, 131, 66, 512, 0, 512);
    }
    bn_fin_k<<<1, TPB, 0, stream>>>(ST + RAW2, g2, b2, ST + FIN2, 128, 1.0f / 134144.0f);

    mconv_k<1, 4, 1, 4><<<dim3(2, 1, 1024), TPB, 0, stream>>>(
        P2, WH3, WL3, ST + FIN2, SPA, ST + RAW3,
        128, 256, 66, 3, 70, 36, 1024, 0, 0);
    bn_fin_k<<<1, TPB, 0, stream>>>(ST + RAW3, g3, b3, ST + FIN3, 256, 1.0f / 71680.0f);

    // ---- fused graph stage (gemm_nf + adj/softmax + G + out + stats) ----
    graph_f_k<<<1152, TPB, 0, stream>>>(SPA, ST + FIN3, WMH, WML, mapb,
                                        THH, THL, thb, GOUT, ST + RAWG);
    final_k<<<9216, TPB, 0, stream>>>(GOUT, ST + RAWG, bng, bnb, out);
}

// Round 11
// 643.917 us; speedup vs baseline: 1.1882x; 1.0512x over previous
//
#include <hip/hip_runtime.h>

// ---------------------------------------------------------------------------
// MPNN_block_seperate — MFMA split-bf16 conv path + MFMA fused graph stage, v11.
// v10 = 677us, term-major reorder null -> MFMA chain not the stall.  Cycle
// accounting showed ~20us of per-block work vs 188us measured: the missing
// serializer is the stats epilogue's global atomics (conv1: 5120 blocks x 512
// atomicAdd to the SAME 512 floats = 82k serialized RMWs per cache line).
// v11 spreads stats into 64 slots (slot = bz&63): per-line atomic chains drop
// 64x.  bn_fin_k sums slots; redg_k folds graph slots before final_k.
// Everything else identical to v10.
// ---------------------------------------------------------------------------

#define TPB 256
#define NSL 64

// stats block offsets (floats) — slotted
#define RAW1 0                      // [64][512]
#define FIN1 (NSL * 512)            // 512
#define RAW2 (FIN1 + 512)           // [64][256]
#define FIN2 (RAW2 + NSL * 256)     // 256
#define RAW3 (FIN2 + 256)           // [64][512]
#define FIN3 (RAW3 + NSL * 512)     // 512
#define RAWG (FIN3 + 512)           // [64][128]
#define RAWGF (RAWG + NSL * 128)    // 128
#define ST_FLOATS (RAWGF + 128)

typedef __attribute__((ext_vector_type(8))) short bf16x8;
typedef __attribute__((ext_vector_type(4))) float f32x4;

union U8 { unsigned u[4]; bf16x8 v; };

__device__ __forceinline__ unsigned short bf16tr(float x) {
    return (unsigned short)(__float_as_uint(x) >> 16);
}
__device__ __forceinline__ float bf16tof(unsigned short h) {
    return __uint_as_float(((unsigned int)h) << 16);
}
__device__ __forceinline__ void split2(float a, float b, unsigned& h, unsigned& l) {
    unsigned short ha = bf16tr(a), hb = bf16tr(b);
    unsigned short la = bf16tr(a - bf16tof(ha)), lb = bf16tr(b - bf16tof(hb));
    h = (unsigned)ha | ((unsigned)hb << 16);
    l = (unsigned)la | ((unsigned)lb << 16);
}

// ---- one-shot weight split: 3 conv weights ([k][CO][CI] layout) + 2 linear ----
__global__ __launch_bounds__(TPB) void split_all_k(const float* __restrict__ c1w,
                                                   const float* __restrict__ c2w,
                                                   const float* __restrict__ c3w,
                                                   const float* __restrict__ mapw,
                                                   const float* __restrict__ thw,
                                                   unsigned short* __restrict__ WB)
{
    int i = blockIdx.x * TPB + threadIdx.x;
    const float* src;
    unsigned short *wh, *wl;
    int CO, CI, j;
    if (i < 49152)       { src = c1w; wh = WB;          wl = WB + 49152;  CO = 256; CI = 64;  j = i; }
    else if (i < 147456) { src = c2w; wh = WB + 98304;  wl = WB + 196608; CO = 128; CI = 256; j = i - 49152; }
    else if (i < 245760) { src = c3w; wh = WB + 294912; wl = WB + 393216; CO = 256; CI = 128; j = i - 147456; }
    else if (i < 262144) {
        int j2 = i - 245760;
        float v = mapw[j2];
        unsigned short h = bf16tr(v);
        WB[491520 + j2] = h; WB[507904 + j2] = bf16tr(v - bf16tof(h));
        return;
    } else if (i < 270336) {
        int j2 = i - 262144;
        float v = thw[j2];
        unsigned short h = bf16tr(v);
        WB[524288 + j2] = h; WB[532480 + j2] = bf16tr(v - bf16tof(h));
        return;
    } else return;
    int ci = j % CI; int rest = j / CI; int co = rest % CO; int k = rest / CO;
    float v = src[((size_t)co * CI + ci) * 3 + k];
    unsigned short h = bf16tr(v);
    wh[j] = h; wl[j] = bf16tr(v - bf16tof(h));
}

// ---------------------------------------------------------------------------
// MFMA conv core.  Tile: FULL CO x 64 l, 4 waves; wave owns CF*16 channels.
// Stats go to slot (bz & 63) of raw[NSL][2*CO] — spread atomics.
// ---------------------------------------------------------------------------
template<int LAYOUT, int MODE, int STAGEBN, int CF>
__global__ __launch_bounds__(TPB) void mconv_k(const float* __restrict__ in,
                                               const unsigned short* __restrict__ wh,
                                               const unsigned short* __restrict__ wl,
                                               const float* __restrict__ finIn,
                                               float* __restrict__ out,
                                               float* __restrict__ raw,
                                               int CI, int CO, int Lin, int pad,
                                               int Lconv, int Lp,
                                               int bzStore, int bn0x, int bn0o)
{
    __shared__ __align__(16) unsigned short Xh[66 * 72];
    __shared__ __align__(16) unsigned short Xl[66 * 72];
    __shared__ float s_s1[256], s_s2[256];
    constexpr bool STATS = (MODE == 3 || MODE == 4);

    int tid  = threadIdx.x;
    int lane = tid & 63;
    int w    = tid >> 6;
    int g16  = lane >> 4;
    int l16  = lane & 15;
    int wbase = w * (CF * 16);
    int bz   = blockIdx.z;
    int Lbase = (int)blockIdx.x * 64 - 1;
    int gbase = Lbase - pad;

    const float* base;
    int RS;
    if (LAYOUT == 0) {
        int bn = bn0x + bz;
        base = in + (size_t)(bn >> 6) * 1048576 + (size_t)(bn & 63) * 64;
        RS = 4096;
    } else {
        base = in + (size_t)bz * CI * Lin;
        RS = CI;
    }

    if (STATS && tid < CO) { s_s1[tid] = 0.f; s_s2[tid] = 0.f; }

    // rows actually consumed: nf_last*16 + 15 (cols) + 2 (taps) + 1
    int nfl = (Lconv - Lbase - 1) >> 4;
    if (nfl > 3) nfl = 3;
    int rlim = nfl * 16 + 18;
    if (rlim > 66) rlim = 66;
    int items = rlim << 3;

    f32x4 acc[CF][4];
#pragma unroll
    for (int cf = 0; cf < CF; cf++)
#pragma unroll
        for (int nf = 0; nf < 4; nf++) {
            f32x4 z = {0.f, 0.f, 0.f, 0.f};
            acc[cf][nf] = z;
        }

    for (int c0 = 0; c0 < CI; c0 += 64) {
        __syncthreads();
        // ---- stage rlim rows x 64 ci: contiguous float4 loads, 16B LDS writes ----
        for (int idx = tid; idx < items; idx += TPB) {
            int r = idx >> 3, q = idx & 7;
            int gl = gbase + r;
            float4 va = {0.f, 0.f, 0.f, 0.f}, vb = {0.f, 0.f, 0.f, 0.f};
            if (gl >= 0 && gl < Lin) {
                const float* p = base + (size_t)gl * RS + c0 + 8 * q;
                va = *(const float4*)p;
                vb = *(const float4*)(p + 4);
                if (STAGEBN) {
                    const float* sc = finIn + c0 + 8 * q;
                    const float* sh = finIn + CI + c0 + 8 * q;
                    float4 s0 = *(const float4*)sc, s1 = *(const float4*)(sc + 4);
                    float4 h0 = *(const float4*)sh, h1 = *(const float4*)(sh + 4);
                    va.x = fmaxf(va.x * s0.x + h0.x, 0.f);
                    va.y = fmaxf(va.y * s0.y + h0.y, 0.f);
                    va.z = fmaxf(va.z * s0.z + h0.z, 0.f);
                    va.w = fmaxf(va.w * s0.w + h0.w, 0.f);
                    vb.x = fmaxf(vb.x * s1.x + h1.x, 0.f);
                    vb.y = fmaxf(vb.y * s1.y + h1.y, 0.f);
                    vb.z = fmaxf(vb.z * s1.z + h1.z, 0.f);
                    vb.w = fmaxf(vb.w * s1.w + h1.w, 0.f);
                }
            }
            uint4 hu, lu;
            split2(va.x, va.y, hu.x, lu.x);
            split2(va.z, va.w, hu.y, lu.y);
            split2(vb.x, vb.y, hu.z, lu.z);
            split2(vb.z, vb.w, hu.w, lu.w);
            *(uint4*)&Xh[r * 72 + 8 * q] = hu;
            *(uint4*)&Xl[r * 72 + 8 * q] = lu;
        }
        __syncthreads();

        // ---- MFMA over the two 32-ci sub-chunks; term-major ----
        for (int ci0 = c0; ci0 < c0 + 64; ci0 += 32) {
            int lofs = ci0 & 63;        // 0 or 32 within the staged 64-ci row
#pragma unroll
            for (int k = 0; k < 3; k++) {
                bf16x8 ah[CF], al[CF];
#pragma unroll
                for (int cf = 0; cf < CF; cf++) {
                    size_t wof = ((size_t)(k * CO + wbase + cf * 16 + l16)) * CI
                                 + ci0 + g16 * 8;
                    ah[cf] = *(const bf16x8*)(wh + wof);
                    al[cf] = *(const bf16x8*)(wl + wof);
                }
#pragma unroll
                for (int nf = 0; nf < 4; nf++) {
                    if (Lbase + nf * 16 >= Lconv) continue;
                    int rb = nf * 16 + l16 + k;
                    bf16x8 bh = *(const bf16x8*)&Xh[rb * 72 + lofs + g16 * 8];
                    bf16x8 bl = *(const bf16x8*)&Xl[rb * 72 + lofs + g16 * 8];
#pragma unroll
                    for (int cf = 0; cf < CF; cf++)
                        acc[cf][nf] = __builtin_amdgcn_mfma_f32_16x16x32_bf16(
                            ah[cf], bh, acc[cf][nf], 0, 0, 0);
#pragma unroll
                    for (int cf = 0; cf < CF; cf++)
                        acc[cf][nf] = __builtin_amdgcn_mfma_f32_16x16x32_bf16(
                            ah[cf], bl, acc[cf][nf], 0, 0, 0);
#pragma unroll
                    for (int cf = 0; cf < CF; cf++)
                        acc[cf][nf] = __builtin_amdgcn_mfma_f32_16x16x32_bf16(
                            al[cf], bh, acc[cf][nf], 0, 0, 0);
                }
            }
        }
    }

    if (STATS) {
#pragma unroll
        for (int cf = 0; cf < CF; cf++)
#pragma unroll
            for (int rg = 0; rg < 4; rg++) {
                float a = 0.f, b = 0.f;
#pragma unroll
                for (int nf = 0; nf < 4; nf++) {
                    int l = Lbase + nf * 16 + l16;
                    if (l >= 0 && l < Lconv) {
                        float v = acc[cf][nf][rg];
                        a += v; b += v * v;
                    }
                }
#pragma unroll
                for (int m = 1; m < 16; m <<= 1) {
                    a += __shfl_xor(a, m); b += __shfl_xor(b, m);
                }
                if (l16 == 0) {
                    atomicAdd(&s_s1[wbase + cf * 16 + g16 * 4 + rg], a);
                    atomicAdd(&s_s2[wbase + cf * 16 + g16 * 4 + rg], b);
                }
            }
    }

    if ((MODE == 3 || MODE == 5) && bz < bzStore) {
#pragma unroll
        for (int cf = 0; cf < CF; cf++)
#pragma unroll
            for (int nf = 0; nf < 4; nf++) {
                int l = Lbase + nf * 16 + l16;
                bool ok = (l >= 0 && l < Lconv);
                float4 pv;
#pragma unroll
                for (int rg = 0; rg < 4; rg++) {
                    float v = ok ? acc[cf][nf][rg] : -3.0e38f;
                    float vv = __shfl_xor(v, 1);
                    ((float*)&pv)[rg] = fmaxf(v, vv);
                }
                int j = (l + 1) >> 1;
                if (!(lane & 1) && j < Lp)
                    *(float4*)&out[((size_t)(bn0o + bz) * Lp + j) * CO
                                   + wbase + cf * 16 + g16 * 4] = pv;
            }
    }
    if (MODE == 4) {
#pragma unroll
        for (int cf = 0; cf < CF; cf++)
#pragma unroll
            for (int nf = 0; nf < 4; nf++) {
                int l = Lbase + nf * 16 + l16;
                bool ok = (l >= 0 && l < Lconv);
                int j = (l + 1) >> 1;
#pragma unroll
                for (int rg = 0; rg < 4; rg++) {
                    float v = ok ? acc[cf][nf][rg] : -3.0e38f;
                    float vv = __shfl_xor(v, 1);
                    if (!(lane & 1) && j < Lp) {
                        float pv = fmaxf(v, vv);
                        int co = wbase + cf * 16 + g16 * 4 + rg;
                        int lin = co * 36 + j;
                        int tc = lin >> 7, f = lin & 127;
                        int bq = bz >> 6, n = bz & 63;
                        out[(((size_t)bq * 72 + tc) * 64 + n) * 128 + f] = pv;
                    }
                }
            }
    }

    if (STATS) {
        __syncthreads();
        int sl = bz & (NSL - 1);
        if (tid < CO) {
            atomicAdd(&raw[sl * 2 * CO + tid], s_s1[tid]);
            atomicAdd(&raw[sl * 2 * CO + CO + tid], s_s2[tid]);
        }
    }
}

// fin[c] = scale = g*rsqrt(var+eps);  fin[C+c] = shift = b - mean*scale
// raw is slotted: [NSL][2C]
__global__ __launch_bounds__(TPB) void bn_fin_k(const float* __restrict__ raw,
                                                const float* __restrict__ g,
                                                const float* __restrict__ b,
                                                float* __restrict__ fin, int C, float invN)
{
    int c = threadIdx.x + blockIdx.x * TPB;
    if (c < C) {
        float s1 = 0.f, s2 = 0.f;
        for (int s = 0; s < NSL; s++) {
            s1 += raw[s * 2 * C + c];
            s2 += raw[s * 2 * C + C + c];
        }
        float m = s1 * invN;
        float v = s2 * invN - m * m;
        float sc = g[c] * rsqrtf(v + 1e-5f);
        fin[c] = sc;
        fin[C + c] = b[c] - m * sc;
    }
}

// ---- fold graph stat slots [NSL][128] -> [128] ----
__global__ __launch_bounds__(128) void redg_k(const float* __restrict__ rawgS,
                                              float* __restrict__ rawgF)
{
    int t = threadIdx.x;
    float s = 0.f;
    for (int i = 0; i < NSL; i++) s += rawgS[i * 128 + t];
    rawgF[t] = s;
}

// ---------------------------------------------------------------------------
// Fused graph stage on MFMA.  Gt aliases NF LDS.  Stats to slot (bp & 63).
// ---------------------------------------------------------------------------
#define AJX(n,m) s_adj[(((n) * 64 + (m)) ^ (((n) & 7) << 3))]

__global__ __launch_bounds__(TPB) void graph_f_k(const float* __restrict__ spa,
                                                 const float* __restrict__ fin3,
                                                 const unsigned short* __restrict__ wmh,
                                                 const unsigned short* __restrict__ wml,
                                                 const float* __restrict__ mapb,
                                                 const unsigned short* __restrict__ thh,
                                                 const unsigned short* __restrict__ thl,
                                                 const float* __restrict__ thb,
                                                 float* __restrict__ gout,
                                                 float* __restrict__ rawg)
{
    __shared__ __align__(16) char smem[49152];
    unsigned short* NFh = (unsigned short*)smem;             // [64][128] swz, 16KB
    unsigned short* NFl = (unsigned short*)(smem + 16384);   // 16KB
    float* s_adj        = (float*)(smem + 32768);            // [64][64] swz, 16KB
    unsigned short* Gth = (unsigned short*)smem;             // alias NFh (dead)
    unsigned short* Gtl = (unsigned short*)(smem + 16384);   // alias NFl (dead)
    __shared__ float s_red[256], s_rmax[64], s_rsum[64], s_s1[64], s_s2[64];

    int tid  = threadIdx.x;
    int lane = tid & 63;
    int w    = tid >> 6;
    int g16  = lane >> 4, l16 = lane & 15;
    int n0   = w * 16;
    int bp   = blockIdx.x;
    int tcb  = (bp % 72) * 128;

    if (tid < 64) { s_s1[tid] = 0.f; s_s2[tid] = 0.f; }

    // ---- P0: A = relu(bn3(spa)) for rows n0+l16 -> registers (split bf16) ----
    unsigned aH[16], aL[16];
    {
        const float* ar = spa + ((size_t)bp * 64 + n0 + l16) * 128;
#pragma unroll
        for (int kc = 0; kc < 4; kc++) {
            int kb = kc * 32 + g16 * 8;
            float4 x0 = *(const float4*)(ar + kb);
            float4 x1 = *(const float4*)(ar + kb + 4);
            float v[8] = {x0.x, x0.y, x0.z, x0.w, x1.x, x1.y, x1.z, x1.w};
#pragma unroll
            for (int j = 0; j < 8; j++) {
                int co = ((tcb + kb + j) * 29128) >> 20;   // exact /36 for x<32768
                float z = v[j] * fin3[co] + fin3[256 + co];
                v[j] = z > 0.f ? z : 0.f;
            }
            split2(v[0], v[1], aH[kc*4+0], aL[kc*4+0]);
            split2(v[2], v[3], aH[kc*4+1], aL[kc*4+1]);
            split2(v[4], v[5], aH[kc*4+2], aL[kc*4+2]);
            split2(v[6], v[7], aH[kc*4+3], aL[kc*4+3]);
        }
    }

    // ---- P1: nf = A @ map_w^T + mapb  -> NFh/NFl ----
    {
        f32x4 acc[8];
#pragma unroll
        for (int i = 0; i < 8; i++) { f32x4 z = {0.f,0.f,0.f,0.f}; acc[i] = z; }
#pragma unroll
        for (int ff = 0; ff < 8; ff++) {
#pragma unroll
            for (int kc = 0; kc < 4; kc++) {
                U8 ah, al;
#pragma unroll
                for (int u = 0; u < 4; u++) { ah.u[u] = aH[kc*4+u]; al.u[u] = aL[kc*4+u]; }
                size_t wo = (size_t)(ff * 16 + l16) * 128 + kc * 32 + g16 * 8;
                bf16x8 bh = *(const bf16x8*)(wmh + wo);
                bf16x8 bl = *(const bf16x8*)(wml + wo);
                acc[ff] = __builtin_amdgcn_mfma_f32_16x16x32_bf16(ah.v, bh, acc[ff], 0, 0, 0);
                acc[ff] = __builtin_amdgcn_mfma_f32_16x16x32_bf16(ah.v, bl, acc[ff], 0, 0, 0);
                acc[ff] = __builtin_amdgcn_mfma_f32_16x16x32_bf16(al.v, bh, acc[ff], 0, 0, 0);
            }
        }
#pragma unroll
        for (int ff = 0; ff < 8; ff++) {
            float bv = mapb[ff * 16 + l16];
#pragma unroll
            for (int rg = 0; rg < 4; rg++) {
                int n = n0 + g16 * 4 + rg;
                float v = acc[ff][rg] + bv;
                int s = ((n * 128) + ff * 16 + l16) ^ ((n & 7) << 3);
                unsigned short h = bf16tr(v);
                NFh[s] = h;
                NFl[s] = bf16tr(v - bf16tof(h));
            }
        }
    }
    __syncthreads();

    // ---- preload this wave's NF rows (A-operand for adj and G) ----
    bf16x8 nh[4], nl[4];
#pragma unroll
    for (int kc = 0; kc < 4; kc++) {
        int r = n0 + l16;
        int s = ((r * 128) + kc * 32 + g16 * 8) ^ ((r & 7) << 3);
        nh[kc] = *(const bf16x8*)&NFh[s];
        nl[kc] = *(const bf16x8*)&NFl[s];
    }

    // ---- P2: adj = nf @ nf^T  (diag -1e8, leaky) -> s_adj ----
    {
        f32x4 aj[4];
#pragma unroll
        for (int i = 0; i < 4; i++) { f32x4 z = {0.f,0.f,0.f,0.f}; aj[i] = z; }
#pragma unroll
        for (int mf = 0; mf < 4; mf++) {
#pragma unroll
            for (int kc = 0; kc < 4; kc++) {
                int r = mf * 16 + l16;
                int s = ((r * 128) + kc * 32 + g16 * 8) ^ ((r & 7) << 3);
                bf16x8 bh = *(const bf16x8*)&NFh[s];
                bf16x8 bl = *(const bf16x8*)&NFl[s];
                aj[mf] = __builtin_amdgcn_mfma_f32_16x16x32_bf16(nh[kc], bh, aj[mf], 0, 0, 0);
                aj[mf] = __builtin_amdgcn_mfma_f32_16x16x32_bf16(nh[kc], bl, aj[mf], 0, 0, 0);
                aj[mf] = __builtin_amdgcn_mfma_f32_16x16x32_bf16(nl[kc], bh, aj[mf], 0, 0, 0);
            }
        }
#pragma unroll
        for (int mf = 0; mf < 4; mf++)
#pragma unroll
            for (int rg = 0; rg < 4; rg++) {
                int n = n0 + g16 * 4 + rg, m = mf * 16 + l16;
                float v = aj[mf][rg];
                if (n == m) v -= 1e8f;
                v = v > 0.f ? v : 0.01f * v;
                AJX(n, m) = v;
            }
    }
    __syncthreads();   // all NF reads done before Gt overwrites the aliased LDS

    // ---- P3: G = nf @ theta^T -> Gt (transposed, split bf16; aliases NF) ----
    {
        f32x4 gg[4];
#pragma unroll
        for (int i = 0; i < 4; i++) { f32x4 z = {0.f,0.f,0.f,0.f}; gg[i] = z; }
#pragma unroll
        for (int of = 0; of < 4; of++) {
#pragma unroll
            for (int kc = 0; kc < 4; kc++) {
                size_t to = (size_t)(of * 16 + l16) * 128 + kc * 32 + g16 * 8;
                bf16x8 th_ = *(const bf16x8*)(thh + to);
                bf16x8 tl_ = *(const bf16x8*)(thl + to);
                gg[of] = __builtin_amdgcn_mfma_f32_16x16x32_bf16(nh[kc], th_, gg[of], 0, 0, 0);
                gg[of] = __builtin_amdgcn_mfma_f32_16x16x32_bf16(nh[kc], tl_, gg[of], 0, 0, 0);
                gg[of] = __builtin_amdgcn_mfma_f32_16x16x32_bf16(nl[kc], th_, gg[of], 0, 0, 0);
            }
        }
#pragma unroll
        for (int of = 0; of < 4; of++) {
            unsigned short hs[4], ls[4];
#pragma unroll
            for (int rg = 0; rg < 4; rg++) {
                float v = gg[of][rg];
                hs[rg] = bf16tr(v);
                ls[rg] = bf16tr(v - bf16tof(hs[rg]));
            }
            int o = of * 16 + l16;
            int m = n0 + g16 * 4;            // 4 consecutive m
            int s = ((o * 64) + m) ^ ((o & 7) << 3);
            uint2 hp, lp;
            hp.x = (unsigned)hs[0] | ((unsigned)hs[1] << 16);
            hp.y = (unsigned)hs[2] | ((unsigned)hs[3] << 16);
            lp.x = (unsigned)ls[0] | ((unsigned)ls[1] << 16);
            lp.y = (unsigned)ls[2] | ((unsigned)ls[3] << 16);
            *(uint2*)&Gth[s] = hp;
            *(uint2*)&Gtl[s] = lp;
        }
    }
    __syncthreads();

    // ---- P4: row softmax + I on s_adj ----
    {
        int n = tid >> 2, q = tid & 3;
        float mx = -3.0e38f;
        for (int m = q * 16; m < q * 16 + 16; m++) mx = fmaxf(mx, AJX(n, m));
        s_red[n * 4 + q] = mx;
    }
    __syncthreads();
    if (tid < 64)
        s_rmax[tid] = fmaxf(fmaxf(s_red[tid * 4], s_red[tid * 4 + 1]),
                            fmaxf(s_red[tid * 4 + 2], s_red[tid * 4 + 3]));
    __syncthreads();
    {
        int n = tid >> 2, q = tid & 3;
        float mx = s_rmax[n];
        float sm = 0.f;
        for (int m = q * 16; m < q * 16 + 16; m++) {
            float e = __expf(AJX(n, m) - mx);
            AJX(n, m) = e;
            sm += e;
        }
        s_red[n * 4 + q] = sm;
    }
    __syncthreads();
    if (tid < 64)
        s_rsum[tid] = 1.0f / (s_red[tid * 4] + s_red[tid * 4 + 1] +
                              s_red[tid * 4 + 2] + s_red[tid * 4 + 3]);
    __syncthreads();
    {
        int n = tid >> 2, q = tid & 3;
        float inv = s_rsum[n];
        for (int m = q * 16; m < q * 16 + 16; m++)
            AJX(n, m) = AJX(n, m) * inv + ((n == m) ? 1.f : 0.f);
    }
    __syncthreads();

    // ---- P5: out = adjS @ G + thb -> gout, fused stats ----
    {
        f32x4 oacc[4];
#pragma unroll
        for (int i = 0; i < 4; i++) { f32x4 z = {0.f,0.f,0.f,0.f}; oacc[i] = z; }
#pragma unroll
        for (int kc = 0; kc < 2; kc++) {
            int r = n0 + l16;
            int sf = ((r * 64) + kc * 32 + g16 * 8) ^ ((r & 7) << 3);
            float4 p0 = *(const float4*)&s_adj[sf];
            float4 p1 = *(const float4*)&s_adj[sf + 4];
            U8 ah, al;
            split2(p0.x, p0.y, ah.u[0], al.u[0]);
            split2(p0.z, p0.w, ah.u[1], al.u[1]);
            split2(p1.x, p1.y, ah.u[2], al.u[2]);
            split2(p1.z, p1.w, ah.u[3], al.u[3]);
#pragma unroll
            for (int of = 0; of < 4; of++) {
                int o = of * 16 + l16;
                int s = ((o * 64) + kc * 32 + g16 * 8) ^ ((o & 7) << 3);
                bf16x8 gh = *(const bf16x8*)&Gth[s];
                bf16x8 gl = *(const bf16x8*)&Gtl[s];
                oacc[of] = __builtin_amdgcn_mfma_f32_16x16x32_bf16(ah.v, gh, oacc[of], 0, 0, 0);
                oacc[of] = __builtin_amdgcn_mfma_f32_16x16x32_bf16(ah.v, gl, oacc[of], 0, 0, 0);
                oacc[of] = __builtin_amdgcn_mfma_f32_16x16x32_bf16(al.v, gh, oacc[of], 0, 0, 0);
            }
        }
        float* gb = gout + (size_t)bp * 4096;
#pragma unroll
        for (int of = 0; of < 4; of++) {
            float tb = thb[of * 16 + l16];
            float a = 0.f, b = 0.f;
#pragma unroll
            for (int rg = 0; rg < 4; rg++) {
                int n = n0 + g16 * 4 + rg;
                float v = oacc[of][rg] + tb;
                gb[n * 64 + of * 16 + l16] = v;
                a += v; b += v * v;
            }
            a += __shfl_xor(a, 16); a += __shfl_xor(a, 32);
            b += __shfl_xor(b, 16); b += __shfl_xor(b, 32);
            if (g16 == 0) {
                atomicAdd(&s_s1[of * 16 + l16], a);
                atomicAdd(&s_s2[of * 16 + l16], b);
            }
        }
    }
    __syncthreads();
    {
        int sl = bp & (NSL - 1);
        if (tid < 64) {
            atomicAdd(&rawg[sl * 128 + tid], s_s1[tid]);
            atomicAdd(&rawg[sl * 128 + 64 + tid], s_s2[tid]);
        }
    }
}

// ---------------- final BN + leaky + pair mean (reads folded rawgF) ----------------
__global__ __launch_bounds__(TPB) void final_k(const float* __restrict__ gout,
                                               const float* __restrict__ raw,
                                               const float* __restrict__ g,
                                               const float* __restrict__ b,
                                               float* __restrict__ out)
{
    long idx = (long)blockIdx.x * TPB + threadIdx.x;
    if (idx >= 2359296L) return;
    int o = (int)(idx & 63);
    long t = idx >> 6;
    int n = (int)(t & 63);
    long t2 = t >> 6;
    long wd = t2 % 36;
    long bb = t2 / 36;
    const float invN = 1.0f / 73728.0f;
    float m = raw[o] * invN;
    float var = raw[64 + o] * invN - m * m;
    float scale = g[o] * rsqrtf(var + 1e-5f);
    float shift = b[o] - m * scale;
    long bp = bb * 72 + wd * 2;
    float v0 = gout[(bp * 64 + n) * 64 + o] * scale + shift;
    float v1 = gout[((bp + 1) * 64 + n) * 64 + o] * scale + shift;
    v0 = v0 > 0.f ? v0 : 0.01f * v0;
    v1 = v1 > 0.f ? v1 : 0.01f * v1;
    out[idx] = 0.5f * (v0 + v1);
}

// ---------------------------------------------------------------------------
extern "C" void kernel_launch(void* const* d_in, const int* in_sizes, int n_in,
                              void* d_out, int out_size, void* d_ws, size_t ws_size,
                              hipStream_t stream)
{
    (void)in_sizes; (void)n_in; (void)out_size;
    const float* x    = (const float*)d_in[0];
    const float* c1w  = (const float*)d_in[1];
    const float* g1   = (const float*)d_in[2];
    const float* b1   = (const float*)d_in[3];
    const float* c2w  = (const float*)d_in[4];
    const float* g2   = (const float*)d_in[5];
    const float* b2   = (const float*)d_in[6];
    const float* c3w  = (const float*)d_in[7];
    const float* g3   = (const float*)d_in[8];
    const float* b3   = (const float*)d_in[9];
    const float* mapw = (const float*)d_in[10];
    const float* mapb = (const float*)d_in[11];
    const float* thw  = (const float*)d_in[12];
    const float* thb  = (const float*)d_in[13];
    const float* bng  = (const float*)d_in[14];
    const float* bnb  = (const float*)d_in[15];
    float* out = (float*)d_out;
    float* ws  = (float*)d_ws;

    // ws_size is constant across calls -> identical launch sequence every call.
    const size_t WSPLIT_USHORT = 540672;    // conv + map/theta split weights
    const size_t MONO_BYTES = ((size_t)33816576 + 8650752 + ST_FLOATS) * 4
                              + WSPLIT_USHORT * 2;
    int nch = (ws_size >= MONO_BYTES) ? 1 : 2;
    size_t P1SZ = (size_t)(nch == 1 ? 1024 : 512) * 33024;   // [bz][129][256]

    float* P1   = ws;                       // pooled-RAW conv1, [bz][129][256]
    float* P2   = ws + P1SZ;                // pooled-RAW conv2, [1024][66][128]
    float* SPA  = ws;                       // pooled-RAW conv3, [1152][64][128] (P1 dead)
    float* GOUT = ws + 9437184;             // [1152][64][64]  (after SPA, inside P1)
    float* ST   = ws + P1SZ + 8650752;
    unsigned short* WB  = (unsigned short*)(ST + ST_FLOATS);
    unsigned short* WH1 = WB;               // [3][256][64]
    unsigned short* WL1 = WB + 49152;
    unsigned short* WH2 = WB + 98304;       // [3][128][256]
    unsigned short* WL2 = WB + 196608;
    unsigned short* WH3 = WB + 294912;      // [3][256][128]
    unsigned short* WL3 = WB + 393216;
    unsigned short* WMH = WB + 491520;      // [128][128]
    unsigned short* WML = WB + 507904;
    unsigned short* THH = WB + 524288;      // [64][128]
    unsigned short* THL = WB + 532480;

    hipMemsetAsync((void*)ST, 0, ST_FLOATS * sizeof(float), stream);
    split_all_k<<<1056, TPB, 0, stream>>>(c1w, c2w, c3w, mapw, thw, WB);

    if (nch == 1) {
        mconv_k<0, 3, 0, 4><<<dim3(5, 1, 1024), TPB, 0, stream>>>(
            x, WH1, WL1, nullptr, P1, ST + RAW1,
            64, 256, 256, 1, 256, 129, 1024, 0, 0);
        bn_fin_k<<<1, TPB, 0, stream>>>(ST + RAW1, g1, b1, ST + FIN1, 256, 1.0f / 262144.0f);
        mconv_k<1, 3, 1, 2><<<dim3(3, 1, 1024), TPB, 0, stream>>>(
            P1, WH2, WL2, ST + FIN1, P2, ST + RAW2,
            256, 128, 129, 2, 131, 66, 1024, 0, 0);
    } else {
        mconv_k<0, 3, 0, 4><<<dim3(5, 1, 1024), TPB, 0, stream>>>(
            x, WH1, WL1, nullptr, P1, ST + RAW1,
            64, 256, 256, 1, 256, 129, 512, 0, 0);
        bn_fin_k<<<1, TPB, 0, stream>>>(ST + RAW1, g1, b1, ST + FIN1, 256, 1.0f / 262144.0f);
        mconv_k<1, 3, 1, 2><<<dim3(3, 1, 512), TPB, 0, stream>>>(
            P1, WH2, WL2, ST + FIN1, P2, ST + RAW2,
            256, 128, 129, 2, 131, 66, 512, 0, 0);
        mconv_k<0, 5, 0, 4><<<dim3(5, 1, 512), TPB, 0, stream>>>(
            x, WH1, WL1, nullptr, P1, nullptr,
            64, 256, 256, 1, 256, 129, 512, 512, 0);
        mconv_k<1, 3, 1, 2><<<dim3(3, 1, 512), TPB, 0, stream>>>(
            P1, WH2, WL2, ST + FIN1, P2, ST + RAW2,
            256, 128, 129, 2, 131, 66, 512, 0, 512);
    }
    bn_fin_k<<<1, TPB, 0, stream>>>(ST + RAW2, g2, b2, ST + FIN2, 128, 1.0f / 134144.0f);

    mconv_k<1, 4, 1, 4><<<dim3(2, 1, 1024), TPB, 0, stream>>>(
        P2, WH3, WL3, ST + FIN2, SPA, ST + RAW3,
        128, 256, 66, 3, 70, 36, 1024, 0, 0);
    bn_fin_k<<<1, TPB, 0, stream>>>(ST + RAW3, g3, b3, ST + FIN3, 256, 1.0f / 71680.0f);

    // ---- fused graph stage (gemm_nf + adj/softmax + G + out + stats) ----
    graph_f_k<<<1152, TPB, 0, stream>>>(SPA, ST + FIN3, WMH, WML, mapb,
                                        THH, THL, thb, GOUT, ST + RAWG);
    redg_k<<<1, 128, 0, stream>>>(ST + RAWG, ST + RAWGF);
    final_k<<<9216, TPB, 0, stream>>>(GOUT, ST + RAWGF, bng, bnb, out);
}